// Round 18
// baseline (663.470 us; speedup 1.0000x reference)
//
#include <hip/hip_runtime.h>
#include <hip/hip_fp16.h>
#include <math.h>

#define WN 4096
#define NP 8192
#define KK 32
#define EPSB 1e-5f

typedef __attribute__((ext_vector_type(8))) short s8v;
typedef __attribute__((ext_vector_type(4))) float f4v;

__device__ __forceinline__ float lrelu(float x){ return fmaxf(x, 0.01f*x); }
__device__ __forceinline__ float rlane(float v, int c){
  return __int_as_float(__builtin_amdgcn_readlane(__float_as_int(v), c));
}
__device__ __forceinline__ short f2bf(float f){
  unsigned u = __float_as_uint(f);
  u = (u + 0x7fffu + ((u>>16)&1u)) >> 16;
  return (short)u;
}

// ---------------- prep ----------------
__global__ void k_prep(const float* __restrict__ x, float* __restrict__ pts, float* __restrict__ xe0,
                       float* __restrict__ sqp, float* __restrict__ sqe,
                       float4* __restrict__ pts4, float4* __restrict__ xe04){
  int i = blockIdx.x*256 + threadIdx.x;
  if(i >= NP) return;
  int b = i>>12, p = i&4095;
  const float* xb = x + b*12288;
  float a0 = xb[p], a1 = xb[4096+p], a2 = xb[8192+p];
  pts[i*3+0]=a0; pts[i*3+1]=a1; pts[i*3+2]=a2;
  float sp = (a0*a0 + a1*a1) + a2*a2;
  sqp[i] = sp;
  pts4[i] = make_float4(a0,a1,a2,sp);
  float e0 = xb[p*3+0], e1 = xb[p*3+1], e2 = xb[p*3+2];
  xe0[i*3+0]=e0; xe0[i*3+1]=e1; xe0[i*3+2]=e2;
  float se = (e0*e0 + e1*e1) + e2*e2;
  sqe[i] = se;
  xe04[i] = make_float4(e0,e1,e2,se);
}

// ---------------- per-half bitonic sort of 32 (d, idx), ascending (lp = lane&31) ----------------
__device__ __forceinline__ void bitonic32(float& d, int& m, int lp){
  #pragma unroll
  for(int k=2;k<=32;k<<=1){
    #pragma unroll
    for(int j=k>>1;j>0;j>>=1){
      float pd = __shfl_xor(d, j);
      int pm = __shfl_xor(m, j);
      bool pLess = (pd < d);
      bool dirUp = ((lp & k) == 0);
      bool lower = ((lp & j) == 0);
      bool take = dirUp ? (lower ? pLess : !pLess) : (lower ? !pLess : pLess);
      if(take){ d = pd; m = pm; }
    }
  }
}

// ---------------- dual-query streaming top-32: lanes 0-31 = query A's list, 32-63 = query B's ----------------
// One insertion from EACH half per round. Empty half inserts +inf -> pos==32 -> structural no-op.
__device__ __forceinline__ void topk2(float d, int m, int l, float& lv, int& li){
  bool low = (l < 32);
  float thrA = rlane(lv, 31), thrB = rlane(lv, 63);
  unsigned long long mask = __ballot(d < (low ? thrA : thrB));
  while(mask){
    unsigned mA = (unsigned)mask, mB = (unsigned)(mask>>32);
    int sa = mA ? (__ffs(mA)-1)  : 0;
    int sb = mB ? (__ffs(mB)+31) : 0;
    float ca = __shfl(d, sa); int ia = __shfl(m, sa);
    float cb = __shfl(d, sb); int ib = __shfl(m, sb);
    float cdA = mA ? ca : 3.4e38f;
    float cdB = mB ? cb : 3.4e38f;
    float cd = low ? cdA : cdB;
    int cm = low ? ia : ib;
    unsigned long long less = __ballot(lv < cd);
    int pos = low ? __popc((unsigned)less) : __popc((unsigned)(less>>32));
    float uv = __shfl_up(lv, 1, 32);
    int ui = __shfl_up(li, 1, 32);
    int p = l&31;
    if(p == pos){ lv = cd; li = cm; }
    else if(p > pos){ lv = uv; li = ui; }
    mA &= mA-1; mB &= mB-1;
    mask = (unsigned long long)mA | (((unsigned long long)mB)<<32);
  }
}

// ---------------- KNN on 3-D points: 2 queries per wave ----------------
__global__ __launch_bounds__(256) void k_knn3(const float4* __restrict__ pnt4, int* __restrict__ idx){
  int l = threadIdx.x&63;
  int lp = l&31;
  int q = blockIdx.x*8 + (threadIdx.x>>6)*2 + ((l>>5)&1);
  int b = q>>12, qr = q&4095;
  const float4* pb = pnt4 + ((size_t)b<<12);
  float4 qv = pb[qr];
  float q0=qv.x, q1=qv.y, q2=qv.z, sqq=qv.w;
  float4 nc = pb[lp + 32];               // prefetch batch 1
  float lv; int li;
  {
    float4 c = pb[lp];
    float dot = q0*c.x + q1*c.y + q2*c.z;
    float dd = (sqq - 2.0f*dot) + c.w;
    int mm = lp;
    bitonic32(dd, mm, lp);
    lv = dd; li = mm;
  }
  #pragma unroll 4
  for(int j=1;j<128;j++){
    float4 c = nc;
    nc = pb[lp + (((j+1)&127)<<5)];
    float dot = q0*c.x + q1*c.y + q2*c.z;
    float d = (sqq - 2.0f*dot) + c.w;
    topk2(d, lp + (j<<5), l, lv, li);
  }
  idx[(size_t)q*KK + lp] = li;
}

// ---------------- KNN selection from fp16-packed D: 2 queries per wave, 2 candidates per load ----------------
__global__ __launch_bounds__(256) void k_knn_sel(const __half2* __restrict__ D, int* __restrict__ idx){
  int l = threadIdx.x&63;
  int lp = l&31;
  int q = blockIdx.x*8 + (threadIdx.x>>6)*2 + ((l>>5)&1);
  int b = q>>12, qr = q&4095;
  const __half2* row = D + ((size_t)b<<23) + ((size_t)qr<<11);
  __half2 h0 = row[lp];
  __half2 nh = row[lp + 32];             // prefetch batch 1
  float2 f0 = __half22float2(h0);
  float dmin, dmax; int mmin, mmax;
  if(f0.x <= f0.y){ dmin=f0.x; mmin=2*lp;   dmax=f0.y; mmax=2*lp+1; }
  else            { dmin=f0.y; mmin=2*lp+1; dmax=f0.x; mmax=2*lp;   }
  bitonic32(dmin, mmin, lp);
  float lv = dmin; int li = mmin;
  topk2(dmax, mmax, l, lv, li);
  #pragma unroll 4
  for(int j=1;j<64;j++){
    __half2 h = nh;
    nh = row[lp + (((j+1)&63)<<5)];
    float2 g = __half22float2(h);
    int base = 2*(lp + (j<<5));
    topk2(g.x, base,   l, lv, li);
    topk2(g.y, base+1, l, lv, li);
  }
  idx[(size_t)q*KK + lp] = li;
}

// ---------------- gaussian kernel conv ----------------
__global__ __launch_bounds__(128) void k_gauss(const float* __restrict__ pts, const float* __restrict__ sqp,
                                               const int* __restrict__ idxP, const float* __restrict__ cen,
                                               float* __restrict__ kout){
  __shared__ float nbx[KK], nby[KK], nbz[KK], nsq[KK];
  int p = blockIdx.x; int b = p>>12; int t = threadIdx.x;
  if(t < KK){
    int id = idxP[(size_t)p*KK + t] + (b<<12);
    nbx[t]=pts[id*3]; nby[t]=pts[id*3+1]; nbz[t]=pts[id*3+2];
    nsq[t]=sqp[id];
  }
  __syncthreads();
  float c0=cen[t*3], c1=cen[t*3+1], c2=cen[t*3+2];
  float sqc=(c0*c0+c1*c1)+c2*c2;
  float acc=0.f;
  #pragma unroll
  for(int k=0;k<KK;k++){
    float dot = nbx[k]*c0 + nby[k]*c1 + nbz[k]*c2;
    float d = (nsq[k] - 2.0f*dot) + sqc;
    acc += __expf(-0.5f*d);
  }
  kout[(size_t)((b<<7)+t)*4096 + (p&4095)] = acc;
}

// ---------------- finalize BN stats ----------------
__global__ void k_fin(const float* __restrict__ psum, const float* __restrict__ psq, int NW, int C, float Nn,
                      const float* __restrict__ g, const float* __restrict__ be,
                      float* __restrict__ sc, float* __restrict__ sh){
  int o = blockIdx.x, t = threadIdx.x;
  float s=0.f, q=0.f;
  for(int w=t; w<NW; w+=256){ s += psum[(size_t)w*C+o]; q += psq[(size_t)w*C+o]; }
  __shared__ float ls[256], lq[256];
  ls[t]=s; lq[t]=q; __syncthreads();
  for(int st=128; st; st>>=1){ if(t<st){ ls[t]+=ls[t+st]; lq[t]+=lq[t+st]; } __syncthreads(); }
  if(t==0){
    float mu = ls[0]/Nn;
    float var = lq[0]/Nn - mu*mu; if(var<0.f) var=0.f;
    float s1 = g[o]*rsqrtf(var + EPSB);
    sc[o]=s1; sh[o]=be[o]-mu*s1;
  }
}

// ---------------- edge-conv 1 BN1 stats via feature moments ----------------
__global__ __launch_bounds__(256) void k_ec1mom(const float* __restrict__ xe0, const int* __restrict__ idx1,
                                                float* __restrict__ pmom){
  int tid = blockIdx.x*256 + threadIdx.x;      // < 131072
  int l = threadIdx.x & 63;
  int wid = tid >> 6;                           // < 2048
  float a[27];
  #pragma unroll
  for(int v=0;v<27;v++) a[v]=0.f;
  #pragma unroll
  for(int u=0;u<2;u++){
    int s = tid*2 + u;
    int p = s>>5;
    int bb = (p>>12)<<12;
    int id = bb + idx1[s];
    const float* nb = xe0 + (size_t)id*3;
    const float* xc = xe0 + (size_t)p*3;
    float f[6];
    f[0]=nb[0]-xc[0]; f[1]=nb[1]-xc[1]; f[2]=nb[2]-xc[2];
    f[3]=xc[0]; f[4]=xc[1]; f[5]=xc[2];
    int v=0;
    #pragma unroll
    for(int i=0;i<6;i++){
      #pragma unroll
      for(int j=i;j<6;j++){ a[v] = fmaf(f[i], f[j], a[v]); v++; }
    }
    #pragma unroll
    for(int i=0;i<6;i++) a[21+i] += f[i];
  }
  #pragma unroll
  for(int v=0;v<27;v++){
    float t = a[v];
    #pragma unroll
    for(int off=32; off; off>>=1) t += __shfl_xor(t, off);
    if(l==0) pmom[v*2048 + wid] = t;
  }
}

__global__ void k_msum(const float* __restrict__ pmom, float* __restrict__ mom){
  int v = blockIdx.x; int t = threadIdx.x;
  float s=0.f;
  for(int i=t;i<2048;i+=256) s += pmom[v*2048+i];
  __shared__ float ls[256];
  ls[t]=s; __syncthreads();
  for(int st=128; st; st>>=1){ if(t<st) ls[t]+=ls[t+st]; __syncthreads(); }
  if(t==0) mom[v]=ls[0];
}

__global__ void k_ec1bn(const float* __restrict__ mom, const float* __restrict__ w1,
                        const float* __restrict__ g, const float* __restrict__ be,
                        float* __restrict__ sc, float* __restrict__ sh){
  __shared__ float M[27];
  int t = threadIdx.x;
  if(t<27) M[t]=mom[t];
  __syncthreads();
  if(t<64){
    float w[6];
    #pragma unroll
    for(int c=0;c<6;c++) w[c]=w1[t*6+c];
    float qf=0.f, m1=0.f;
    int v=0;
    #pragma unroll
    for(int i=0;i<6;i++){
      #pragma unroll
      for(int j=i;j<6;j++){ qf += (i==j?1.f:2.f)*w[i]*w[j]*M[v]; v++; }
    }
    #pragma unroll
    for(int i=0;i<6;i++) m1 += w[i]*M[21+i];
    float N = 262144.f;
    float mu = m1/N;
    float var = qf/N - mu*mu; if(var<0.f) var=0.f;
    float s1 = g[t]*rsqrtf(var + EPSB);
    sc[t]=s1; sh[t]=be[t]-mu*s1;
  }
}

// ---------------- edge-conv 1 fused ----------------
__global__ __launch_bounds__(256) void k_ec1g2(const float* __restrict__ xe0, const int* __restrict__ idx1,
                                               const float* __restrict__ w1, const float* __restrict__ w2T,
                                               const float* __restrict__ s1, const float* __restrict__ t1,
                                               float* __restrict__ h2m, float* __restrict__ psum,
                                               float* __restrict__ psq){
  __shared__ float As[64*64];
  __shared__ float Bs[64*132];
  __shared__ float feat[6][128];
  __shared__ float w1l[384];
  int t = threadIdx.x;
  int blk = blockIdx.x;
  int s0 = blk*128;
  int pbase = s0>>5;
  int bb = (s0>>17)<<12;
  #pragma unroll
  for(int i=0;i<16;i++) As[t + i*256] = w2T[t + i*256];
  for(int i=t; i<384; i+=256) w1l[i] = w1[i];
  if(t < 128){
    int s = s0 + t;
    int p = pbase + (t>>5);
    int id = bb + idx1[s];
    const float* nb = xe0 + (size_t)id*3;
    const float* xc = xe0 + (size_t)p*3;
    float x0 = xc[0], x1 = xc[1], x2 = xc[2];
    feat[0][t] = nb[0]-x0; feat[1][t] = nb[1]-x1; feat[2][t] = nb[2]-x2;
    feat[3][t] = x0; feat[4][t] = x1; feat[5][t] = x2;
  }
  __syncthreads();
  #pragma unroll
  for(int i=0;i<32;i++){
    int e = t + (i<<8);
    int k = e>>7, n = e&127;
    float h = w1l[k*6+0]*feat[0][n] + w1l[k*6+1]*feat[1][n] + w1l[k*6+2]*feat[2][n]
            + w1l[k*6+3]*feat[3][n] + w1l[k*6+4]*feat[4][n] + w1l[k*6+5]*feat[5][n];
    Bs[k*132 + n] = lrelu(fmaf(h, s1[k], t1[k]));
  }
  __syncthreads();
  int tx = t&15, ty = t>>4;
  float acc[4][8];
  #pragma unroll
  for(int i=0;i<4;i++){
    #pragma unroll
    for(int j=0;j<8;j++) acc[i][j]=0.f;
  }
  #pragma unroll 4
  for(int k=0;k<64;k++){
    float4 a  = *(const float4*)&As[k*64 + ty*4];
    float4 b0 = *(const float4*)&Bs[k*132 + tx*4];
    float4 b1 = *(const float4*)&Bs[k*132 + 64 + tx*4];
    float av[4] = {a.x,a.y,a.z,a.w};
    float bv[8] = {b0.x,b0.y,b0.z,b0.w,b1.x,b1.y,b1.z,b1.w};
    #pragma unroll
    for(int i=0;i<4;i++){
      #pragma unroll
      for(int j=0;j<8;j++) acc[i][j] = fmaf(av[i], bv[j], acc[i][j]);
    }
  }
  #pragma unroll
  for(int i=0;i<4;i++){
    int m = ty*4 + i;
    float sr = ((acc[i][0]+acc[i][1])+(acc[i][2]+acc[i][3])) + ((acc[i][4]+acc[i][5])+(acc[i][6]+acc[i][7]));
    float sq = ((acc[i][0]*acc[i][0]+acc[i][1]*acc[i][1])+(acc[i][2]*acc[i][2]+acc[i][3]*acc[i][3]))
             + ((acc[i][4]*acc[i][4]+acc[i][5]*acc[i][5])+(acc[i][6]*acc[i][6]+acc[i][7]*acc[i][7]));
    #pragma unroll
    for(int off=1; off<16; off<<=1){ sr += __shfl_xor(sr, off); sq += __shfl_xor(sq, off); }
    if(tx==0){ psum[(size_t)blk*64+m]=sr; psq[(size_t)blk*64+m]=sq; }
    float m0 = fmaxf(fmaxf(acc[i][0],acc[i][1]), fmaxf(acc[i][2],acc[i][3]));
    float m1 = fmaxf(fmaxf(acc[i][4],acc[i][5]), fmaxf(acc[i][6],acc[i][7]));
    #pragma unroll
    for(int off=1; off<8; off<<=1){ m0 = fmaxf(m0, __shfl_xor(m0, off)); m1 = fmaxf(m1, __shfl_xor(m1, off)); }
    if((tx&7)==0){
      int pl = pbase + (tx>>3);
      h2m[(size_t)pl*64 + m]     = m0;
      h2m[(size_t)(pl+2)*64 + m] = m1;
    }
  }
}

// ---------------- ec1 finalize ----------------
__global__ __launch_bounds__(256) void k_ec1fin(const float* __restrict__ h2m, const float* __restrict__ s2,
                                                const float* __restrict__ t2, float* __restrict__ xe1,
                                                float* __restrict__ xe1T, float* __restrict__ sqx){
  int gid = blockIdx.x*256 + threadIdx.x;  // < NP*64
  int p = gid>>6, l = gid&63;
  float v = lrelu(fmaf(h2m[(size_t)p*64+l], s2[l], t2[l]));
  xe1[(size_t)p*64+l] = v;
  int b=p>>12, pr=p&4095;
  xe1T[(size_t)(b*64+l)*4096 + pr] = v;
  float sq = v*v;
  #pragma unroll
  for(int off=32; off; off>>=1) sq += __shfl_xor(sq, off);
  if(l==0) sqx[p]=sq;
}

// ---------------- D (fp16) via bf16 MFMA: block (mb,nb,b); writes transposed (D symmetric) ----------------
__global__ __launch_bounds__(256) void k_dgemm_m(const short* __restrict__ X, const float* __restrict__ sqx,
                                                 __half* __restrict__ D){
  __shared__ short sA[8192], sB[8192];
  int t = threadIdx.x;
  int lane = t&63, w = t>>6;
  int wm4 = (w>>1)*4, wn4 = (w&1)*4;
  int mb = blockIdx.y, nb = blockIdx.x, b = blockIdx.z;
  const short* AG = X + (size_t)(b*32 + mb)*8192;
  const short* BG = X + (size_t)(b*32 + nb)*8192;
  #pragma unroll
  for(int i=0;i<4;i++){
    int slot = t + i*256;
    *(s8v*)&sA[slot*8] = *(const s8v*)&AG[slot*8];
    *(s8v*)&sB[slot*8] = *(const s8v*)&BG[slot*8];
  }
  __syncthreads();
  f4v acc[4][4];
  #pragma unroll
  for(int i=0;i<4;i++){
    #pragma unroll
    for(int j=0;j<4;j++) acc[i][j] = (f4v)(0.f);
  }
  #pragma unroll
  for(int kh=0;kh<2;kh++){
    s8v av[4], bv[4];
    #pragma unroll
    for(int f=0;f<4;f++) av[f] = *(const s8v*)&sA[(kh*8 + wm4 + f)*512 + lane*8];
    #pragma unroll
    for(int f=0;f<4;f++) bv[f] = *(const s8v*)&sB[(kh*8 + wn4 + f)*512 + lane*8];
    #pragma unroll
    for(int fm=0;fm<4;fm++){
      #pragma unroll
      for(int fn=0;fn<4;fn++)
        acc[fm][fn] = __builtin_amdgcn_mfma_f32_16x16x32_bf16(av[fm], bv[fn], acc[fm][fn], 0, 0, 0);
    }
  }
  const float* sb = sqx + (b<<12);
  __half* Db = D + ((size_t)b<<24);
  int l15 = lane&15, l4 = (lane>>4)*4;
  #pragma unroll
  for(int fm=0;fm<4;fm++){
    int m0 = mb*128 + wm4*16 + fm*16 + l4;
    float sm0 = sb[m0], sm1 = sb[m0+1], sm2 = sb[m0+2], sm3 = sb[m0+3];
    #pragma unroll
    for(int fn=0;fn<4;fn++){
      int n = nb*128 + wn4*16 + fn*16 + l15;
      float sqn = sb[n];
      __half2 h01 = __floats2half2_rn((sm0 + sqn) - 2.f*acc[fm][fn][0],
                                      (sm1 + sqn) - 2.f*acc[fm][fn][1]);
      __half2 h23 = __floats2half2_rn((sm2 + sqn) - 2.f*acc[fm][fn][2],
                                      (sm3 + sqn) - 2.f*acc[fm][fn][3]);
      __half2* p = (__half2*)&Db[(size_t)n*4096 + m0];
      p[0] = h01; p[1] = h23;
    }
  }
}

// ---------------- edge-conv 2 pass 1 (bf16 MFMA gather-GEMM) ----------------
__global__ __launch_bounds__(256) void k_ec2m1(const float* __restrict__ xe1, const int* __restrict__ idx2,
                                               const short* __restrict__ wb, float* __restrict__ h1,
                                               float* __restrict__ psum, float* __restrict__ psq){
  __shared__ short sA[8192], sB[8192];
  __shared__ float cts[4][64];
  __shared__ int nid[128];
  __shared__ float srs[2][128], srq[2][128];
  int t = threadIdx.x;
  int blk = blockIdx.x;
  int s0 = blk*128;
  int pbase = s0>>5;
  int bb = (s0>>17)<<12;
  if(t<128) nid[t] = (idx2[s0+t] + bb)<<6;
  cts[t>>6][t&63] = xe1[(size_t)(pbase + (t>>6))*64 + (t&63)];
  int lane = t&63, w = t>>6;
  int wm4 = (w>>1)*4, wn4 = (w&1)*4;
  f4v acc[4][4];
  #pragma unroll
  for(int i=0;i<4;i++){
    #pragma unroll
    for(int j=0;j<4;j++) acc[i][j] = (f4v)(0.f);
  }
  for(int st=0; st<2; ++st){
    __syncthreads();
    #pragma unroll
    for(int i=0;i<4;i++){
      int slot = t + i*256;
      *(s8v*)&sA[slot*8] = *(const s8v*)&wb[st*8192 + slot*8];
      int chunk = slot>>6, li = slot&63;
      int n = (chunk&7)*16 + (li&15);
      int c = ((chunk>>3)<<5) + ((li>>4)<<3);
      float v[8];
      if(st==0){
        const float* src = xe1 + nid[n] + c;
        float4 a0 = *(const float4*)src;
        float4 a1 = *(const float4*)(src+4);
        const float* cc = &cts[n>>5][c];
        float4 c0 = *(const float4*)cc;
        float4 c1 = *(const float4*)(cc+4);
        v[0]=a0.x-c0.x; v[1]=a0.y-c0.y; v[2]=a0.z-c0.z; v[3]=a0.w-c0.w;
        v[4]=a1.x-c1.x; v[5]=a1.y-c1.y; v[6]=a1.z-c1.z; v[7]=a1.w-c1.w;
      } else {
        const float* cc = &cts[n>>5][c];
        float4 c0 = *(const float4*)cc;
        float4 c1 = *(const float4*)(cc+4);
        v[0]=c0.x; v[1]=c0.y; v[2]=c0.z; v[3]=c0.w;
        v[4]=c1.x; v[5]=c1.y; v[6]=c1.z; v[7]=c1.w;
      }
      s8v r;
      #pragma unroll
      for(int j=0;j<8;j++) r[j] = f2bf(v[j]);
      *(s8v*)&sB[slot*8] = r;
    }
    __syncthreads();
    #pragma unroll
    for(int kh=0;kh<2;kh++){
      s8v av[4], bv[4];
      #pragma unroll
      for(int f=0;f<4;f++) av[f] = *(const s8v*)&sA[(kh*8 + wm4 + f)*512 + lane*8];
      #pragma unroll
      for(int f=0;f<4;f++) bv[f] = *(const s8v*)&sB[(kh*8 + wn4 + f)*512 + lane*8];
      #pragma unroll
      for(int fm=0;fm<4;fm++){
        #pragma unroll
        for(int fn=0;fn<4;fn++)
          acc[fm][fn] = __builtin_amdgcn_mfma_f32_16x16x32_bf16(av[fm], bv[fn], acc[fm][fn], 0, 0, 0);
      }
    }
  }
  int l15 = lane&15, l4 = (lane>>4)<<2;
  #pragma unroll
  for(int fm=0;fm<4;fm++){
    int mb_ = wm4*16 + fm*16 + l4;
    #pragma unroll
    for(int fn=0;fn<4;fn++){
      int n = wn4*16 + fn*16 + l15;
      *(float4*)&h1[(size_t)(s0+n)*128 + mb_] =
        make_float4(acc[fm][fn][0], acc[fm][fn][1], acc[fm][fn][2], acc[fm][fn][3]);
    }
    #pragma unroll
    for(int r=0;r<4;r++){
      float sr = (acc[fm][0][r]+acc[fm][1][r]) + (acc[fm][2][r]+acc[fm][3][r]);
      float sq = (acc[fm][0][r]*acc[fm][0][r]+acc[fm][1][r]*acc[fm][1][r])
               + (acc[fm][2][r]*acc[fm][2][r]+acc[fm][3][r]*acc[fm][3][r]);
      #pragma unroll
      for(int off=1; off<16; off<<=1){ sr += __shfl_xor(sr, off); sq += __shfl_xor(sq, off); }
      if(l15==0){ srs[w&1][mb_+r] = sr; srq[w&1][mb_+r] = sq; }
    }
  }
  __syncthreads();
  if(t<128){
    psum[(size_t)blk*128+t] = srs[0][t]+srs[1][t];
    psq[(size_t)blk*128+t]  = srq[0][t]+srq[1][t];
  }
}

// ---------------- edge-conv 2 pass 2 (bf16 MFMA, fused BN1+lrelu, stats + per-point max) ----------------
__global__ __launch_bounds__(256) void k_ec2m2(const float* __restrict__ h1, const short* __restrict__ wb,
                                               const float* __restrict__ s1, const float* __restrict__ t1,
                                               float* __restrict__ h2max, float* __restrict__ psum,
                                               float* __restrict__ psq){
  __shared__ short sA[8192], sB[8192];
  __shared__ float bnS[128], bnT[128];
  __shared__ float srs[2][128], srq[2][128];
  int t = threadIdx.x;
  int blk = blockIdx.x;
  int s0 = blk*128;
  int pbase = s0>>5;
  if(t<128){ bnS[t]=s1[t]; bnT[t]=t1[t]; }
  int lane = t&63, w = t>>6;
  int wm4 = (w>>1)*4, wn4 = (w&1)*4;
  f4v acc[4][4];
  #pragma unroll
  for(int i=0;i<4;i++){
    #pragma unroll
    for(int j=0;j<4;j++) acc[i][j] = (f4v)(0.f);
  }
  for(int st=0; st<2; ++st){
    __syncthreads();
    #pragma unroll
    for(int i=0;i<4;i++){
      int slot = t + i*256;
      *(s8v*)&sA[slot*8] = *(const s8v*)&wb[st*8192 + slot*8];
      int chunk = slot>>6, li = slot&63;
      int n = (chunk&7)*16 + (li&15);
      int c = st*64 + ((chunk>>3)<<5) + ((li>>4)<<3);
      const float* src = h1 + (size_t)(s0+n)*128 + c;
      float4 a0 = *(const float4*)src;
      float4 a1 = *(const float4*)(src+4);
      float v[8] = {a0.x,a0.y,a0.z,a0.w,a1.x,a1.y,a1.z,a1.w};
      s8v r;
      #pragma unroll
      for(int j=0;j<8;j++) r[j] = f2bf(lrelu(fmaf(v[j], bnS[c+j], bnT[c+j])));
      *(s8v*)&sB[slot*8] = r;
    }
    __syncthreads();
    #pragma unroll
    for(int kh=0;kh<2;kh++){
      s8v av[4], bv[4];
      #pragma unroll
      for(int f=0;f<4;f++) av[f] = *(const s8v*)&sA[(kh*8 + wm4 + f)*512 + lane*8];
      #pragma unroll
      for(int f=0;f<4;f++) bv[f] = *(const s8v*)&sB[(kh*8 + wn4 + f)*512 + lane*8];
      #pragma unroll
      for(int fm=0;fm<4;fm++){
        #pragma unroll
        for(int fn=0;fn<4;fn++)
          acc[fm][fn] = __builtin_amdgcn_mfma_f32_16x16x32_bf16(av[fm], bv[fn], acc[fm][fn], 0, 0, 0);
      }
    }
  }
  int l15 = lane&15, l4 = (lane>>4)<<2;
  int pp0 = wn4>>1;
  #pragma unroll
  for(int fm=0;fm<4;fm++){
    int mb_ = wm4*16 + fm*16 + l4;
    #pragma unroll
    for(int r=0;r<4;r++){
      float sr = (acc[fm][0][r]+acc[fm][1][r]) + (acc[fm][2][r]+acc[fm][3][r]);
      float sq = (acc[fm][0][r]*acc[fm][0][r]+acc[fm][1][r]*acc[fm][1][r])
               + (acc[fm][2][r]*acc[fm][2][r]+acc[fm][3][r]*acc[fm][3][r]);
      float m0 = fmaxf(acc[fm][0][r], acc[fm][1][r]);
      float m1 = fmaxf(acc[fm][2][r], acc[fm][3][r]);
      #pragma unroll
      for(int off=1; off<16; off<<=1){ sr += __shfl_xor(sr, off); sq += __shfl_xor(sq, off); }
      #pragma unroll
      for(int off=1; off<16; off<<=1){ m0 = fmaxf(m0, __shfl_xor(m0, off)); m1 = fmaxf(m1, __shfl_xor(m1, off)); }
      if(l15==0){
        srs[w&1][mb_+r] = sr; srq[w&1][mb_+r] = sq;
        h2max[(size_t)(pbase+pp0)*128   + mb_+r] = m0;
        h2max[(size_t)(pbase+pp0+1)*128 + mb_+r] = m1;
      }
    }
  }
  __syncthreads();
  if(t<128){
    psum[(size_t)blk*128+t] = srs[0][t]+srs[1][t];
    psq[(size_t)blk*128+t]  = srq[0][t]+srq[1][t];
  }
}

// ---------------- xe2 = lrelu(BN(h2max)) in-place ----------------
__global__ void k_xe2fin(float* __restrict__ xe2, const float* __restrict__ s2, const float* __restrict__ t2){
  int i = blockIdx.x*256 + threadIdx.x;   // < NP*128
  if(i >= NP*128) return;
  int o = i&127;
  xe2[i] = lrelu(fmaf(xe2[i], s2[o], t2[o]));
}

// ---------------- generic small transpose ----------------
__global__ void k_transpose(const float* __restrict__ w, float* __restrict__ wT, int O, int C){
  int i = blockIdx.x*256 + threadIdx.x;
  if(i >= O*C) return;
  int o = i / C, c = i % C;
  wT[(size_t)c*O + o] = w[i];
}

// ---------------- weight fp32 -> bf16 fragment-linear ----------------
__global__ void k_wprep(const float* __restrict__ w, short* __restrict__ wb, int M, int K){
  int tid = blockIdx.x*256 + threadIdx.x;
  int m = tid % M, kb8 = tid / M;
  int k0 = kb8*8;
  float4 v0 = *(const float4*)&w[(size_t)m*K + k0];
  float4 v1 = *(const float4*)&w[(size_t)m*K + k0 + 4];
  s8v r;
  r[0]=f2bf(v0.x); r[1]=f2bf(v0.y); r[2]=f2bf(v0.z); r[3]=f2bf(v0.w);
  r[4]=f2bf(v1.x); r[5]=f2bf(v1.y); r[6]=f2bf(v1.z); r[7]=f2bf(v1.w);
  int region = (m>>7)*(K>>6) + (k0>>6);
  int chunk = ((kb8>>2)&1)*8 + ((m>>4)&7);
  int lane = (kb8&3)*16 + (m&15);
  *(s8v*)&wb[(size_t)region*8192 + chunk*512 + lane*8] = r;
}

// ---------------- activations -> bf16 fragment-linear ----------------
__global__ void k_bprep(const float* __restrict__ in, const float* __restrict__ sc, const float* __restrict__ sh,
                        short* __restrict__ ob, int K){
  int tid = blockIdx.x*256 + threadIdx.x;
  int n = tid & 8191, kb8 = tid >> 13;
  int k0 = kb8*8;
  int b = n>>12, s = n&4095;
  const float* ib = in + ((size_t)b*K + k0)*4096 + s;
  float v[8];
  #pragma unroll
  for(int j=0;j<8;j++) v[j] = ib[(size_t)j*4096];
  if(sc){
    #pragma unroll
    for(int j=0;j<8;j++) v[j] = lrelu(fmaf(v[j], sc[k0+j], sh[k0+j]));
  }
  s8v r;
  #pragma unroll
  for(int j=0;j<8;j++) r[j] = f2bf(v[j]);
  int region = (n>>7)*(K>>6) + (k0>>6);
  int chunk = ((kb8>>2)&1)*8 + ((n>>4)&7);
  int lane = (kb8&3)*16 + (n&15);
  *(s8v*)&ob[(size_t)region*8192 + chunk*512 + lane*8] = r;
}

// ---------------- layer-1 activations: read [xe2-flat ; kr] directly ----------------
__global__ void k_bprep1(const float* __restrict__ xe2, const float* __restrict__ kr,
                         short* __restrict__ ob){
  int tid = blockIdx.x*256 + threadIdx.x;   // < 8192*256/8
  int n = tid & 8191, kb8 = tid >> 13;
  int k0 = kb8*8;
  int b = n>>12, s = n&4095;
  const float* ib;
  if(k0 < 128) ib = xe2 + (size_t)b*524288 + (size_t)k0*4096 + s;
  else         ib = kr + ((size_t)(b*128 + (k0-128)))*4096 + s;
  float v[8];
  #pragma unroll
  for(int j=0;j<8;j++) v[j] = ib[(size_t)j*4096];
  s8v r;
  #pragma unroll
  for(int j=0;j<8;j++) r[j] = f2bf(v[j]);
  int region = (n>>7)*4 + (k0>>6);
  int chunk = ((kb8>>2)&1)*8 + ((n>>4)&7);
  int lane = (kb8&3)*16 + (n&15);
  *(s8v*)&ob[(size_t)region*8192 + chunk*512 + lane*8] = r;
}

// ---------------- bf16 MFMA GEMM ----------------
__global__ __launch_bounds__(256) void k_gmm(const short* __restrict__ A, const short* __restrict__ B,
                                             float* __restrict__ out, int M, int K){
  __shared__ short sA[8192], sB[8192];
  int t = threadIdx.x;
  int lane = t&63;
  int w = t>>6;
  int wm4 = (w>>1)*4, wn4 = (w&1)*4;
  int mb = blockIdx.y, nb = blockIdx.x;
  int ksteps = K>>6;
  const short* AG = A + (size_t)mb*ksteps*8192;
  const short* BG = B + (size_t)nb*ksteps*8192;
  f4v acc[4][4];
  #pragma unroll
  for(int i=0;i<4;i++){
    #pragma unroll
    for(int j=0;j<4;j++) acc[i][j] = (f4v)(0.f);
  }
  for(int st=0; st<ksteps; ++st){
    __syncthreads();
    #pragma unroll
    for(int i=0;i<4;i++){
      int slot = t + i*256;
      *(s8v*)&sA[slot*8] = *(const s8v*)&AG[(size_t)st*8192 + slot*8];
      *(s8v*)&sB[slot*8] = *(const s8v*)&BG[(size_t)st*8192 + slot*8];
    }
    __syncthreads();
    #pragma unroll
    for(int kh=0;kh<2;kh++){
      s8v av[4], bv[4];
      #pragma unroll
      for(int f=0;f<4;f++) av[f] = *(const s8v*)&sA[(kh*8 + wm4 + f)*512 + lane*8];
      #pragma unroll
      for(int f=0;f<4;f++) bv[f] = *(const s8v*)&sB[(kh*8 + wn4 + f)*512 + lane*8];
      #pragma unroll
      for(int fm=0;fm<4;fm++){
        #pragma unroll
        for(int fn=0;fn<4;fn++)
          acc[fm][fn] = __builtin_amdgcn_mfma_f32_16x16x32_bf16(av[fm], bv[fn], acc[fm][fn], 0, 0, 0);
      }
    }
  }
  int l15 = lane&15, l4 = (lane>>4)*4;
  #pragma unroll
  for(int fm=0;fm<4;fm++){
    int mrow = mb*128 + wm4*16 + fm*16 + l4;
    #pragma unroll
    for(int fn=0;fn<4;fn++){
      int n = nb*128 + wn4*16 + fn*16 + l15;
      int b = n>>12, s = n&4095;
      float* ob = out + ((size_t)b*M + mrow)*4096 + s;
      #pragma unroll
      for(int r=0;r<4;r++) ob[(size_t)r*4096] = acc[fm][fn][r];
    }
  }
}

// ---------------- per-channel stats for cbr layers ----------------
__global__ void k_cstats(const float* __restrict__ buf, int C, const float* __restrict__ g,
                         const float* __restrict__ be, float* __restrict__ sc, float* __restrict__ sh){
  int o = blockIdx.x, t = threadIdx.x;
  float s=0.f, q=0.f;
  for(int i=t;i<8192;i+=256){
    int b=i>>12, ss_=i&4095;
    float v = buf[(size_t)(b*C+o)*4096 + ss_];
    s+=v; q+=v*v;
  }
  __shared__ float ls[256], lq[256];
  ls[t]=s; lq[t]=q; __syncthreads();
  for(int st=128; st; st>>=1){ if(t<st){ ls[t]+=ls[t+st]; lq[t]+=lq[t+st]; } __syncthreads(); }
  if(t==0){
    float mu = ls[0]/8192.f;
    float var = lq[0]/8192.f - mu*mu; if(var<0.f) var=0.f;
    float s1 = g[o]*rsqrtf(var + EPSB);
    sc[o]=s1; sh[o]=be[o]-mu*s1;
  }
}

// ---------------- final layer ----------------
__global__ __launch_bounds__(256) void k_final4(const float* __restrict__ c3, const float* __restrict__ w4T,
                                                const float* __restrict__ sc, const float* __restrict__ sh,
                                                float* __restrict__ pmax){
  int b = blockIdx.y, st = blockIdx.x;
  int t = threadIdx.x; int s = st*256 + t;
  float acc[9];
  #pragma unroll
  for(int j=0;j<9;j++) acc[j]=0.f;
  const float* ib = c3 + (size_t)b*256*4096;
  for(int c=0;c<256;c++){
    float x = lrelu(fmaf(ib[(size_t)c*4096+s], sc[c], sh[c]));
    #pragma unroll
    for(int j=0;j<9;j++) acc[j]=fmaf(x, w4T[c*9+j], acc[j]);
  }
  __shared__ float red[256];
  for(int j=0;j<9;j++){
    red[t]=acc[j]; __syncthreads();
    for(int stp=128; stp; stp>>=1){ if(t<stp) red[t]=fmaxf(red[t],red[t+stp]); __syncthreads(); }
    if(t==0) pmax[(b*16+st)*9 + j]=red[0];
    __syncthreads();
  }
}

__global__ void k_out(const float* __restrict__ pmax, float* __restrict__ out){
  int i = threadIdx.x;
  if(i<18){
    int b=i/9, o=i%9;
    float m=-3.4e38f;
    for(int k=0;k<16;k++) m=fmaxf(m, pmax[(b*16+k)*9+o]);
    out[i] = m + ((o==0||o==4||o==8)?1.f:0.f);
  }
}

// ---------------- launch ----------------
extern "C" void kernel_launch(void* const* d_in, const int* in_sizes, int n_in,
                              void* d_out, int out_size, void* d_ws, size_t ws_size,
                              hipStream_t stream){
  const float* x    = (const float*)d_in[0];
  const float* kc   = (const float*)d_in[1];
  const float* e1w1 = (const float*)d_in[2];
  const float* e1g1 = (const float*)d_in[3];
  const float* e1b1 = (const float*)d_in[4];
  const float* e1w2 = (const float*)d_in[5];
  const float* e1g2 = (const float*)d_in[6];
  const float* e1b2 = (const float*)d_in[7];
  const float* e2w1 = (const float*)d_in[8];
  const float* e2g1 = (const float*)d_in[9];
  const float* e2b1 = (const float*)d_in[10];
  const float* e2w2 = (const float*)d_in[11];
  const float* e2g2 = (const float*)d_in[12];
  const float* e2b2 = (const float*)d_in[13];
  const float* w1   = (const float*)d_in[14];
  const float* g1   = (const float*)d_in[15];
  const float* b1   = (const float*)d_in[16];
  const float* w2   = (const float*)d_in[17];
  const float* g2   = (const float*)d_in[18];
  const float* b2   = (const float*)d_in[19];
  const float* w3   = (const float*)d_in[20];
  const float* g3   = (const float*)d_in[21];
  const float* b3   = (const float*)d_in[22];
  const float* w4   = (const float*)d_in[23];

  if(ws_size < 156061696ull) return;
  char* ws = (char*)d_ws;
  float* pts   = (float*)(ws + 0);
  float* xe0   = (float*)(ws + 98304);
  float* sqp   = (float*)(ws + 196608);
  float* sqe   = (float*)(ws + 229376);
  float* sqx1  = (float*)(ws + 262144);
  float* xe1   = (float*)(ws + 294912);
  float* xe1T  = (float*)(ws + 2392064);
  float* xe2   = (float*)(ws + 4489216);
  float* kr    = (float*)(ws + 8683520);
  int*   idxP  = (int*)  (ws + 12877824);
  int*   idx1  = (int*)  (ws + 13926400);
  int*   idx2  = (int*)  (ws + 14974976);
  float* psum  = (float*)(ws + 16023552);
  float* psq   = (float*)(ws + 17072128);
  float* par   = (float*)(ws + 18120704);
  float* pmax  = (float*)(ws + 18153472);
  float* e1w2T = (float*)(ws + 18157568);
  float* wT4   = (float*)(ws + 21827584);
  float* hbuf  = (float*)(ws + 21843968);
  short* wbe1  = (short*)(ws + 0);
  short* wbe2  = (short*)(ws + 65536);
  float4* pts4 = (float4*)(ws + 4489216);
  float4* xe04 = (float4*)(ws + 4489216 + 131072);
  short* actB  = (short*)(ws + 88952832);
  short* xpack = (short*)(ws + 88952832);
  short* wb1   = (short*)(ws + 105730048);
  short* wb2   = (short*)(ws + 106254336);
  short* wb3   = (short*)(ws + 107302912);
  float* pmom  = psum;
  float* momv  = psq;

  float* e1s1 = par+0;    float* e1t1 = par+64;
  float* e1s2 = par+128;  float* e1t2 = par+192;
  float* e2s1 = par+256;  float* e2t1 = par+384;
  float* e2s2 = par+512;  float* e2t2 = par+640;
  float* c1s  = par+768;  float* c1t  = par+1792;
  float* c2s  = par+2816; float* c2t  = par+3328;
  float* c3s  = par+3840; float* c3t  = par+4096;

  float* c1out = hbuf + 2097152;
  float* c2out = hbuf + 10485760;
  float* c3out = hbuf + 14680064;

  hipLaunchKernelGGL(k_prep, dim3(32), dim3(256), 0, stream, x, pts, xe0, sqp, sqe, pts4, xe04);
  hipLaunchKernelGGL(k_knn3, dim3(1024), dim3(256), 0, stream, pts4, idxP);
  hipLaunchKernelGGL(k_knn3, dim3(1024), dim3(256), 0, stream, xe04, idx1);
  hipLaunchKernelGGL(k_gauss, dim3(8192), dim3(128), 0, stream, pts, sqp, idxP, kc, kr);

  // edge-conv 1 (moment-based BN1 stats; h1 never stored)
  hipLaunchKernelGGL(k_transpose, dim3(16), dim3(256), 0, stream, e1w2, e1w2T, 64, 64);
  hipLaunchKernelGGL(k_ec1mom, dim3(512), dim3(256), 0, stream, xe0, idx1, pmom);
  hipLaunchKernelGGL(k_msum, dim3(27), dim3(256), 0, stream, pmom, momv);
  hipLaunchKernelGGL(k_ec1bn, dim3(1), dim3(64), 0, stream, momv, e1w1, e1g1, e1b1, e1s1, e1t1);
  hipLaunchKernelGGL(k_ec1g2, dim3(2048), dim3(256), 0, stream, xe0, idx1, e1w1, e1w2T, e1s1, e1t1, hbuf, psum, psq);
  hipLaunchKernelGGL(k_fin, dim3(64), dim3(256), 0, stream, psum, psq, 2048, 64, 262144.f, e1g2, e1b2, e1s2, e1t2);
  hipLaunchKernelGGL(k_ec1fin, dim3(2048), dim3(256), 0, stream, hbuf, e1s2, e1t2, xe1, xe1T, sqx1);

  // knn on 64-d features: bf16 MFMA distance GEMM (fp16-packed D) + dual-query selection
  hipLaunchKernelGGL(k_wprep, dim3(256), dim3(256), 0, stream, xe1, xpack, 8192, 64);
  hipLaunchKernelGGL(k_dgemm_m, dim3(32,32,2), dim3(256), 0, stream, xpack, sqx1, (__half*)hbuf);
  hipLaunchKernelGGL(k_knn_sel, dim3(1024), dim3(256), 0, stream, (const __half2*)hbuf, idx2);

  // edge-conv 2 (bf16 MFMA formulation, fused stats+max)
  hipLaunchKernelGGL(k_wprep, dim3(8), dim3(256), 0, stream, e2w1, wbe1, 128, 128);
  hipLaunchKernelGGL(k_wprep, dim3(8), dim3(256), 0, stream, e2w2, wbe2, 128, 128);
  hipLaunchKernelGGL(k_ec2m1, dim3(2048), dim3(256), 0, stream, xe1, idx2, wbe1, hbuf, psum, psq);
  hipLaunchKernelGGL(k_fin, dim3(128), dim3(256), 0, stream, psum, psq, 2048, 128, 262144.f, e2g1, e2b1, e2s1, e2t1);
  hipLaunchKernelGGL(k_ec2m2, dim3(2048), dim3(256), 0, stream, hbuf, wbe2, e2s1, e2t1, xe2, psum, psq);
  hipLaunchKernelGGL(k_fin, dim3(128), dim3(256), 0, stream, psum, psq, 2048, 128, 262144.f, e2g2, e2b2, e2s2, e2t2);
  hipLaunchKernelGGL(k_xe2fin, dim3(4096), dim3(256), 0, stream, xe2, e2s2, e2t2);

  // bf16 MFMA cbr chain (hcat fused into k_bprep1)
  hipLaunchKernelGGL(k_wprep, dim3(128), dim3(256), 0, stream, w1, wb1, 1024, 256);
  hipLaunchKernelGGL(k_wprep, dim3(256), dim3(256), 0, stream, w2, wb2, 512, 1024);
  hipLaunchKernelGGL(k_wprep, dim3(64),  dim3(256), 0, stream, w3, wb3, 256, 512);
  hipLaunchKernelGGL(k_transpose, dim3((9*256+255)/256), dim3(256), 0, stream, w4, wT4, 9, 256);

  hipLaunchKernelGGL(k_bprep1, dim3(1024), dim3(256), 0, stream, xe2, kr, actB);
  hipLaunchKernelGGL(k_gmm, dim3(64,8), dim3(256), 0, stream, wb1, actB, c1out, 1024, 256);
  hipLaunchKernelGGL(k_cstats, dim3(1024), dim3(256), 0, stream, c1out, 1024, g1, b1, c1s, c1t);

  hipLaunchKernelGGL(k_bprep, dim3(4096), dim3(256), 0, stream, c1out, c1s, c1t, actB, 1024);
  hipLaunchKernelGGL(k_gmm, dim3(64,4), dim3(256), 0, stream, wb2, actB, c2out, 512, 1024);
  hipLaunchKernelGGL(k_cstats, dim3(512), dim3(256), 0, stream, c2out, 512, g2, b2, c2s, c2t);

  hipLaunchKernelGGL(k_bprep, dim3(2048), dim3(256), 0, stream, c2out, c2s, c2t, actB, 512);
  hipLaunchKernelGGL(k_gmm, dim3(64,2), dim3(256), 0, stream, wb3, actB, c3out, 256, 512);
  hipLaunchKernelGGL(k_cstats, dim3(256), dim3(256), 0, stream, c3out, 256, g3, b3, c3s, c3t);

  hipLaunchKernelGGL(k_final4, dim3(16,2), dim3(256), 0, stream, c3out, wT4, c3s, c3t, pmax);
  hipLaunchKernelGGL(k_out, dim3(1), dim3(32), 0, stream, pmax, (float*)d_out);
}

// Round 19
// 627.703 us; speedup vs baseline: 1.0570x; 1.0570x over previous
//
#include <hip/hip_runtime.h>
#include <hip/hip_fp16.h>
#include <math.h>

#define WN 4096
#define NP 8192
#define KK 32
#define EPSB 1e-5f

typedef __attribute__((ext_vector_type(8))) short s8v;
typedef __attribute__((ext_vector_type(4))) float f4v;

__device__ __forceinline__ float lrelu(float x){ return fmaxf(x, 0.01f*x); }
__device__ __forceinline__ float rlane(float v, int c){
  return __int_as_float(__builtin_amdgcn_readlane(__float_as_int(v), c));
}
__device__ __forceinline__ short f2bf(float f){
  unsigned u = __float_as_uint(f);
  u = (u + 0x7fffu + ((u>>16)&1u)) >> 16;
  return (short)u;
}

// ---------------- prep ----------------
__global__ void k_prep(const float* __restrict__ x, float* __restrict__ pts, float* __restrict__ xe0,
                       float* __restrict__ sqp, float* __restrict__ sqe,
                       float4* __restrict__ pts4, float4* __restrict__ xe04){
  int i = blockIdx.x*256 + threadIdx.x;
  if(i >= NP) return;
  int b = i>>12, p = i&4095;
  const float* xb = x + b*12288;
  float a0 = xb[p], a1 = xb[4096+p], a2 = xb[8192+p];
  pts[i*3+0]=a0; pts[i*3+1]=a1; pts[i*3+2]=a2;
  float sp = (a0*a0 + a1*a1) + a2*a2;
  sqp[i] = sp;
  pts4[i] = make_float4(a0,a1,a2,sp);
  float e0 = xb[p*3+0], e1 = xb[p*3+1], e2 = xb[p*3+2];
  xe0[i*3+0]=e0; xe0[i*3+1]=e1; xe0[i*3+2]=e2;
  float se = (e0*e0 + e1*e1) + e2*e2;
  sqe[i] = se;
  xe04[i] = make_float4(e0,e1,e2,se);
}

// ---------------- bitonic sort of 64 (d, idx) pairs across lanes, ascending ----------------
__device__ __forceinline__ void bitonic64(float& d, int& m, int l){
  #pragma unroll
  for(int k=2;k<=64;k<<=1){
    #pragma unroll
    for(int j=k>>1;j>0;j>>=1){
      float pd = __shfl_xor(d, j);
      int pm = __shfl_xor(m, j);
      bool pLess = (pd < d);
      bool dirUp = ((l & k) == 0);
      bool lower = ((l & j) == 0);
      bool take = dirUp ? (lower ? pLess : !pLess) : (lower ? !pLess : pLess);
      if(take){ d = pd; m = pm; }
    }
  }
}

// ---------------- streaming wave top-32 (sorted list in lanes 0..31) ----------------
__device__ __forceinline__ void topk_stream(float d, int m, int l, float& lv, int& li){
  unsigned long long mask = __ballot(d < rlane(lv, 31));
  while(mask){
    int s = __ffsll((unsigned long long)mask) - 1;
    float cd = __shfl(d, s);
    int cm = __shfl(m, s);
    unsigned long long less = __ballot(lv < cd);
    int pos = __popcll(less & 0xffffffffULL);
    float uv = __shfl_up(lv, 1);
    int ui = __shfl_up(li, 1);
    if(l < 32){
      if(l == pos){ lv = cd; li = cm; }
      else if(l > pos){ lv = uv; li = ui; }
    }
    mask &= mask - 1;
  }
}

__global__ __launch_bounds__(256) void k_knn3(const float4* __restrict__ pnt4, int* __restrict__ idx){
  int l = threadIdx.x&63;
  int q = blockIdx.x*4 + (threadIdx.x>>6);
  int b = q>>12, qr = q&4095;
  const float4* pb = pnt4 + ((size_t)b<<12);
  float4 qv = pb[qr];
  float q0=qv.x, q1=qv.y, q2=qv.z, sqq=qv.w;
  float4 nc = pb[l + 64];          // prefetch batch 1
  float dd; int mm = l;
  {
    float4 c = pb[l];
    float dot = q0*c.x + q1*c.y + q2*c.z;
    dd = (sqq - 2.0f*dot) + c.w;
  }
  bitonic64(dd, mm, l);
  float lv = (l<32) ? dd : 3.4e38f;
  int li = (l<32) ? mm : 0x7fffffff;
  #pragma unroll 4
  for(int j=1;j<64;j++){
    float4 c = nc;
    nc = pb[l + (((j+1)&63)<<6)];
    float dot = q0*c.x + q1*c.y + q2*c.z;
    float d = (sqq - 2.0f*dot) + c.w;
    topk_stream(d, l + (j<<6), l, lv, li);
  }
  if(l < 32) idx[(size_t)q*KK + l] = li;
}

// ---------------- KNN selection from fp16-packed D: 2 candidates per load ----------------
__global__ __launch_bounds__(256) void k_knn_sel(const __half2* __restrict__ D, int* __restrict__ idx){
  int l = threadIdx.x&63;
  int q = blockIdx.x*4 + (threadIdx.x>>6);
  int b = q>>12, qr = q&4095;
  const __half2* row = D + ((size_t)b<<23) + ((size_t)qr<<11);
  __half2 h0 = row[l];
  __half2 nh = row[l + 64];        // prefetch batch 1
  float2 f0 = __half22float2(h0);
  float dmin, dmax; int mmin, mmax;
  if(f0.x <= f0.y){ dmin=f0.x; mmin=2*l;   dmax=f0.y; mmax=2*l+1; }
  else            { dmin=f0.y; mmin=2*l+1; dmax=f0.x; mmax=2*l;   }
  bitonic64(dmin, mmin, l);
  float lv = (l<32) ? dmin : 3.4e38f;
  int li = (l<32) ? mmin : 0x7fffffff;
  topk_stream(dmax, mmax, l, lv, li);
  #pragma unroll 4
  for(int j=1;j<32;j++){
    __half2 h = nh;
    nh = row[l + (((j+1)&31)<<6)];
    float2 g = __half22float2(h);
    int base = 2*(l + (j<<6));
    topk_stream(g.x, base,   l, lv, li);
    topk_stream(g.y, base+1, l, lv, li);
  }
  if(l < 32) idx[(size_t)q*KK + l] = li;
}

// ---------------- gaussian kernel conv ----------------
__global__ __launch_bounds__(128) void k_gauss(const float* __restrict__ pts, const float* __restrict__ sqp,
                                               const int* __restrict__ idxP, const float* __restrict__ cen,
                                               float* __restrict__ kout){
  __shared__ float nbx[KK], nby[KK], nbz[KK], nsq[KK];
  int p = blockIdx.x; int b = p>>12; int t = threadIdx.x;
  if(t < KK){
    int id = idxP[(size_t)p*KK + t] + (b<<12);
    nbx[t]=pts[id*3]; nby[t]=pts[id*3+1]; nbz[t]=pts[id*3+2];
    nsq[t]=sqp[id];
  }
  __syncthreads();
  float c0=cen[t*3], c1=cen[t*3+1], c2=cen[t*3+2];
  float sqc=(c0*c0+c1*c1)+c2*c2;
  float acc=0.f;
  #pragma unroll
  for(int k=0;k<KK;k++){
    float dot = nbx[k]*c0 + nby[k]*c1 + nbz[k]*c2;
    float d = (nsq[k] - 2.0f*dot) + sqc;
    acc += __expf(-0.5f*d);
  }
  kout[(size_t)((b<<7)+t)*4096 + (p&4095)] = acc;
}

// ---------------- finalize BN stats ----------------
__global__ void k_fin(const float* __restrict__ psum, const float* __restrict__ psq, int NW, int C, float Nn,
                      const float* __restrict__ g, const float* __restrict__ be,
                      float* __restrict__ sc, float* __restrict__ sh){
  int o = blockIdx.x, t = threadIdx.x;
  float s=0.f, q=0.f;
  for(int w=t; w<NW; w+=256){ s += psum[(size_t)w*C+o]; q += psq[(size_t)w*C+o]; }
  __shared__ float ls[256], lq[256];
  ls[t]=s; lq[t]=q; __syncthreads();
  for(int st=128; st; st>>=1){ if(t<st){ ls[t]+=ls[t+st]; lq[t]+=lq[t+st]; } __syncthreads(); }
  if(t==0){
    float mu = ls[0]/Nn;
    float var = lq[0]/Nn - mu*mu; if(var<0.f) var=0.f;
    float s1 = g[o]*rsqrtf(var + EPSB);
    sc[o]=s1; sh[o]=be[o]-mu*s1;
  }
}

// ---------------- edge-conv 1 BN1 stats via feature moments ----------------
__global__ __launch_bounds__(256) void k_ec1mom(const float* __restrict__ xe0, const int* __restrict__ idx1,
                                                float* __restrict__ pmom){
  int tid = blockIdx.x*256 + threadIdx.x;      // < 131072
  int l = threadIdx.x & 63;
  int wid = tid >> 6;                           // < 2048
  float a[27];
  #pragma unroll
  for(int v=0;v<27;v++) a[v]=0.f;
  #pragma unroll
  for(int u=0;u<2;u++){
    int s = tid*2 + u;
    int p = s>>5;
    int bb = (p>>12)<<12;
    int id = bb + idx1[s];
    const float* nb = xe0 + (size_t)id*3;
    const float* xc = xe0 + (size_t)p*3;
    float f[6];
    f[0]=nb[0]-xc[0]; f[1]=nb[1]-xc[1]; f[2]=nb[2]-xc[2];
    f[3]=xc[0]; f[4]=xc[1]; f[5]=xc[2];
    int v=0;
    #pragma unroll
    for(int i=0;i<6;i++){
      #pragma unroll
      for(int j=i;j<6;j++){ a[v] = fmaf(f[i], f[j], a[v]); v++; }
    }
    #pragma unroll
    for(int i=0;i<6;i++) a[21+i] += f[i];
  }
  #pragma unroll
  for(int v=0;v<27;v++){
    float t = a[v];
    #pragma unroll
    for(int off=32; off; off>>=1) t += __shfl_xor(t, off);
    if(l==0) pmom[v*2048 + wid] = t;
  }
}

__global__ void k_msum(const float* __restrict__ pmom, float* __restrict__ mom){
  int v = blockIdx.x; int t = threadIdx.x;
  float s=0.f;
  for(int i=t;i<2048;i+=256) s += pmom[v*2048+i];
  __shared__ float ls[256];
  ls[t]=s; __syncthreads();
  for(int st=128; st; st>>=1){ if(t<st) ls[t]+=ls[t+st]; __syncthreads(); }
  if(t==0) mom[v]=ls[0];
}

__global__ void k_ec1bn(const float* __restrict__ mom, const float* __restrict__ w1,
                        const float* __restrict__ g, const float* __restrict__ be,
                        float* __restrict__ sc, float* __restrict__ sh){
  __shared__ float M[27];
  int t = threadIdx.x;
  if(t<27) M[t]=mom[t];
  __syncthreads();
  if(t<64){
    float w[6];
    #pragma unroll
    for(int c=0;c<6;c++) w[c]=w1[t*6+c];
    float qf=0.f, m1=0.f;
    int v=0;
    #pragma unroll
    for(int i=0;i<6;i++){
      #pragma unroll
      for(int j=i;j<6;j++){ qf += (i==j?1.f:2.f)*w[i]*w[j]*M[v]; v++; }
    }
    #pragma unroll
    for(int i=0;i<6;i++) m1 += w[i]*M[21+i];
    float N = 262144.f;
    float mu = m1/N;
    float var = qf/N - mu*mu; if(var<0.f) var=0.f;
    float s1 = g[t]*rsqrtf(var + EPSB);
    sc[t]=s1; sh[t]=be[t]-mu*s1;
  }
}

// ---------------- edge-conv 1 fused ----------------
__global__ __launch_bounds__(256) void k_ec1g2(const float* __restrict__ xe0, const int* __restrict__ idx1,
                                               const float* __restrict__ w1, const float* __restrict__ w2T,
                                               const float* __restrict__ s1, const float* __restrict__ t1,
                                               float* __restrict__ h2m, float* __restrict__ psum,
                                               float* __restrict__ psq){
  __shared__ float As[64*64];
  __shared__ float Bs[64*132];
  __shared__ float feat[6][128];
  __shared__ float w1l[384];
  int t = threadIdx.x;
  int blk = blockIdx.x;
  int s0 = blk*128;
  int pbase = s0>>5;
  int bb = (s0>>17)<<12;
  #pragma unroll
  for(int i=0;i<16;i++) As[t + i*256] = w2T[t + i*256];
  for(int i=t; i<384; i+=256) w1l[i] = w1[i];
  if(t < 128){
    int s = s0 + t;
    int p = pbase + (t>>5);
    int id = bb + idx1[s];
    const float* nb = xe0 + (size_t)id*3;
    const float* xc = xe0 + (size_t)p*3;
    float x0 = xc[0], x1 = xc[1], x2 = xc[2];
    feat[0][t] = nb[0]-x0; feat[1][t] = nb[1]-x1; feat[2][t] = nb[2]-x2;
    feat[3][t] = x0; feat[4][t] = x1; feat[5][t] = x2;
  }
  __syncthreads();
  #pragma unroll
  for(int i=0;i<32;i++){
    int e = t + (i<<8);
    int k = e>>7, n = e&127;
    float h = w1l[k*6+0]*feat[0][n] + w1l[k*6+1]*feat[1][n] + w1l[k*6+2]*feat[2][n]
            + w1l[k*6+3]*feat[3][n] + w1l[k*6+4]*feat[4][n] + w1l[k*6+5]*feat[5][n];
    Bs[k*132 + n] = lrelu(fmaf(h, s1[k], t1[k]));
  }
  __syncthreads();
  int tx = t&15, ty = t>>4;
  float acc[4][8];
  #pragma unroll
  for(int i=0;i<4;i++){
    #pragma unroll
    for(int j=0;j<8;j++) acc[i][j]=0.f;
  }
  #pragma unroll 4
  for(int k=0;k<64;k++){
    float4 a  = *(const float4*)&As[k*64 + ty*4];
    float4 b0 = *(const float4*)&Bs[k*132 + tx*4];
    float4 b1 = *(const float4*)&Bs[k*132 + 64 + tx*4];
    float av[4] = {a.x,a.y,a.z,a.w};
    float bv[8] = {b0.x,b0.y,b0.z,b0.w,b1.x,b1.y,b1.z,b1.w};
    #pragma unroll
    for(int i=0;i<4;i++){
      #pragma unroll
      for(int j=0;j<8;j++) acc[i][j] = fmaf(av[i], bv[j], acc[i][j]);
    }
  }
  #pragma unroll
  for(int i=0;i<4;i++){
    int m = ty*4 + i;
    float sr = ((acc[i][0]+acc[i][1])+(acc[i][2]+acc[i][3])) + ((acc[i][4]+acc[i][5])+(acc[i][6]+acc[i][7]));
    float sq = ((acc[i][0]*acc[i][0]+acc[i][1]*acc[i][1])+(acc[i][2]*acc[i][2]+acc[i][3]*acc[i][3]))
             + ((acc[i][4]*acc[i][4]+acc[i][5]*acc[i][5])+(acc[i][6]*acc[i][6]+acc[i][7]*acc[i][7]));
    #pragma unroll
    for(int off=1; off<16; off<<=1){ sr += __shfl_xor(sr, off); sq += __shfl_xor(sq, off); }
    if(tx==0){ psum[(size_t)blk*64+m]=sr; psq[(size_t)blk*64+m]=sq; }
    float m0 = fmaxf(fmaxf(acc[i][0],acc[i][1]), fmaxf(acc[i][2],acc[i][3]));
    float m1 = fmaxf(fmaxf(acc[i][4],acc[i][5]), fmaxf(acc[i][6],acc[i][7]));
    #pragma unroll
    for(int off=1; off<8; off<<=1){ m0 = fmaxf(m0, __shfl_xor(m0, off)); m1 = fmaxf(m1, __shfl_xor(m1, off)); }
    if((tx&7)==0){
      int pl = pbase + (tx>>3);
      h2m[(size_t)pl*64 + m]     = m0;
      h2m[(size_t)(pl+2)*64 + m] = m1;
    }
  }
}

// ---------------- ec1 finalize ----------------
__global__ __launch_bounds__(256) void k_ec1fin(const float* __restrict__ h2m, const float* __restrict__ s2,
                                                const float* __restrict__ t2, float* __restrict__ xe1,
                                                float* __restrict__ xe1T, float* __restrict__ sqx){
  int gid = blockIdx.x*256 + threadIdx.x;  // < NP*64
  int p = gid>>6, l = gid&63;
  float v = lrelu(fmaf(h2m[(size_t)p*64+l], s2[l], t2[l]));
  xe1[(size_t)p*64+l] = v;
  int b=p>>12, pr=p&4095;
  xe1T[(size_t)(b*64+l)*4096 + pr] = v;
  float sq = v*v;
  #pragma unroll
  for(int off=32; off; off>>=1) sq += __shfl_xor(sq, off);
  if(l==0) sqx[p]=sq;
}

// ---------------- D (fp16) via bf16 MFMA: block (mb,nb,b); writes transposed (D symmetric) ----------------
__global__ __launch_bounds__(256) void k_dgemm_m(const short* __restrict__ X, const float* __restrict__ sqx,
                                                 __half* __restrict__ D){
  __shared__ short sA[8192], sB[8192];
  int t = threadIdx.x;
  int lane = t&63, w = t>>6;
  int wm4 = (w>>1)*4, wn4 = (w&1)*4;
  int mb = blockIdx.y, nb = blockIdx.x, b = blockIdx.z;
  const short* AG = X + (size_t)(b*32 + mb)*8192;
  const short* BG = X + (size_t)(b*32 + nb)*8192;
  #pragma unroll
  for(int i=0;i<4;i++){
    int slot = t + i*256;
    *(s8v*)&sA[slot*8] = *(const s8v*)&AG[slot*8];
    *(s8v*)&sB[slot*8] = *(const s8v*)&BG[slot*8];
  }
  __syncthreads();
  f4v acc[4][4];
  #pragma unroll
  for(int i=0;i<4;i++){
    #pragma unroll
    for(int j=0;j<4;j++) acc[i][j] = (f4v)(0.f);
  }
  #pragma unroll
  for(int kh=0;kh<2;kh++){
    s8v av[4], bv[4];
    #pragma unroll
    for(int f=0;f<4;f++) av[f] = *(const s8v*)&sA[(kh*8 + wm4 + f)*512 + lane*8];
    #pragma unroll
    for(int f=0;f<4;f++) bv[f] = *(const s8v*)&sB[(kh*8 + wn4 + f)*512 + lane*8];
    #pragma unroll
    for(int fm=0;fm<4;fm++){
      #pragma unroll
      for(int fn=0;fn<4;fn++)
        acc[fm][fn] = __builtin_amdgcn_mfma_f32_16x16x32_bf16(av[fm], bv[fn], acc[fm][fn], 0, 0, 0);
    }
  }
  const float* sb = sqx + (b<<12);
  __half* Db = D + ((size_t)b<<24);
  int l15 = lane&15, l4 = (lane>>4)*4;
  #pragma unroll
  for(int fm=0;fm<4;fm++){
    int m0 = mb*128 + wm4*16 + fm*16 + l4;
    float sm0 = sb[m0], sm1 = sb[m0+1], sm2 = sb[m0+2], sm3 = sb[m0+3];
    #pragma unroll
    for(int fn=0;fn<4;fn++){
      int n = nb*128 + wn4*16 + fn*16 + l15;
      float sqn = sb[n];
      __half2 h01 = __floats2half2_rn((sm0 + sqn) - 2.f*acc[fm][fn][0],
                                      (sm1 + sqn) - 2.f*acc[fm][fn][1]);
      __half2 h23 = __floats2half2_rn((sm2 + sqn) - 2.f*acc[fm][fn][2],
                                      (sm3 + sqn) - 2.f*acc[fm][fn][3]);
      __half2* p = (__half2*)&Db[(size_t)n*4096 + m0];
      p[0] = h01; p[1] = h23;
    }
  }
}

// ---------------- edge-conv 2 pass 1 (bf16 MFMA gather-GEMM) ----------------
__global__ __launch_bounds__(256) void k_ec2m1(const float* __restrict__ xe1, const int* __restrict__ idx2,
                                               const short* __restrict__ wb, float* __restrict__ h1,
                                               float* __restrict__ psum, float* __restrict__ psq){
  __shared__ short sA[8192], sB[8192];
  __shared__ float cts[4][64];
  __shared__ int nid[128];
  __shared__ float srs[2][128], srq[2][128];
  int t = threadIdx.x;
  int blk = blockIdx.x;
  int s0 = blk*128;
  int pbase = s0>>5;
  int bb = (s0>>17)<<12;
  if(t<128) nid[t] = (idx2[s0+t] + bb)<<6;
  cts[t>>6][t&63] = xe1[(size_t)(pbase + (t>>6))*64 + (t&63)];
  int lane = t&63, w = t>>6;
  int wm4 = (w>>1)*4, wn4 = (w&1)*4;
  f4v acc[4][4];
  #pragma unroll
  for(int i=0;i<4;i++){
    #pragma unroll
    for(int j=0;j<4;j++) acc[i][j] = (f4v)(0.f);
  }
  for(int st=0; st<2; ++st){
    __syncthreads();
    #pragma unroll
    for(int i=0;i<4;i++){
      int slot = t + i*256;
      *(s8v*)&sA[slot*8] = *(const s8v*)&wb[st*8192 + slot*8];
      int chunk = slot>>6, li = slot&63;
      int n = (chunk&7)*16 + (li&15);
      int c = ((chunk>>3)<<5) + ((li>>4)<<3);
      float v[8];
      if(st==0){
        const float* src = xe1 + nid[n] + c;
        float4 a0 = *(const float4*)src;
        float4 a1 = *(const float4*)(src+4);
        const float* cc = &cts[n>>5][c];
        float4 c0 = *(const float4*)cc;
        float4 c1 = *(const float4*)(cc+4);
        v[0]=a0.x-c0.x; v[1]=a0.y-c0.y; v[2]=a0.z-c0.z; v[3]=a0.w-c0.w;
        v[4]=a1.x-c1.x; v[5]=a1.y-c1.y; v[6]=a1.z-c1.z; v[7]=a1.w-c1.w;
      } else {
        const float* cc = &cts[n>>5][c];
        float4 c0 = *(const float4*)cc;
        float4 c1 = *(const float4*)(cc+4);
        v[0]=c0.x; v[1]=c0.y; v[2]=c0.z; v[3]=c0.w;
        v[4]=c1.x; v[5]=c1.y; v[6]=c1.z; v[7]=c1.w;
      }
      s8v r;
      #pragma unroll
      for(int j=0;j<8;j++) r[j] = f2bf(v[j]);
      *(s8v*)&sB[slot*8] = r;
    }
    __syncthreads();
    #pragma unroll
    for(int kh=0;kh<2;kh++){
      s8v av[4], bv[4];
      #pragma unroll
      for(int f=0;f<4;f++) av[f] = *(const s8v*)&sA[(kh*8 + wm4 + f)*512 + lane*8];
      #pragma unroll
      for(int f=0;f<4;f++) bv[f] = *(const s8v*)&sB[(kh*8 + wn4 + f)*512 + lane*8];
      #pragma unroll
      for(int fm=0;fm<4;fm++){
        #pragma unroll
        for(int fn=0;fn<4;fn++)
          acc[fm][fn] = __builtin_amdgcn_mfma_f32_16x16x32_bf16(av[fm], bv[fn], acc[fm][fn], 0, 0, 0);
      }
    }
  }
  int l15 = lane&15, l4 = (lane>>4)<<2;
  #pragma unroll
  for(int fm=0;fm<4;fm++){
    int mb_ = wm4*16 + fm*16 + l4;
    #pragma unroll
    for(int fn=0;fn<4;fn++){
      int n = wn4*16 + fn*16 + l15;
      *(float4*)&h1[(size_t)(s0+n)*128 + mb_] =
        make_float4(acc[fm][fn][0], acc[fm][fn][1], acc[fm][fn][2], acc[fm][fn][3]);
    }
    #pragma unroll
    for(int r=0;r<4;r++){
      float sr = (acc[fm][0][r]+acc[fm][1][r]) + (acc[fm][2][r]+acc[fm][3][r]);
      float sq = (acc[fm][0][r]*acc[fm][0][r]+acc[fm][1][r]*acc[fm][1][r])
               + (acc[fm][2][r]*acc[fm][2][r]+acc[fm][3][r]*acc[fm][3][r]);
      #pragma unroll
      for(int off=1; off<16; off<<=1){ sr += __shfl_xor(sr, off); sq += __shfl_xor(sq, off); }
      if(l15==0){ srs[w&1][mb_+r] = sr; srq[w&1][mb_+r] = sq; }
    }
  }
  __syncthreads();
  if(t<128){
    psum[(size_t)blk*128+t] = srs[0][t]+srs[1][t];
    psq[(size_t)blk*128+t]  = srq[0][t]+srq[1][t];
  }
}

// ---------------- edge-conv 2 pass 2 (bf16 MFMA, fused BN1+lrelu, stats + per-point max) ----------------
__global__ __launch_bounds__(256) void k_ec2m2(const float* __restrict__ h1, const short* __restrict__ wb,
                                               const float* __restrict__ s1, const float* __restrict__ t1,
                                               float* __restrict__ h2max, float* __restrict__ psum,
                                               float* __restrict__ psq){
  __shared__ short sA[8192], sB[8192];
  __shared__ float bnS[128], bnT[128];
  __shared__ float srs[2][128], srq[2][128];
  int t = threadIdx.x;
  int blk = blockIdx.x;
  int s0 = blk*128;
  int pbase = s0>>5;
  if(t<128){ bnS[t]=s1[t]; bnT[t]=t1[t]; }
  int lane = t&63, w = t>>6;
  int wm4 = (w>>1)*4, wn4 = (w&1)*4;
  f4v acc[4][4];
  #pragma unroll
  for(int i=0;i<4;i++){
    #pragma unroll
    for(int j=0;j<4;j++) acc[i][j] = (f4v)(0.f);
  }
  for(int st=0; st<2; ++st){
    __syncthreads();
    #pragma unroll
    for(int i=0;i<4;i++){
      int slot = t + i*256;
      *(s8v*)&sA[slot*8] = *(const s8v*)&wb[st*8192 + slot*8];
      int chunk = slot>>6, li = slot&63;
      int n = (chunk&7)*16 + (li&15);
      int c = st*64 + ((chunk>>3)<<5) + ((li>>4)<<3);
      const float* src = h1 + (size_t)(s0+n)*128 + c;
      float4 a0 = *(const float4*)src;
      float4 a1 = *(const float4*)(src+4);
      float v[8] = {a0.x,a0.y,a0.z,a0.w,a1.x,a1.y,a1.z,a1.w};
      s8v r;
      #pragma unroll
      for(int j=0;j<8;j++) r[j] = f2bf(lrelu(fmaf(v[j], bnS[c+j], bnT[c+j])));
      *(s8v*)&sB[slot*8] = r;
    }
    __syncthreads();
    #pragma unroll
    for(int kh=0;kh<2;kh++){
      s8v av[4], bv[4];
      #pragma unroll
      for(int f=0;f<4;f++) av[f] = *(const s8v*)&sA[(kh*8 + wm4 + f)*512 + lane*8];
      #pragma unroll
      for(int f=0;f<4;f++) bv[f] = *(const s8v*)&sB[(kh*8 + wn4 + f)*512 + lane*8];
      #pragma unroll
      for(int fm=0;fm<4;fm++){
        #pragma unroll
        for(int fn=0;fn<4;fn++)
          acc[fm][fn] = __builtin_amdgcn_mfma_f32_16x16x32_bf16(av[fm], bv[fn], acc[fm][fn], 0, 0, 0);
      }
    }
  }
  int l15 = lane&15, l4 = (lane>>4)<<2;
  int pp0 = wn4>>1;
  #pragma unroll
  for(int fm=0;fm<4;fm++){
    int mb_ = wm4*16 + fm*16 + l4;
    #pragma unroll
    for(int r=0;r<4;r++){
      float sr = (acc[fm][0][r]+acc[fm][1][r]) + (acc[fm][2][r]+acc[fm][3][r]);
      float sq = (acc[fm][0][r]*acc[fm][0][r]+acc[fm][1][r]*acc[fm][1][r])
               + (acc[fm][2][r]*acc[fm][2][r]+acc[fm][3][r]*acc[fm][3][r]);
      float m0 = fmaxf(acc[fm][0][r], acc[fm][1][r]);
      float m1 = fmaxf(acc[fm][2][r], acc[fm][3][r]);
      #pragma unroll
      for(int off=1; off<16; off<<=1){ sr += __shfl_xor(sr, off); sq += __shfl_xor(sq, off); }
      #pragma unroll
      for(int off=1; off<16; off<<=1){ m0 = fmaxf(m0, __shfl_xor(m0, off)); m1 = fmaxf(m1, __shfl_xor(m1, off)); }
      if(l15==0){
        srs[w&1][mb_+r] = sr; srq[w&1][mb_+r] = sq;
        h2max[(size_t)(pbase+pp0)*128   + mb_+r] = m0;
        h2max[(size_t)(pbase+pp0+1)*128 + mb_+r] = m1;
      }
    }
  }
  __syncthreads();
  if(t<128){
    psum[(size_t)blk*128+t] = srs[0][t]+srs[1][t];
    psq[(size_t)blk*128+t]  = srq[0][t]+srq[1][t];
  }
}

// ---------------- xe2 = lrelu(BN(h2max)) in-place ----------------
__global__ void k_xe2fin(float* __restrict__ xe2, const float* __restrict__ s2, const float* __restrict__ t2){
  int i = blockIdx.x*256 + threadIdx.x;   // < NP*128
  if(i >= NP*128) return;
  int o = i&127;
  xe2[i] = lrelu(fmaf(xe2[i], s2[o], t2[o]));
}

// ---------------- generic small transpose ----------------
__global__ void k_transpose(const float* __restrict__ w, float* __restrict__ wT, int O, int C){
  int i = blockIdx.x*256 + threadIdx.x;
  if(i >= O*C) return;
  int o = i / C, c = i % C;
  wT[(size_t)c*O + o] = w[i];
}

// ---------------- weight fp32 -> bf16 fragment-linear ----------------
__global__ void k_wprep(const float* __restrict__ w, short* __restrict__ wb, int M, int K){
  int tid = blockIdx.x*256 + threadIdx.x;
  int m = tid % M, kb8 = tid / M;
  int k0 = kb8*8;
  float4 v0 = *(const float4*)&w[(size_t)m*K + k0];
  float4 v1 = *(const float4*)&w[(size_t)m*K + k0 + 4];
  s8v r;
  r[0]=f2bf(v0.x); r[1]=f2bf(v0.y); r[2]=f2bf(v0.z); r[3]=f2bf(v0.w);
  r[4]=f2bf(v1.x); r[5]=f2bf(v1.y); r[6]=f2bf(v1.z); r[7]=f2bf(v1.w);
  int region = (m>>7)*(K>>6) + (k0>>6);
  int chunk = ((kb8>>2)&1)*8 + ((m>>4)&7);
  int lane = (kb8&3)*16 + (m&15);
  *(s8v*)&wb[(size_t)region*8192 + chunk*512 + lane*8] = r;
}

// ---------------- activations -> bf16 fragment-linear ----------------
__global__ void k_bprep(const float* __restrict__ in, const float* __restrict__ sc, const float* __restrict__ sh,
                        short* __restrict__ ob, int K){
  int tid = blockIdx.x*256 + threadIdx.x;
  int n = tid & 8191, kb8 = tid >> 13;
  int k0 = kb8*8;
  int b = n>>12, s = n&4095;
  const float* ib = in + ((size_t)b*K + k0)*4096 + s;
  float v[8];
  #pragma unroll
  for(int j=0;j<8;j++) v[j] = ib[(size_t)j*4096];
  if(sc){
    #pragma unroll
    for(int j=0;j<8;j++) v[j] = lrelu(fmaf(v[j], sc[k0+j], sh[k0+j]));
  }
  s8v r;
  #pragma unroll
  for(int j=0;j<8;j++) r[j] = f2bf(v[j]);
  int region = (n>>7)*(K>>6) + (k0>>6);
  int chunk = ((kb8>>2)&1)*8 + ((n>>4)&7);
  int lane = (kb8&3)*16 + (n&15);
  *(s8v*)&ob[(size_t)region*8192 + chunk*512 + lane*8] = r;
}

// ---------------- layer-1 activations: read [xe2-flat ; kr] directly ----------------
__global__ void k_bprep1(const float* __restrict__ xe2, const float* __restrict__ kr,
                         short* __restrict__ ob){
  int tid = blockIdx.x*256 + threadIdx.x;   // < 8192*256/8
  int n = tid & 8191, kb8 = tid >> 13;
  int k0 = kb8*8;
  int b = n>>12, s = n&4095;
  const float* ib;
  if(k0 < 128) ib = xe2 + (size_t)b*524288 + (size_t)k0*4096 + s;
  else         ib = kr + ((size_t)(b*128 + (k0-128)))*4096 + s;
  float v[8];
  #pragma unroll
  for(int j=0;j<8;j++) v[j] = ib[(size_t)j*4096];
  s8v r;
  #pragma unroll
  for(int j=0;j<8;j++) r[j] = f2bf(v[j]);
  int region = (n>>7)*4 + (k0>>6);
  int chunk = ((kb8>>2)&1)*8 + ((n>>4)&7);
  int lane = (kb8&3)*16 + (n&15);
  *(s8v*)&ob[(size_t)region*8192 + chunk*512 + lane*8] = r;
}

// ---------------- bf16 MFMA GEMM ----------------
__global__ __launch_bounds__(256) void k_gmm(const short* __restrict__ A, const short* __restrict__ B,
                                             float* __restrict__ out, int M, int K){
  __shared__ short sA[8192], sB[8192];
  int t = threadIdx.x;
  int lane = t&63;
  int w = t>>6;
  int wm4 = (w>>1)*4, wn4 = (w&1)*4;
  int mb = blockIdx.y, nb = blockIdx.x;
  int ksteps = K>>6;
  const short* AG = A + (size_t)mb*ksteps*8192;
  const short* BG = B + (size_t)nb*ksteps*8192;
  f4v acc[4][4];
  #pragma unroll
  for(int i=0;i<4;i++){
    #pragma unroll
    for(int j=0;j<4;j++) acc[i][j] = (f4v)(0.f);
  }
  for(int st=0; st<ksteps; ++st){
    __syncthreads();
    #pragma unroll
    for(int i=0;i<4;i++){
      int slot = t + i*256;
      *(s8v*)&sA[slot*8] = *(const s8v*)&AG[(size_t)st*8192 + slot*8];
      *(s8v*)&sB[slot*8] = *(const s8v*)&BG[(size_t)st*8192 + slot*8];
    }
    __syncthreads();
    #pragma unroll
    for(int kh=0;kh<2;kh++){
      s8v av[4], bv[4];
      #pragma unroll
      for(int f=0;f<4;f++) av[f] = *(const s8v*)&sA[(kh*8 + wm4 + f)*512 + lane*8];
      #pragma unroll
      for(int f=0;f<4;f++) bv[f] = *(const s8v*)&sB[(kh*8 + wn4 + f)*512 + lane*8];
      #pragma unroll
      for(int fm=0;fm<4;fm++){
        #pragma unroll
        for(int fn=0;fn<4;fn++)
          acc[fm][fn] = __builtin_amdgcn_mfma_f32_16x16x32_bf16(av[fm], bv[fn], acc[fm][fn], 0, 0, 0);
      }
    }
  }
  int l15 = lane&15, l4 = (lane>>4)*4;
  #pragma unroll
  for(int fm=0;fm<4;fm++){
    int mrow = mb*128 + wm4*16 + fm*16 + l4;
    #pragma unroll
    for(int fn=0;fn<4;fn++){
      int n = nb*128 + wn4*16 + fn*16 + l15;
      int b = n>>12, s = n&4095;
      float* ob = out + ((size_t)b*M + mrow)*4096 + s;
      #pragma unroll
      for(int r=0;r<4;r++) ob[(size_t)r*4096] = acc[fm][fn][r];
    }
  }
}

// ---------------- per-channel stats for cbr layers ----------------
__global__ void k_cstats(const float* __restrict__ buf, int C, const float* __restrict__ g,
                         const float* __restrict__ be, float* __restrict__ sc, float* __restrict__ sh){
  int o = blockIdx.x, t = threadIdx.x;
  float s=0.f, q=0.f;
  for(int i=t;i<8192;i+=256){
    int b=i>>12, ss_=i&4095;
    float v = buf[(size_t)(b*C+o)*4096 + ss_];
    s+=v; q+=v*v;
  }
  __shared__ float ls[256], lq[256];
  ls[t]=s; lq[t]=q; __syncthreads();
  for(int st=128; st; st>>=1){ if(t<st){ ls[t]+=ls[t+st]; lq[t]+=lq[t+st]; } __syncthreads(); }
  if(t==0){
    float mu = ls[0]/8192.f;
    float var = lq[0]/8192.f - mu*mu; if(var<0.f) var=0.f;
    float s1 = g[o]*rsqrtf(var + EPSB);
    sc[o]=s1; sh[o]=be[o]-mu*s1;
  }
}

// ---------------- final layer ----------------
__global__ __launch_bounds__(256) void k_final4(const float* __restrict__ c3, const float* __restrict__ w4T,
                                                const float* __restrict__ sc, const float* __restrict__ sh,
                                                float* __restrict__ pmax){
  int b = blockIdx.y, st = blockIdx.x;
  int t = threadIdx.x; int s = st*256 + t;
  float acc[9];
  #pragma unroll
  for(int j=0;j<9;j++) acc[j]=0.f;
  const float* ib = c3 + (size_t)b*256*4096;
  for(int c=0;c<256;c++){
    float x = lrelu(fmaf(ib[(size_t)c*4096+s], sc[c], sh[c]));
    #pragma unroll
    for(int j=0;j<9;j++) acc[j]=fmaf(x, w4T[c*9+j], acc[j]);
  }
  __shared__ float red[256];
  for(int j=0;j<9;j++){
    red[t]=acc[j]; __syncthreads();
    for(int stp=128; stp; stp>>=1){ if(t<stp) red[t]=fmaxf(red[t],red[t+stp]); __syncthreads(); }
    if(t==0) pmax[(b*16+st)*9 + j]=red[0];
    __syncthreads();
  }
}

__global__ void k_out(const float* __restrict__ pmax, float* __restrict__ out){
  int i = threadIdx.x;
  if(i<18){
    int b=i/9, o=i%9;
    float m=-3.4e38f;
    for(int k=0;k<16;k++) m=fmaxf(m, pmax[(b*16+k)*9+o]);
    out[i] = m + ((o==0||o==4||o==8)?1.f:0.f);
  }
}

// ---------------- launch ----------------
extern "C" void kernel_launch(void* const* d_in, const int* in_sizes, int n_in,
                              void* d_out, int out_size, void* d_ws, size_t ws_size,
                              hipStream_t stream){
  const float* x    = (const float*)d_in[0];
  const float* kc   = (const float*)d_in[1];
  const float* e1w1 = (const float*)d_in[2];
  const float* e1g1 = (const float*)d_in[3];
  const float* e1b1 = (const float*)d_in[4];
  const float* e1w2 = (const float*)d_in[5];
  const float* e1g2 = (const float*)d_in[6];
  const float* e1b2 = (const float*)d_in[7];
  const float* e2w1 = (const float*)d_in[8];
  const float* e2g1 = (const float*)d_in[9];
  const float* e2b1 = (const float*)d_in[10];
  const float* e2w2 = (const float*)d_in[11];
  const float* e2g2 = (const float*)d_in[12];
  const float* e2b2 = (const float*)d_in[13];
  const float* w1   = (const float*)d_in[14];
  const float* g1   = (const float*)d_in[15];
  const float* b1   = (const float*)d_in[16];
  const float* w2   = (const float*)d_in[17];
  const float* g2   = (const float*)d_in[18];
  const float* b2   = (const float*)d_in[19];
  const float* w3   = (const float*)d_in[20];
  const float* g3   = (const float*)d_in[21];
  const float* b3   = (const float*)d_in[22];
  const float* w4   = (const float*)d_in[23];

  if(ws_size < 156061696ull) return;
  char* ws = (char*)d_ws;
  float* pts   = (float*)(ws + 0);
  float* xe0   = (float*)(ws + 98304);
  float* sqp   = (float*)(ws + 196608);
  float* sqe   = (float*)(ws + 229376);
  float* sqx1  = (float*)(ws + 262144);
  float* xe1   = (float*)(ws + 294912);
  float* xe1T  = (float*)(ws + 2392064);
  float* xe2   = (float*)(ws + 4489216);
  float* kr    = (float*)(ws + 8683520);
  int*   idxP  = (int*)  (ws + 12877824);
  int*   idx1  = (int*)  (ws + 13926400);
  int*   idx2  = (int*)  (ws + 14974976);
  float* psum  = (float*)(ws + 16023552);
  float* psq   = (float*)(ws + 17072128);
  float* par   = (float*)(ws + 18120704);
  float* pmax  = (float*)(ws + 18153472);
  float* e1w2T = (float*)(ws + 18157568);
  float* wT4   = (float*)(ws + 21827584);
  float* hbuf  = (float*)(ws + 21843968);
  short* wbe1  = (short*)(ws + 0);
  short* wbe2  = (short*)(ws + 65536);
  float4* pts4 = (float4*)(ws + 4489216);
  float4* xe04 = (float4*)(ws + 4489216 + 131072);
  short* actB  = (short*)(ws + 88952832);
  short* xpack = (short*)(ws + 88952832);
  short* wb1   = (short*)(ws + 105730048);
  short* wb2   = (short*)(ws + 106254336);
  short* wb3   = (short*)(ws + 107302912);
  float* pmom  = psum;
  float* momv  = psq;

  float* e1s1 = par+0;    float* e1t1 = par+64;
  float* e1s2 = par+128;  float* e1t2 = par+192;
  float* e2s1 = par+256;  float* e2t1 = par+384;
  float* e2s2 = par+512;  float* e2t2 = par+640;
  float* c1s  = par+768;  float* c1t  = par+1792;
  float* c2s  = par+2816; float* c2t  = par+3328;
  float* c3s  = par+3840; float* c3t  = par+4096;

  float* c1out = hbuf + 2097152;
  float* c2out = hbuf + 10485760;
  float* c3out = hbuf + 14680064;

  hipLaunchKernelGGL(k_prep, dim3(32), dim3(256), 0, stream, x, pts, xe0, sqp, sqe, pts4, xe04);
  hipLaunchKernelGGL(k_knn3, dim3(2048), dim3(256), 0, stream, pts4, idxP);
  hipLaunchKernelGGL(k_knn3, dim3(2048), dim3(256), 0, stream, xe04, idx1);
  hipLaunchKernelGGL(k_gauss, dim3(8192), dim3(128), 0, stream, pts, sqp, idxP, kc, kr);

  // edge-conv 1 (moment-based BN1 stats; h1 never stored)
  hipLaunchKernelGGL(k_transpose, dim3(16), dim3(256), 0, stream, e1w2, e1w2T, 64, 64);
  hipLaunchKernelGGL(k_ec1mom, dim3(512), dim3(256), 0, stream, xe0, idx1, pmom);
  hipLaunchKernelGGL(k_msum, dim3(27), dim3(256), 0, stream, pmom, momv);
  hipLaunchKernelGGL(k_ec1bn, dim3(1), dim3(64), 0, stream, momv, e1w1, e1g1, e1b1, e1s1, e1t1);
  hipLaunchKernelGGL(k_ec1g2, dim3(2048), dim3(256), 0, stream, xe0, idx1, e1w1, e1w2T, e1s1, e1t1, hbuf, psum, psq);
  hipLaunchKernelGGL(k_fin, dim3(64), dim3(256), 0, stream, psum, psq, 2048, 64, 262144.f, e1g2, e1b2, e1s2, e1t2);
  hipLaunchKernelGGL(k_ec1fin, dim3(2048), dim3(256), 0, stream, hbuf, e1s2, e1t2, xe1, xe1T, sqx1);

  // knn on 64-d features: bf16 MFMA distance GEMM (fp16-packed D) + streaming selection
  hipLaunchKernelGGL(k_wprep, dim3(256), dim3(256), 0, stream, xe1, xpack, 8192, 64);
  hipLaunchKernelGGL(k_dgemm_m, dim3(32,32,2), dim3(256), 0, stream, xpack, sqx1, (__half*)hbuf);
  hipLaunchKernelGGL(k_knn_sel, dim3(2048), dim3(256), 0, stream, (const __half2*)hbuf, idx2);

  // edge-conv 2 (bf16 MFMA formulation, fused stats+max)
  hipLaunchKernelGGL(k_wprep, dim3(8), dim3(256), 0, stream, e2w1, wbe1, 128, 128);
  hipLaunchKernelGGL(k_wprep, dim3(8), dim3(256), 0, stream, e2w2, wbe2, 128, 128);
  hipLaunchKernelGGL(k_ec2m1, dim3(2048), dim3(256), 0, stream, xe1, idx2, wbe1, hbuf, psum, psq);
  hipLaunchKernelGGL(k_fin, dim3(128), dim3(256), 0, stream, psum, psq, 2048, 128, 262144.f, e2g1, e2b1, e2s1, e2t1);
  hipLaunchKernelGGL(k_ec2m2, dim3(2048), dim3(256), 0, stream, hbuf, wbe2, e2s1, e2t1, xe2, psum, psq);
  hipLaunchKernelGGL(k_fin, dim3(128), dim3(256), 0, stream, psum, psq, 2048, 128, 262144.f, e2g2, e2b2, e2s2, e2t2);
  hipLaunchKernelGGL(k_xe2fin, dim3(4096), dim3(256), 0, stream, xe2, e2s2, e2t2);

  // bf16 MFMA cbr chain (hcat fused into k_bprep1)
  hipLaunchKernelGGL(k_wprep, dim3(128), dim3(256), 0, stream, w1, wb1, 1024, 256);
  hipLaunchKernelGGL(k_wprep, dim3(256), dim3(256), 0, stream, w2, wb2, 512, 1024);
  hipLaunchKernelGGL(k_wprep, dim3(64),  dim3(256), 0, stream, w3, wb3, 256, 512);
  hipLaunchKernelGGL(k_transpose, dim3((9*256+255)/256), dim3(256), 0, stream, w4, wT4, 9, 256);

  hipLaunchKernelGGL(k_bprep1, dim3(1024), dim3(256), 0, stream, xe2, kr, actB);
  hipLaunchKernelGGL(k_gmm, dim3(64,8), dim3(256), 0, stream, wb1, actB, c1out, 1024, 256);
  hipLaunchKernelGGL(k_cstats, dim3(1024), dim3(256), 0, stream, c1out, 1024, g1, b1, c1s, c1t);

  hipLaunchKernelGGL(k_bprep, dim3(4096), dim3(256), 0, stream, c1out, c1s, c1t, actB, 1024);
  hipLaunchKernelGGL(k_gmm, dim3(64,4), dim3(256), 0, stream, wb2, actB, c2out, 512, 1024);
  hipLaunchKernelGGL(k_cstats, dim3(512), dim3(256), 0, stream, c2out, 512, g2, b2, c2s, c2t);

  hipLaunchKernelGGL(k_bprep, dim3(2048), dim3(256), 0, stream, c2out, c2s, c2t, actB, 512);
  hipLaunchKernelGGL(k_gmm, dim3(64,2), dim3(256), 0, stream, wb3, actB, c3out, 256, 512);
  hipLaunchKernelGGL(k_cstats, dim3(256), dim3(256), 0, stream, c3out, 256, g3, b3, c3s, c3t);

  hipLaunchKernelGGL(k_final4, dim3(16,2), dim3(256), 0, stream, c3out, wT4, c3s, c3t, pmax);
  hipLaunchKernelGGL(k_out, dim3(1), dim3(32), 0, stream, pmax, (float*)d_out);
}

// Round 20
// 543.397 us; speedup vs baseline: 1.2210x; 1.1551x over previous
//
#include <hip/hip_runtime.h>
#include <hip/hip_fp16.h>
#include <math.h>

#define WN 4096
#define NP 8192
#define KK 32
#define EPSB 1e-5f

typedef __attribute__((ext_vector_type(8))) short s8v;
typedef __attribute__((ext_vector_type(4))) float f4v;

__device__ __forceinline__ float lrelu(float x){ return fmaxf(x, 0.01f*x); }
__device__ __forceinline__ float rlane(float v, int c){
  return __int_as_float(__builtin_amdgcn_readlane(__float_as_int(v), c));
}
__device__ __forceinline__ short f2bf(float f){
  unsigned u = __float_as_uint(f);
  u = (u + 0x7fffu + ((u>>16)&1u)) >> 16;
  return (short)u;
}

// ---------------- prep ----------------
__global__ void k_prep(const float* __restrict__ x, float* __restrict__ pts, float* __restrict__ xe0,
                       float* __restrict__ sqp, float* __restrict__ sqe,
                       float4* __restrict__ pts4, float4* __restrict__ xe04){
  int i = blockIdx.x*256 + threadIdx.x;
  if(i >= NP) return;
  int b = i>>12, p = i&4095;
  const float* xb = x + b*12288;
  float a0 = xb[p], a1 = xb[4096+p], a2 = xb[8192+p];
  pts[i*3+0]=a0; pts[i*3+1]=a1; pts[i*3+2]=a2;
  float sp = (a0*a0 + a1*a1) + a2*a2;
  sqp[i] = sp;
  pts4[i] = make_float4(a0,a1,a2,sp);
  float e0 = xb[p*3+0], e1 = xb[p*3+1], e2 = xb[p*3+2];
  xe0[i*3+0]=e0; xe0[i*3+1]=e1; xe0[i*3+2]=e2;
  float se = (e0*e0 + e1*e1) + e2*e2;
  sqe[i] = se;
  xe04[i] = make_float4(e0,e1,e2,se);
}

// ---------------- bitonic sort of 64 (d, idx) pairs across lanes, ascending ----------------
__device__ __forceinline__ void bitonic64(float& d, int& m, int l){
  #pragma unroll
  for(int k=2;k<=64;k<<=1){
    #pragma unroll
    for(int j=k>>1;j>0;j>>=1){
      float pd = __shfl_xor(d, j);
      int pm = __shfl_xor(m, j);
      bool pLess = (pd < d);
      bool dirUp = ((l & k) == 0);
      bool lower = ((l & j) == 0);
      bool take = dirUp ? (lower ? pLess : !pLess) : (lower ? !pLess : pLess);
      if(take){ d = pd; m = pm; }
    }
  }
}

// ---------------- merge sorted list (lanes 0..31) with LDS reservoir (cnt entries) ----------------
__device__ __forceinline__ void kmerge(const float2* __restrict__ buf, int cnt, int l,
                                       float& lv, int& li){
  __builtin_amdgcn_wave_barrier();       // ensure buffered ds_writes are ordered before reads
  float md; int mi;
  if(l < 32){ md = lv; mi = li; }
  else{
    int i = l - 32;
    if(i < cnt){ float2 e = buf[i]; md = e.x; mi = __float_as_int(e.y); }
    else{ md = 3.4e38f; mi = 0x7fffffff; }
  }
  bitonic64(md, mi, l);
  if(l < 32){ lv = md; li = mi; }
}

// ---------------- buffered streaming top-32 insert (reservoir; exact) ----------------
// thr only tightens at merges; d >= thr is always a safe reject.
__device__ __forceinline__ void topk_buf(float d, int m, int l, float2* __restrict__ buf,
                                         int& cnt, float& thr, float& lv, int& li){
  bool alive = d < thr;
  unsigned long long mask = __ballot(alive);
  while(mask){
    int nsurv = __popcll(mask);
    int space = 32 - cnt;                      // cnt in [0,31] here -> space >= 1
    int prefix = __popcll(mask & ((1ull<<l)-1ull));
    bool store = alive && (prefix < space);
    if(store) buf[cnt + prefix] = make_float2(d, __int_as_float(m));
    cnt += (nsurv < space) ? nsurv : space;
    alive = alive && !store;
    if(cnt == 32){
      kmerge(buf, 32, l, lv, li);
      cnt = 0;
      thr = rlane(lv, 31);
      alive = alive && (d < thr);
    }
    mask = __ballot(alive);
  }
}

// ---------------- KNN on 3-D points (reservoir selection) ----------------
__global__ __launch_bounds__(256) void k_knn3(const float4* __restrict__ pnt4, int* __restrict__ idx){
  __shared__ float2 bufs[4][32];
  int l = threadIdx.x&63;
  int wid = threadIdx.x>>6;
  int q = blockIdx.x*4 + wid;
  int b = q>>12, qr = q&4095;
  const float4* pb = pnt4 + ((size_t)b<<12);
  float2* buf = bufs[wid];
  float4 qv = pb[qr];
  float q0=qv.x, q1=qv.y, q2=qv.z, sqq=qv.w;
  float4 nc = pb[l + 64];          // prefetch batch 1
  float dd; int mm = l;
  {
    float4 c = pb[l];
    float dot = q0*c.x + q1*c.y + q2*c.z;
    dd = (sqq - 2.0f*dot) + c.w;
  }
  bitonic64(dd, mm, l);
  float lv = (l<32) ? dd : 3.4e38f;
  int li = (l<32) ? mm : 0x7fffffff;
  float thr = rlane(lv, 31);
  int cnt = 0;
  #pragma unroll 4
  for(int j=1;j<64;j++){
    float4 c = nc;
    nc = pb[l + (((j+1)&63)<<6)];
    float dot = q0*c.x + q1*c.y + q2*c.z;
    float d = (sqq - 2.0f*dot) + c.w;
    topk_buf(d, l + (j<<6), l, buf, cnt, thr, lv, li);
  }
  if(cnt) kmerge(buf, cnt, l, lv, li);
  if(l < 32) idx[(size_t)q*KK + l] = li;
}

// ---------------- KNN selection from fp16-packed D (reservoir; 2 candidates per load) ----------------
__global__ __launch_bounds__(256) void k_knn_sel(const __half2* __restrict__ D, int* __restrict__ idx){
  __shared__ float2 bufs[4][32];
  int l = threadIdx.x&63;
  int wid = threadIdx.x>>6;
  int q = blockIdx.x*4 + wid;
  int b = q>>12, qr = q&4095;
  const __half2* row = D + ((size_t)b<<23) + ((size_t)qr<<11);
  float2* buf = bufs[wid];
  __half2 h0 = row[l];
  __half2 nh = row[l + 64];        // prefetch batch 1
  float2 f0 = __half22float2(h0);
  float dmin, dmax; int mmin, mmax;
  if(f0.x <= f0.y){ dmin=f0.x; mmin=2*l;   dmax=f0.y; mmax=2*l+1; }
  else            { dmin=f0.y; mmin=2*l+1; dmax=f0.x; mmax=2*l;   }
  bitonic64(dmin, mmin, l);
  float lv = (l<32) ? dmin : 3.4e38f;
  int li = (l<32) ? mmin : 0x7fffffff;
  float thr = rlane(lv, 31);
  int cnt = 0;
  topk_buf(dmax, mmax, l, buf, cnt, thr, lv, li);
  #pragma unroll 4
  for(int j=1;j<32;j++){
    __half2 h = nh;
    nh = row[l + (((j+1)&31)<<6)];
    float2 g = __half22float2(h);
    int base = 2*(l + (j<<6));
    topk_buf(g.x, base,   l, buf, cnt, thr, lv, li);
    topk_buf(g.y, base+1, l, buf, cnt, thr, lv, li);
  }
  if(cnt) kmerge(buf, cnt, l, lv, li);
  if(l < 32) idx[(size_t)q*KK + l] = li;
}

// ---------------- gaussian kernel conv ----------------
__global__ __launch_bounds__(128) void k_gauss(const float* __restrict__ pts, const float* __restrict__ sqp,
                                               const int* __restrict__ idxP, const float* __restrict__ cen,
                                               float* __restrict__ kout){
  __shared__ float nbx[KK], nby[KK], nbz[KK], nsq[KK];
  int p = blockIdx.x; int b = p>>12; int t = threadIdx.x;
  if(t < KK){
    int id = idxP[(size_t)p*KK + t] + (b<<12);
    nbx[t]=pts[id*3]; nby[t]=pts[id*3+1]; nbz[t]=pts[id*3+2];
    nsq[t]=sqp[id];
  }
  __syncthreads();
  float c0=cen[t*3], c1=cen[t*3+1], c2=cen[t*3+2];
  float sqc=(c0*c0+c1*c1)+c2*c2;
  float acc=0.f;
  #pragma unroll
  for(int k=0;k<KK;k++){
    float dot = nbx[k]*c0 + nby[k]*c1 + nbz[k]*c2;
    float d = (nsq[k] - 2.0f*dot) + sqc;
    acc += __expf(-0.5f*d);
  }
  kout[(size_t)((b<<7)+t)*4096 + (p&4095)] = acc;
}

// ---------------- finalize BN stats ----------------
__global__ void k_fin(const float* __restrict__ psum, const float* __restrict__ psq, int NW, int C, float Nn,
                      const float* __restrict__ g, const float* __restrict__ be,
                      float* __restrict__ sc, float* __restrict__ sh){
  int o = blockIdx.x, t = threadIdx.x;
  float s=0.f, q=0.f;
  for(int w=t; w<NW; w+=256){ s += psum[(size_t)w*C+o]; q += psq[(size_t)w*C+o]; }
  __shared__ float ls[256], lq[256];
  ls[t]=s; lq[t]=q; __syncthreads();
  for(int st=128; st; st>>=1){ if(t<st){ ls[t]+=ls[t+st]; lq[t]+=lq[t+st]; } __syncthreads(); }
  if(t==0){
    float mu = ls[0]/Nn;
    float var = lq[0]/Nn - mu*mu; if(var<0.f) var=0.f;
    float s1 = g[o]*rsqrtf(var + EPSB);
    sc[o]=s1; sh[o]=be[o]-mu*s1;
  }
}

// ---------------- edge-conv 1 BN1 stats via feature moments ----------------
__global__ __launch_bounds__(256) void k_ec1mom(const float* __restrict__ xe0, const int* __restrict__ idx1,
                                                float* __restrict__ pmom){
  int tid = blockIdx.x*256 + threadIdx.x;      // < 131072
  int l = threadIdx.x & 63;
  int wid = tid >> 6;                           // < 2048
  float a[27];
  #pragma unroll
  for(int v=0;v<27;v++) a[v]=0.f;
  #pragma unroll
  for(int u=0;u<2;u++){
    int s = tid*2 + u;
    int p = s>>5;
    int bb = (p>>12)<<12;
    int id = bb + idx1[s];
    const float* nb = xe0 + (size_t)id*3;
    const float* xc = xe0 + (size_t)p*3;
    float f[6];
    f[0]=nb[0]-xc[0]; f[1]=nb[1]-xc[1]; f[2]=nb[2]-xc[2];
    f[3]=xc[0]; f[4]=xc[1]; f[5]=xc[2];
    int v=0;
    #pragma unroll
    for(int i=0;i<6;i++){
      #pragma unroll
      for(int j=i;j<6;j++){ a[v] = fmaf(f[i], f[j], a[v]); v++; }
    }
    #pragma unroll
    for(int i=0;i<6;i++) a[21+i] += f[i];
  }
  #pragma unroll
  for(int v=0;v<27;v++){
    float t = a[v];
    #pragma unroll
    for(int off=32; off; off>>=1) t += __shfl_xor(t, off);
    if(l==0) pmom[v*2048 + wid] = t;
  }
}

__global__ void k_msum(const float* __restrict__ pmom, float* __restrict__ mom){
  int v = blockIdx.x; int t = threadIdx.x;
  float s=0.f;
  for(int i=t;i<2048;i+=256) s += pmom[v*2048+i];
  __shared__ float ls[256];
  ls[t]=s; __syncthreads();
  for(int st=128; st; st>>=1){ if(t<st) ls[t]+=ls[t+st]; __syncthreads(); }
  if(t==0) mom[v]=ls[0];
}

__global__ void k_ec1bn(const float* __restrict__ mom, const float* __restrict__ w1,
                        const float* __restrict__ g, const float* __restrict__ be,
                        float* __restrict__ sc, float* __restrict__ sh){
  __shared__ float M[27];
  int t = threadIdx.x;
  if(t<27) M[t]=mom[t];
  __syncthreads();
  if(t<64){
    float w[6];
    #pragma unroll
    for(int c=0;c<6;c++) w[c]=w1[t*6+c];
    float qf=0.f, m1=0.f;
    int v=0;
    #pragma unroll
    for(int i=0;i<6;i++){
      #pragma unroll
      for(int j=i;j<6;j++){ qf += (i==j?1.f:2.f)*w[i]*w[j]*M[v]; v++; }
    }
    #pragma unroll
    for(int i=0;i<6;i++) m1 += w[i]*M[21+i];
    float N = 262144.f;
    float mu = m1/N;
    float var = qf/N - mu*mu; if(var<0.f) var=0.f;
    float s1 = g[t]*rsqrtf(var + EPSB);
    sc[t]=s1; sh[t]=be[t]-mu*s1;
  }
}

// ---------------- edge-conv 1 fused ----------------
__global__ __launch_bounds__(256) void k_ec1g2(const float* __restrict__ xe0, const int* __restrict__ idx1,
                                               const float* __restrict__ w1, const float* __restrict__ w2T,
                                               const float* __restrict__ s1, const float* __restrict__ t1,
                                               float* __restrict__ h2m, float* __restrict__ psum,
                                               float* __restrict__ psq){
  __shared__ float As[64*64];
  __shared__ float Bs[64*132];
  __shared__ float feat[6][128];
  __shared__ float w1l[384];
  int t = threadIdx.x;
  int blk = blockIdx.x;
  int s0 = blk*128;
  int pbase = s0>>5;
  int bb = (s0>>17)<<12;
  #pragma unroll
  for(int i=0;i<16;i++) As[t + i*256] = w2T[t + i*256];
  for(int i=t; i<384; i+=256) w1l[i] = w1[i];
  if(t < 128){
    int s = s0 + t;
    int p = pbase + (t>>5);
    int id = bb + idx1[s];
    const float* nb = xe0 + (size_t)id*3;
    const float* xc = xe0 + (size_t)p*3;
    float x0 = xc[0], x1 = xc[1], x2 = xc[2];
    feat[0][t] = nb[0]-x0; feat[1][t] = nb[1]-x1; feat[2][t] = nb[2]-x2;
    feat[3][t] = x0; feat[4][t] = x1; feat[5][t] = x2;
  }
  __syncthreads();
  #pragma unroll
  for(int i=0;i<32;i++){
    int e = t + (i<<8);
    int k = e>>7, n = e&127;
    float h = w1l[k*6+0]*feat[0][n] + w1l[k*6+1]*feat[1][n] + w1l[k*6+2]*feat[2][n]
            + w1l[k*6+3]*feat[3][n] + w1l[k*6+4]*feat[4][n] + w1l[k*6+5]*feat[5][n];
    Bs[k*132 + n] = lrelu(fmaf(h, s1[k], t1[k]));
  }
  __syncthreads();
  int tx = t&15, ty = t>>4;
  float acc[4][8];
  #pragma unroll
  for(int i=0;i<4;i++){
    #pragma unroll
    for(int j=0;j<8;j++) acc[i][j]=0.f;
  }
  #pragma unroll 4
  for(int k=0;k<64;k++){
    float4 a  = *(const float4*)&As[k*64 + ty*4];
    float4 b0 = *(const float4*)&Bs[k*132 + tx*4];
    float4 b1 = *(const float4*)&Bs[k*132 + 64 + tx*4];
    float av[4] = {a.x,a.y,a.z,a.w};
    float bv[8] = {b0.x,b0.y,b0.z,b0.w,b1.x,b1.y,b1.z,b1.w};
    #pragma unroll
    for(int i=0;i<4;i++){
      #pragma unroll
      for(int j=0;j<8;j++) acc[i][j] = fmaf(av[i], bv[j], acc[i][j]);
    }
  }
  #pragma unroll
  for(int i=0;i<4;i++){
    int m = ty*4 + i;
    float sr = ((acc[i][0]+acc[i][1])+(acc[i][2]+acc[i][3])) + ((acc[i][4]+acc[i][5])+(acc[i][6]+acc[i][7]));
    float sq = ((acc[i][0]*acc[i][0]+acc[i][1]*acc[i][1])+(acc[i][2]*acc[i][2]+acc[i][3]*acc[i][3]))
             + ((acc[i][4]*acc[i][4]+acc[i][5]*acc[i][5])+(acc[i][6]*acc[i][6]+acc[i][7]*acc[i][7]));
    #pragma unroll
    for(int off=1; off<16; off<<=1){ sr += __shfl_xor(sr, off); sq += __shfl_xor(sq, off); }
    if(tx==0){ psum[(size_t)blk*64+m]=sr; psq[(size_t)blk*64+m]=sq; }
    float m0 = fmaxf(fmaxf(acc[i][0],acc[i][1]), fmaxf(acc[i][2],acc[i][3]));
    float m1 = fmaxf(fmaxf(acc[i][4],acc[i][5]), fmaxf(acc[i][6],acc[i][7]));
    #pragma unroll
    for(int off=1; off<8; off<<=1){ m0 = fmaxf(m0, __shfl_xor(m0, off)); m1 = fmaxf(m1, __shfl_xor(m1, off)); }
    if((tx&7)==0){
      int pl = pbase + (tx>>3);
      h2m[(size_t)pl*64 + m]     = m0;
      h2m[(size_t)(pl+2)*64 + m] = m1;
    }
  }
}

// ---------------- ec1 finalize ----------------
__global__ __launch_bounds__(256) void k_ec1fin(const float* __restrict__ h2m, const float* __restrict__ s2,
                                                const float* __restrict__ t2, float* __restrict__ xe1,
                                                float* __restrict__ xe1T, float* __restrict__ sqx){
  int gid = blockIdx.x*256 + threadIdx.x;  // < NP*64
  int p = gid>>6, l = gid&63;
  float v = lrelu(fmaf(h2m[(size_t)p*64+l], s2[l], t2[l]));
  xe1[(size_t)p*64+l] = v;
  int b=p>>12, pr=p&4095;
  xe1T[(size_t)(b*64+l)*4096 + pr] = v;
  float sq = v*v;
  #pragma unroll
  for(int off=32; off; off>>=1) sq += __shfl_xor(sq, off);
  if(l==0) sqx[p]=sq;
}

// ---------------- D (fp16) via bf16 MFMA: block (mb,nb,b); writes transposed (D symmetric) ----------------
__global__ __launch_bounds__(256) void k_dgemm_m(const short* __restrict__ X, const float* __restrict__ sqx,
                                                 __half* __restrict__ D){
  __shared__ short sA[8192], sB[8192];
  int t = threadIdx.x;
  int lane = t&63, w = t>>6;
  int wm4 = (w>>1)*4, wn4 = (w&1)*4;
  int mb = blockIdx.y, nb = blockIdx.x, b = blockIdx.z;
  const short* AG = X + (size_t)(b*32 + mb)*8192;
  const short* BG = X + (size_t)(b*32 + nb)*8192;
  #pragma unroll
  for(int i=0;i<4;i++){
    int slot = t + i*256;
    *(s8v*)&sA[slot*8] = *(const s8v*)&AG[slot*8];
    *(s8v*)&sB[slot*8] = *(const s8v*)&BG[slot*8];
  }
  __syncthreads();
  f4v acc[4][4];
  #pragma unroll
  for(int i=0;i<4;i++){
    #pragma unroll
    for(int j=0;j<4;j++) acc[i][j] = (f4v)(0.f);
  }
  #pragma unroll
  for(int kh=0;kh<2;kh++){
    s8v av[4], bv[4];
    #pragma unroll
    for(int f=0;f<4;f++) av[f] = *(const s8v*)&sA[(kh*8 + wm4 + f)*512 + lane*8];
    #pragma unroll
    for(int f=0;f<4;f++) bv[f] = *(const s8v*)&sB[(kh*8 + wn4 + f)*512 + lane*8];
    #pragma unroll
    for(int fm=0;fm<4;fm++){
      #pragma unroll
      for(int fn=0;fn<4;fn++)
        acc[fm][fn] = __builtin_amdgcn_mfma_f32_16x16x32_bf16(av[fm], bv[fn], acc[fm][fn], 0, 0, 0);
    }
  }
  const float* sb = sqx + (b<<12);
  __half* Db = D + ((size_t)b<<24);
  int l15 = lane&15, l4 = (lane>>4)*4;
  #pragma unroll
  for(int fm=0;fm<4;fm++){
    int m0 = mb*128 + wm4*16 + fm*16 + l4;
    float sm0 = sb[m0], sm1 = sb[m0+1], sm2 = sb[m0+2], sm3 = sb[m0+3];
    #pragma unroll
    for(int fn=0;fn<4;fn++){
      int n = nb*128 + wn4*16 + fn*16 + l15;
      float sqn = sb[n];
      __half2 h01 = __floats2half2_rn((sm0 + sqn) - 2.f*acc[fm][fn][0],
                                      (sm1 + sqn) - 2.f*acc[fm][fn][1]);
      __half2 h23 = __floats2half2_rn((sm2 + sqn) - 2.f*acc[fm][fn][2],
                                      (sm3 + sqn) - 2.f*acc[fm][fn][3]);
      __half2* p = (__half2*)&Db[(size_t)n*4096 + m0];
      p[0] = h01; p[1] = h23;
    }
  }
}

// ---------------- edge-conv 2 pass 1 (bf16 MFMA gather-GEMM) ----------------
__global__ __launch_bounds__(256) void k_ec2m1(const float* __restrict__ xe1, const int* __restrict__ idx2,
                                               const short* __restrict__ wb, float* __restrict__ h1,
                                               float* __restrict__ psum, float* __restrict__ psq){
  __shared__ short sA[8192], sB[8192];
  __shared__ float cts[4][64];
  __shared__ int nid[128];
  __shared__ float srs[2][128], srq[2][128];
  int t = threadIdx.x;
  int blk = blockIdx.x;
  int s0 = blk*128;
  int pbase = s0>>5;
  int bb = (s0>>17)<<12;
  if(t<128) nid[t] = (idx2[s0+t] + bb)<<6;
  cts[t>>6][t&63] = xe1[(size_t)(pbase + (t>>6))*64 + (t&63)];
  int lane = t&63, w = t>>6;
  int wm4 = (w>>1)*4, wn4 = (w&1)*4;
  f4v acc[4][4];
  #pragma unroll
  for(int i=0;i<4;i++){
    #pragma unroll
    for(int j=0;j<4;j++) acc[i][j] = (f4v)(0.f);
  }
  for(int st=0; st<2; ++st){
    __syncthreads();
    #pragma unroll
    for(int i=0;i<4;i++){
      int slot = t + i*256;
      *(s8v*)&sA[slot*8] = *(const s8v*)&wb[st*8192 + slot*8];
      int chunk = slot>>6, li = slot&63;
      int n = (chunk&7)*16 + (li&15);
      int c = ((chunk>>3)<<5) + ((li>>4)<<3);
      float v[8];
      if(st==0){
        const float* src = xe1 + nid[n] + c;
        float4 a0 = *(const float4*)src;
        float4 a1 = *(const float4*)(src+4);
        const float* cc = &cts[n>>5][c];
        float4 c0 = *(const float4*)cc;
        float4 c1 = *(const float4*)(cc+4);
        v[0]=a0.x-c0.x; v[1]=a0.y-c0.y; v[2]=a0.z-c0.z; v[3]=a0.w-c0.w;
        v[4]=a1.x-c1.x; v[5]=a1.y-c1.y; v[6]=a1.z-c1.z; v[7]=a1.w-c1.w;
      } else {
        const float* cc = &cts[n>>5][c];
        float4 c0 = *(const float4*)cc;
        float4 c1 = *(const float4*)(cc+4);
        v[0]=c0.x; v[1]=c0.y; v[2]=c0.z; v[3]=c0.w;
        v[4]=c1.x; v[5]=c1.y; v[6]=c1.z; v[7]=c1.w;
      }
      s8v r;
      #pragma unroll
      for(int j=0;j<8;j++) r[j] = f2bf(v[j]);
      *(s8v*)&sB[slot*8] = r;
    }
    __syncthreads();
    #pragma unroll
    for(int kh=0;kh<2;kh++){
      s8v av[4], bv[4];
      #pragma unroll
      for(int f=0;f<4;f++) av[f] = *(const s8v*)&sA[(kh*8 + wm4 + f)*512 + lane*8];
      #pragma unroll
      for(int f=0;f<4;f++) bv[f] = *(const s8v*)&sB[(kh*8 + wn4 + f)*512 + lane*8];
      #pragma unroll
      for(int fm=0;fm<4;fm++){
        #pragma unroll
        for(int fn=0;fn<4;fn++)
          acc[fm][fn] = __builtin_amdgcn_mfma_f32_16x16x32_bf16(av[fm], bv[fn], acc[fm][fn], 0, 0, 0);
      }
    }
  }
  int l15 = lane&15, l4 = (lane>>4)<<2;
  #pragma unroll
  for(int fm=0;fm<4;fm++){
    int mb_ = wm4*16 + fm*16 + l4;
    #pragma unroll
    for(int fn=0;fn<4;fn++){
      int n = wn4*16 + fn*16 + l15;
      *(float4*)&h1[(size_t)(s0+n)*128 + mb_] =
        make_float4(acc[fm][fn][0], acc[fm][fn][1], acc[fm][fn][2], acc[fm][fn][3]);
    }
    #pragma unroll
    for(int r=0;r<4;r++){
      float sr = (acc[fm][0][r]+acc[fm][1][r]) + (acc[fm][2][r]+acc[fm][3][r]);
      float sq = (acc[fm][0][r]*acc[fm][0][r]+acc[fm][1][r]*acc[fm][1][r])
               + (acc[fm][2][r]*acc[fm][2][r]+acc[fm][3][r]*acc[fm][3][r]);
      #pragma unroll
      for(int off=1; off<16; off<<=1){ sr += __shfl_xor(sr, off); sq += __shfl_xor(sq, off); }
      if(l15==0){ srs[w&1][mb_+r] = sr; srq[w&1][mb_+r] = sq; }
    }
  }
  __syncthreads();
  if(t<128){
    psum[(size_t)blk*128+t] = srs[0][t]+srs[1][t];
    psq[(size_t)blk*128+t]  = srq[0][t]+srq[1][t];
  }
}

// ---------------- edge-conv 2 pass 2 (bf16 MFMA, fused BN1+lrelu, stats + per-point max) ----------------
__global__ __launch_bounds__(256) void k_ec2m2(const float* __restrict__ h1, const short* __restrict__ wb,
                                               const float* __restrict__ s1, const float* __restrict__ t1,
                                               float* __restrict__ h2max, float* __restrict__ psum,
                                               float* __restrict__ psq){
  __shared__ short sA[8192], sB[8192];
  __shared__ float bnS[128], bnT[128];
  __shared__ float srs[2][128], srq[2][128];
  int t = threadIdx.x;
  int blk = blockIdx.x;
  int s0 = blk*128;
  int pbase = s0>>5;
  if(t<128){ bnS[t]=s1[t]; bnT[t]=t1[t]; }
  int lane = t&63, w = t>>6;
  int wm4 = (w>>1)*4, wn4 = (w&1)*4;
  f4v acc[4][4];
  #pragma unroll
  for(int i=0;i<4;i++){
    #pragma unroll
    for(int j=0;j<4;j++) acc[i][j] = (f4v)(0.f);
  }
  for(int st=0; st<2; ++st){
    __syncthreads();
    #pragma unroll
    for(int i=0;i<4;i++){
      int slot = t + i*256;
      *(s8v*)&sA[slot*8] = *(const s8v*)&wb[st*8192 + slot*8];
      int chunk = slot>>6, li = slot&63;
      int n = (chunk&7)*16 + (li&15);
      int c = st*64 + ((chunk>>3)<<5) + ((li>>4)<<3);
      const float* src = h1 + (size_t)(s0+n)*128 + c;
      float4 a0 = *(const float4*)src;
      float4 a1 = *(const float4*)(src+4);
      float v[8] = {a0.x,a0.y,a0.z,a0.w,a1.x,a1.y,a1.z,a1.w};
      s8v r;
      #pragma unroll
      for(int j=0;j<8;j++) r[j] = f2bf(lrelu(fmaf(v[j], bnS[c+j], bnT[c+j])));
      *(s8v*)&sB[slot*8] = r;
    }
    __syncthreads();
    #pragma unroll
    for(int kh=0;kh<2;kh++){
      s8v av[4], bv[4];
      #pragma unroll
      for(int f=0;f<4;f++) av[f] = *(const s8v*)&sA[(kh*8 + wm4 + f)*512 + lane*8];
      #pragma unroll
      for(int f=0;f<4;f++) bv[f] = *(const s8v*)&sB[(kh*8 + wn4 + f)*512 + lane*8];
      #pragma unroll
      for(int fm=0;fm<4;fm++){
        #pragma unroll
        for(int fn=0;fn<4;fn++)
          acc[fm][fn] = __builtin_amdgcn_mfma_f32_16x16x32_bf16(av[fm], bv[fn], acc[fm][fn], 0, 0, 0);
      }
    }
  }
  int l15 = lane&15, l4 = (lane>>4)<<2;
  int pp0 = wn4>>1;
  #pragma unroll
  for(int fm=0;fm<4;fm++){
    int mb_ = wm4*16 + fm*16 + l4;
    #pragma unroll
    for(int r=0;r<4;r++){
      float sr = (acc[fm][0][r]+acc[fm][1][r]) + (acc[fm][2][r]+acc[fm][3][r]);
      float sq = (acc[fm][0][r]*acc[fm][0][r]+acc[fm][1][r]*acc[fm][1][r])
               + (acc[fm][2][r]*acc[fm][2][r]+acc[fm][3][r]*acc[fm][3][r]);
      float m0 = fmaxf(acc[fm][0][r], acc[fm][1][r]);
      float m1 = fmaxf(acc[fm][2][r], acc[fm][3][r]);
      #pragma unroll
      for(int off=1; off<16; off<<=1){ sr += __shfl_xor(sr, off); sq += __shfl_xor(sq, off); }
      #pragma unroll
      for(int off=1; off<16; off<<=1){ m0 = fmaxf(m0, __shfl_xor(m0, off)); m1 = fmaxf(m1, __shfl_xor(m1, off)); }
      if(l15==0){
        srs[w&1][mb_+r] = sr; srq[w&1][mb_+r] = sq;
        h2max[(size_t)(pbase+pp0)*128   + mb_+r] = m0;
        h2max[(size_t)(pbase+pp0+1)*128 + mb_+r] = m1;
      }
    }
  }
  __syncthreads();
  if(t<128){
    psum[(size_t)blk*128+t] = srs[0][t]+srs[1][t];
    psq[(size_t)blk*128+t]  = srq[0][t]+srq[1][t];
  }
}

// ---------------- xe2 = lrelu(BN(h2max)) in-place ----------------
__global__ void k_xe2fin(float* __restrict__ xe2, const float* __restrict__ s2, const float* __restrict__ t2){
  int i = blockIdx.x*256 + threadIdx.x;   // < NP*128
  if(i >= NP*128) return;
  int o = i&127;
  xe2[i] = lrelu(fmaf(xe2[i], s2[o], t2[o]));
}

// ---------------- generic small transpose ----------------
__global__ void k_transpose(const float* __restrict__ w, float* __restrict__ wT, int O, int C){
  int i = blockIdx.x*256 + threadIdx.x;
  if(i >= O*C) return;
  int o = i / C, c = i % C;
  wT[(size_t)c*O + o] = w[i];
}

// ---------------- weight fp32 -> bf16 fragment-linear ----------------
__global__ void k_wprep(const float* __restrict__ w, short* __restrict__ wb, int M, int K){
  int tid = blockIdx.x*256 + threadIdx.x;
  int m = tid % M, kb8 = tid / M;
  int k0 = kb8*8;
  float4 v0 = *(const float4*)&w[(size_t)m*K + k0];
  float4 v1 = *(const float4*)&w[(size_t)m*K + k0 + 4];
  s8v r;
  r[0]=f2bf(v0.x); r[1]=f2bf(v0.y); r[2]=f2bf(v0.z); r[3]=f2bf(v0.w);
  r[4]=f2bf(v1.x); r[5]=f2bf(v1.y); r[6]=f2bf(v1.z); r[7]=f2bf(v1.w);
  int region = (m>>7)*(K>>6) + (k0>>6);
  int chunk = ((kb8>>2)&1)*8 + ((m>>4)&7);
  int lane = (kb8&3)*16 + (m&15);
  *(s8v*)&wb[(size_t)region*8192 + chunk*512 + lane*8] = r;
}

// ---------------- activations -> bf16 fragment-linear ----------------
__global__ void k_bprep(const float* __restrict__ in, const float* __restrict__ sc, const float* __restrict__ sh,
                        short* __restrict__ ob, int K){
  int tid = blockIdx.x*256 + threadIdx.x;
  int n = tid & 8191, kb8 = tid >> 13;
  int k0 = kb8*8;
  int b = n>>12, s = n&4095;
  const float* ib = in + ((size_t)b*K + k0)*4096 + s;
  float v[8];
  #pragma unroll
  for(int j=0;j<8;j++) v[j] = ib[(size_t)j*4096];
  if(sc){
    #pragma unroll
    for(int j=0;j<8;j++) v[j] = lrelu(fmaf(v[j], sc[k0+j], sh[k0+j]));
  }
  s8v r;
  #pragma unroll
  for(int j=0;j<8;j++) r[j] = f2bf(v[j]);
  int region = (n>>7)*(K>>6) + (k0>>6);
  int chunk = ((kb8>>2)&1)*8 + ((n>>4)&7);
  int lane = (kb8&3)*16 + (n&15);
  *(s8v*)&ob[(size_t)region*8192 + chunk*512 + lane*8] = r;
}

// ---------------- layer-1 activations: read [xe2-flat ; kr] directly ----------------
__global__ void k_bprep1(const float* __restrict__ xe2, const float* __restrict__ kr,
                         short* __restrict__ ob){
  int tid = blockIdx.x*256 + threadIdx.x;   // < 8192*256/8
  int n = tid & 8191, kb8 = tid >> 13;
  int k0 = kb8*8;
  int b = n>>12, s = n&4095;
  const float* ib;
  if(k0 < 128) ib = xe2 + (size_t)b*524288 + (size_t)k0*4096 + s;
  else         ib = kr + ((size_t)(b*128 + (k0-128)))*4096 + s;
  float v[8];
  #pragma unroll
  for(int j=0;j<8;j++) v[j] = ib[(size_t)j*4096];
  s8v r;
  #pragma unroll
  for(int j=0;j<8;j++) r[j] = f2bf(v[j]);
  int region = (n>>7)*4 + (k0>>6);
  int chunk = ((kb8>>2)&1)*8 + ((n>>4)&7);
  int lane = (kb8&3)*16 + (n&15);
  *(s8v*)&ob[(size_t)region*8192 + chunk*512 + lane*8] = r;
}

// ---------------- bf16 MFMA GEMM ----------------
__global__ __launch_bounds__(256) void k_gmm(const short* __restrict__ A, const short* __restrict__ B,
                                             float* __restrict__ out, int M, int K){
  __shared__ short sA[8192], sB[8192];
  int t = threadIdx.x;
  int lane = t&63;
  int w = t>>6;
  int wm4 = (w>>1)*4, wn4 = (w&1)*4;
  int mb = blockIdx.y, nb = blockIdx.x;
  int ksteps = K>>6;
  const short* AG = A + (size_t)mb*ksteps*8192;
  const short* BG = B + (size_t)nb*ksteps*8192;
  f4v acc[4][4];
  #pragma unroll
  for(int i=0;i<4;i++){
    #pragma unroll
    for(int j=0;j<4;j++) acc[i][j] = (f4v)(0.f);
  }
  for(int st=0; st<ksteps; ++st){
    __syncthreads();
    #pragma unroll
    for(int i=0;i<4;i++){
      int slot = t + i*256;
      *(s8v*)&sA[slot*8] = *(const s8v*)&AG[(size_t)st*8192 + slot*8];
      *(s8v*)&sB[slot*8] = *(const s8v*)&BG[(size_t)st*8192 + slot*8];
    }
    __syncthreads();
    #pragma unroll
    for(int kh=0;kh<2;kh++){
      s8v av[4], bv[4];
      #pragma unroll
      for(int f=0;f<4;f++) av[f] = *(const s8v*)&sA[(kh*8 + wm4 + f)*512 + lane*8];
      #pragma unroll
      for(int f=0;f<4;f++) bv[f] = *(const s8v*)&sB[(kh*8 + wn4 + f)*512 + lane*8];
      #pragma unroll
      for(int fm=0;fm<4;fm++){
        #pragma unroll
        for(int fn=0;fn<4;fn++)
          acc[fm][fn] = __builtin_amdgcn_mfma_f32_16x16x32_bf16(av[fm], bv[fn], acc[fm][fn], 0, 0, 0);
      }
    }
  }
  int l15 = lane&15, l4 = (lane>>4)*4;
  #pragma unroll
  for(int fm=0;fm<4;fm++){
    int mrow = mb*128 + wm4*16 + fm*16 + l4;
    #pragma unroll
    for(int fn=0;fn<4;fn++){
      int n = nb*128 + wn4*16 + fn*16 + l15;
      int b = n>>12, s = n&4095;
      float* ob = out + ((size_t)b*M + mrow)*4096 + s;
      #pragma unroll
      for(int r=0;r<4;r++) ob[(size_t)r*4096] = acc[fm][fn][r];
    }
  }
}

// ---------------- per-channel stats for cbr layers ----------------
__global__ void k_cstats(const float* __restrict__ buf, int C, const float* __restrict__ g,
                         const float* __restrict__ be, float* __restrict__ sc, float* __restrict__ sh){
  int o = blockIdx.x, t = threadIdx.x;
  float s=0.f, q=0.f;
  for(int i=t;i<8192;i+=256){
    int b=i>>12, ss_=i&4095;
    float v = buf[(size_t)(b*C+o)*4096 + ss_];
    s+=v; q+=v*v;
  }
  __shared__ float ls[256], lq[256];
  ls[t]=s; lq[t]=q; __syncthreads();
  for(int st=128; st; st>>=1){ if(t<st){ ls[t]+=ls[t+st]; lq[t]+=lq[t+st]; } __syncthreads(); }
  if(t==0){
    float mu = ls[0]/8192.f;
    float var = lq[0]/8192.f - mu*mu; if(var<0.f) var=0.f;
    float s1 = g[o]*rsqrtf(var + EPSB);
    sc[o]=s1; sh[o]=be[o]-mu*s1;
  }
}

// ---------------- final layer ----------------
__global__ __launch_bounds__(256) void k_final4(const float* __restrict__ c3, const float* __restrict__ w4T,
                                                const float* __restrict__ sc, const float* __restrict__ sh,
                                                float* __restrict__ pmax){
  int b = blockIdx.y, st = blockIdx.x;
  int t = threadIdx.x; int s = st*256 + t;
  float acc[9];
  #pragma unroll
  for(int j=0;j<9;j++) acc[j]=0.f;
  const float* ib = c3 + (size_t)b*256*4096;
  for(int c=0;c<256;c++){
    float x = lrelu(fmaf(ib[(size_t)c*4096+s], sc[c], sh[c]));
    #pragma unroll
    for(int j=0;j<9;j++) acc[j]=fmaf(x, w4T[c*9+j], acc[j]);
  }
  __shared__ float red[256];
  for(int j=0;j<9;j++){
    red[t]=acc[j]; __syncthreads();
    for(int stp=128; stp; stp>>=1){ if(t<stp) red[t]=fmaxf(red[t],red[t+stp]); __syncthreads(); }
    if(t==0) pmax[(b*16+st)*9 + j]=red[0];
    __syncthreads();
  }
}

__global__ void k_out(const float* __restrict__ pmax, float* __restrict__ out){
  int i = threadIdx.x;
  if(i<18){
    int b=i/9, o=i%9;
    float m=-3.4e38f;
    for(int k=0;k<16;k++) m=fmaxf(m, pmax[(b*16+k)*9+o]);
    out[i] = m + ((o==0||o==4||o==8)?1.f:0.f);
  }
}

// ---------------- launch ----------------
extern "C" void kernel_launch(void* const* d_in, const int* in_sizes, int n_in,
                              void* d_out, int out_size, void* d_ws, size_t ws_size,
                              hipStream_t stream){
  const float* x    = (const float*)d_in[0];
  const float* kc   = (const float*)d_in[1];
  const float* e1w1 = (const float*)d_in[2];
  const float* e1g1 = (const float*)d_in[3];
  const float* e1b1 = (const float*)d_in[4];
  const float* e1w2 = (const float*)d_in[5];
  const float* e1g2 = (const float*)d_in[6];
  const float* e1b2 = (const float*)d_in[7];
  const float* e2w1 = (const float*)d_in[8];
  const float* e2g1 = (const float*)d_in[9];
  const float* e2b1 = (const float*)d_in[10];
  const float* e2w2 = (const float*)d_in[11];
  const float* e2g2 = (const float*)d_in[12];
  const float* e2b2 = (const float*)d_in[13];
  const float* w1   = (const float*)d_in[14];
  const float* g1   = (const float*)d_in[15];
  const float* b1   = (const float*)d_in[16];
  const float* w2   = (const float*)d_in[17];
  const float* g2   = (const float*)d_in[18];
  const float* b2   = (const float*)d_in[19];
  const float* w3   = (const float*)d_in[20];
  const float* g3   = (const float*)d_in[21];
  const float* b3   = (const float*)d_in[22];
  const float* w4   = (const float*)d_in[23];

  if(ws_size < 156061696ull) return;
  char* ws = (char*)d_ws;
  float* pts   = (float*)(ws + 0);
  float* xe0   = (float*)(ws + 98304);
  float* sqp   = (float*)(ws + 196608);
  float* sqe   = (float*)(ws + 229376);
  float* sqx1  = (float*)(ws + 262144);
  float* xe1   = (float*)(ws + 294912);
  float* xe1T  = (float*)(ws + 2392064);
  float* xe2   = (float*)(ws + 4489216);
  float* kr    = (float*)(ws + 8683520);
  int*   idxP  = (int*)  (ws + 12877824);
  int*   idx1  = (int*)  (ws + 13926400);
  int*   idx2  = (int*)  (ws + 14974976);
  float* psum  = (float*)(ws + 16023552);
  float* psq   = (float*)(ws + 17072128);
  float* par   = (float*)(ws + 18120704);
  float* pmax  = (float*)(ws + 18153472);
  float* e1w2T = (float*)(ws + 18157568);
  float* wT4   = (float*)(ws + 21827584);
  float* hbuf  = (float*)(ws + 21843968);
  short* wbe1  = (short*)(ws + 0);
  short* wbe2  = (short*)(ws + 65536);
  float4* pts4 = (float4*)(ws + 4489216);
  float4* xe04 = (float4*)(ws + 4489216 + 131072);
  short* actB  = (short*)(ws + 88952832);
  short* xpack = (short*)(ws + 88952832);
  short* wb1   = (short*)(ws + 105730048);
  short* wb2   = (short*)(ws + 106254336);
  short* wb3   = (short*)(ws + 107302912);
  float* pmom  = psum;
  float* momv  = psq;

  float* e1s1 = par+0;    float* e1t1 = par+64;
  float* e1s2 = par+128;  float* e1t2 = par+192;
  float* e2s1 = par+256;  float* e2t1 = par+384;
  float* e2s2 = par+512;  float* e2t2 = par+640;
  float* c1s  = par+768;  float* c1t  = par+1792;
  float* c2s  = par+2816; float* c2t  = par+3328;
  float* c3s  = par+3840; float* c3t  = par+4096;

  float* c1out = hbuf + 2097152;
  float* c2out = hbuf + 10485760;
  float* c3out = hbuf + 14680064;

  hipLaunchKernelGGL(k_prep, dim3(32), dim3(256), 0, stream, x, pts, xe0, sqp, sqe, pts4, xe04);
  hipLaunchKernelGGL(k_knn3, dim3(2048), dim3(256), 0, stream, pts4, idxP);
  hipLaunchKernelGGL(k_knn3, dim3(2048), dim3(256), 0, stream, xe04, idx1);
  hipLaunchKernelGGL(k_gauss, dim3(8192), dim3(128), 0, stream, pts, sqp, idxP, kc, kr);

  // edge-conv 1 (moment-based BN1 stats; h1 never stored)
  hipLaunchKernelGGL(k_transpose, dim3(16), dim3(256), 0, stream, e1w2, e1w2T, 64, 64);
  hipLaunchKernelGGL(k_ec1mom, dim3(512), dim3(256), 0, stream, xe0, idx1, pmom);
  hipLaunchKernelGGL(k_msum, dim3(27), dim3(256), 0, stream, pmom, momv);
  hipLaunchKernelGGL(k_ec1bn, dim3(1), dim3(64), 0, stream, momv, e1w1, e1g1, e1b1, e1s1, e1t1);
  hipLaunchKernelGGL(k_ec1g2, dim3(2048), dim3(256), 0, stream, xe0, idx1, e1w1, e1w2T, e1s1, e1t1, hbuf, psum, psq);
  hipLaunchKernelGGL(k_fin, dim3(64), dim3(256), 0, stream, psum, psq, 2048, 64, 262144.f, e1g2, e1b2, e1s2, e1t2);
  hipLaunchKernelGGL(k_ec1fin, dim3(2048), dim3(256), 0, stream, hbuf, e1s2, e1t2, xe1, xe1T, sqx1);

  // knn on 64-d features: bf16 MFMA distance GEMM (fp16-packed D) + streaming selection
  hipLaunchKernelGGL(k_wprep, dim3(256), dim3(256), 0, stream, xe1, xpack, 8192, 64);
  hipLaunchKernelGGL(k_dgemm_m, dim3(32,32,2), dim3(256), 0, stream, xpack, sqx1, (__half*)hbuf);
  hipLaunchKernelGGL(k_knn_sel, dim3(2048), dim3(256), 0, stream, (const __half2*)hbuf, idx2);

  // edge-conv 2 (bf16 MFMA formulation, fused stats+max)
  hipLaunchKernelGGL(k_wprep, dim3(8), dim3(256), 0, stream, e2w1, wbe1, 128, 128);
  hipLaunchKernelGGL(k_wprep, dim3(8), dim3(256), 0, stream, e2w2, wbe2, 128, 128);
  hipLaunchKernelGGL(k_ec2m1, dim3(2048), dim3(256), 0, stream, xe1, idx2, wbe1, hbuf, psum, psq);
  hipLaunchKernelGGL(k_fin, dim3(128), dim3(256), 0, stream, psum, psq, 2048, 128, 262144.f, e2g1, e2b1, e2s1, e2t1);
  hipLaunchKernelGGL(k_ec2m2, dim3(2048), dim3(256), 0, stream, hbuf, wbe2, e2s1, e2t1, xe2, psum, psq);
  hipLaunchKernelGGL(k_fin, dim3(128), dim3(256), 0, stream, psum, psq, 2048, 128, 262144.f, e2g2, e2b2, e2s2, e2t2);
  hipLaunchKernelGGL(k_xe2fin, dim3(4096), dim3(256), 0, stream, xe2, e2s2, e2t2);

  // bf16 MFMA cbr chain (hcat fused into k_bprep1)
  hipLaunchKernelGGL(k_wprep, dim3(128), dim3(256), 0, stream, w1, wb1, 1024, 256);
  hipLaunchKernelGGL(k_wprep, dim3(256), dim3(256), 0, stream, w2, wb2, 512, 1024);
  hipLaunchKernelGGL(k_wprep, dim3(64),  dim3(256), 0, stream, w3, wb3, 256, 512);
  hipLaunchKernelGGL(k_transpose, dim3((9*256+255)/256), dim3(256), 0, stream, w4, wT4, 9, 256);

  hipLaunchKernelGGL(k_bprep1, dim3(1024), dim3(256), 0, stream, xe2, kr, actB);
  hipLaunchKernelGGL(k_gmm, dim3(64,8), dim3(256), 0, stream, wb1, actB, c1out, 1024, 256);
  hipLaunchKernelGGL(k_cstats, dim3(1024), dim3(256), 0, stream, c1out, 1024, g1, b1, c1s, c1t);

  hipLaunchKernelGGL(k_bprep, dim3(4096), dim3(256), 0, stream, c1out, c1s, c1t, actB, 1024);
  hipLaunchKernelGGL(k_gmm, dim3(64,4), dim3(256), 0, stream, wb2, actB, c2out, 512, 1024);
  hipLaunchKernelGGL(k_cstats, dim3(512), dim3(256), 0, stream, c2out, 512, g2, b2, c2s, c2t);

  hipLaunchKernelGGL(k_bprep, dim3(2048), dim3(256), 0, stream, c2out, c2s, c2t, actB, 512);
  hipLaunchKernelGGL(k_gmm, dim3(64,2), dim3(256), 0, stream, wb3, actB, c3out, 256, 512);
  hipLaunchKernelGGL(k_cstats, dim3(256), dim3(256), 0, stream, c3out, 256, g3, b3, c3s, c3t);

  hipLaunchKernelGGL(k_final4, dim3(16,2), dim3(256), 0, stream, c3out, wT4, c3s, c3t, pmax);
  hipLaunchKernelGGL(k_out, dim3(1), dim3(32), 0, stream, pmax, (float*)d_out);
}

// Round 21
// 530.283 us; speedup vs baseline: 1.2512x; 1.0247x over previous
//
#include <hip/hip_runtime.h>
#include <hip/hip_fp16.h>
#include <math.h>

#define WN 4096
#define NP 8192
#define KK 32
#define EPSB 1e-5f

typedef __attribute__((ext_vector_type(8))) short s8v;
typedef __attribute__((ext_vector_type(4))) short s4v;
typedef __attribute__((ext_vector_type(4))) float f4v;

__device__ __forceinline__ float lrelu(float x){ return fmaxf(x, 0.01f*x); }
__device__ __forceinline__ float rlane(float v, int c){
  return __int_as_float(__builtin_amdgcn_readlane(__float_as_int(v), c));
}
__device__ __forceinline__ short f2bf(float f){
  unsigned u = __float_as_uint(f);
  u = (u + 0x7fffu + ((u>>16)&1u)) >> 16;
  return (short)u;
}
__device__ __forceinline__ float bf2f(short s){
  return __uint_as_float(((unsigned)(unsigned short)s) << 16);
}

// ---------------- prep ----------------
__global__ void k_prep(const float* __restrict__ x, float* __restrict__ pts, float* __restrict__ xe0,
                       float* __restrict__ sqp, float* __restrict__ sqe,
                       float4* __restrict__ pts4, float4* __restrict__ xe04){
  int i = blockIdx.x*256 + threadIdx.x;
  if(i >= NP) return;
  int b = i>>12, p = i&4095;
  const float* xb = x + b*12288;
  float a0 = xb[p], a1 = xb[4096+p], a2 = xb[8192+p];
  pts[i*3+0]=a0; pts[i*3+1]=a1; pts[i*3+2]=a2;
  float sp = (a0*a0 + a1*a1) + a2*a2;
  sqp[i] = sp;
  pts4[i] = make_float4(a0,a1,a2,sp);
  float e0 = xb[p*3+0], e1 = xb[p*3+1], e2 = xb[p*3+2];
  xe0[i*3+0]=e0; xe0[i*3+1]=e1; xe0[i*3+2]=e2;
  float se = (e0*e0 + e1*e1) + e2*e2;
  sqe[i] = se;
  xe04[i] = make_float4(e0,e1,e2,se);
}

// ---------------- bitonic sort of 64 (d, idx) pairs across lanes, ascending ----------------
__device__ __forceinline__ void bitonic64(float& d, int& m, int l){
  #pragma unroll
  for(int k=2;k<=64;k<<=1){
    #pragma unroll
    for(int j=k>>1;j>0;j>>=1){
      float pd = __shfl_xor(d, j);
      int pm = __shfl_xor(m, j);
      bool pLess = (pd < d);
      bool dirUp = ((l & k) == 0);
      bool lower = ((l & j) == 0);
      bool take = dirUp ? (lower ? pLess : !pLess) : (lower ? !pLess : pLess);
      if(take){ d = pd; m = pm; }
    }
  }
}

// ---------------- merge sorted list (lanes 0..31) with LDS reservoir (cnt entries) ----------------
__device__ __forceinline__ void kmerge(const float2* __restrict__ buf, int cnt, int l,
                                       float& lv, int& li){
  __builtin_amdgcn_wave_barrier();       // ensure buffered ds_writes are ordered before reads
  float md; int mi;
  if(l < 32){ md = lv; mi = li; }
  else{
    int i = l - 32;
    if(i < cnt){ float2 e = buf[i]; md = e.x; mi = __float_as_int(e.y); }
    else{ md = 3.4e38f; mi = 0x7fffffff; }
  }
  bitonic64(md, mi, l);
  if(l < 32){ lv = md; li = mi; }
}

// ---------------- buffered streaming top-32 insert (reservoir; exact) ----------------
// thr only tightens at merges; d >= thr is always a safe reject.
__device__ __forceinline__ void topk_buf(float d, int m, int l, float2* __restrict__ buf,
                                         int& cnt, float& thr, float& lv, int& li){
  bool alive = d < thr;
  unsigned long long mask = __ballot(alive);
  while(mask){
    int nsurv = __popcll(mask);
    int space = 32 - cnt;                      // cnt in [0,31] here -> space >= 1
    int prefix = __popcll(mask & ((1ull<<l)-1ull));
    bool store = alive && (prefix < space);
    if(store) buf[cnt + prefix] = make_float2(d, __int_as_float(m));
    cnt += (nsurv < space) ? nsurv : space;
    alive = alive && !store;
    if(cnt == 32){
      kmerge(buf, 32, l, lv, li);
      cnt = 0;
      thr = rlane(lv, 31);
      alive = alive && (d < thr);
    }
    mask = __ballot(alive);
  }
}

// ---------------- KNN on 3-D points (reservoir selection) ----------------
__global__ __launch_bounds__(256) void k_knn3(const float4* __restrict__ pnt4, int* __restrict__ idx){
  __shared__ float2 bufs[4][32];
  int l = threadIdx.x&63;
  int wid = threadIdx.x>>6;
  int q = blockIdx.x*4 + wid;
  int b = q>>12, qr = q&4095;
  const float4* pb = pnt4 + ((size_t)b<<12);
  float2* buf = bufs[wid];
  float4 qv = pb[qr];
  float q0=qv.x, q1=qv.y, q2=qv.z, sqq=qv.w;
  float4 nc = pb[l + 64];          // prefetch batch 1
  float dd; int mm = l;
  {
    float4 c = pb[l];
    float dot = q0*c.x + q1*c.y + q2*c.z;
    dd = (sqq - 2.0f*dot) + c.w;
  }
  bitonic64(dd, mm, l);
  float lv = (l<32) ? dd : 3.4e38f;
  int li = (l<32) ? mm : 0x7fffffff;
  float thr = rlane(lv, 31);
  int cnt = 0;
  #pragma unroll 4
  for(int j=1;j<64;j++){
    float4 c = nc;
    nc = pb[l + (((j+1)&63)<<6)];
    float dot = q0*c.x + q1*c.y + q2*c.z;
    float d = (sqq - 2.0f*dot) + c.w;
    topk_buf(d, l + (j<<6), l, buf, cnt, thr, lv, li);
  }
  if(cnt) kmerge(buf, cnt, l, lv, li);
  if(l < 32) idx[(size_t)q*KK + l] = li;
}

// ---------------- KNN selection from fp16-packed D (reservoir; 2 candidates per load) ----------------
__global__ __launch_bounds__(256) void k_knn_sel(const __half2* __restrict__ D, int* __restrict__ idx){
  __shared__ float2 bufs[4][32];
  int l = threadIdx.x&63;
  int wid = threadIdx.x>>6;
  int q = blockIdx.x*4 + wid;
  int b = q>>12, qr = q&4095;
  const __half2* row = D + ((size_t)b<<23) + ((size_t)qr<<11);
  float2* buf = bufs[wid];
  __half2 h0 = row[l];
  __half2 nh = row[l + 64];        // prefetch batch 1
  float2 f0 = __half22float2(h0);
  float dmin, dmax; int mmin, mmax;
  if(f0.x <= f0.y){ dmin=f0.x; mmin=2*l;   dmax=f0.y; mmax=2*l+1; }
  else            { dmin=f0.y; mmin=2*l+1; dmax=f0.x; mmax=2*l;   }
  bitonic64(dmin, mmin, l);
  float lv = (l<32) ? dmin : 3.4e38f;
  int li = (l<32) ? mmin : 0x7fffffff;
  float thr = rlane(lv, 31);
  int cnt = 0;
  topk_buf(dmax, mmax, l, buf, cnt, thr, lv, li);
  #pragma unroll 4
  for(int j=1;j<32;j++){
    __half2 h = nh;
    nh = row[l + (((j+1)&31)<<6)];
    float2 g = __half22float2(h);
    int base = 2*(l + (j<<6));
    topk_buf(g.x, base,   l, buf, cnt, thr, lv, li);
    topk_buf(g.y, base+1, l, buf, cnt, thr, lv, li);
  }
  if(cnt) kmerge(buf, cnt, l, lv, li);
  if(l < 32) idx[(size_t)q*KK + l] = li;
}

// ---------------- gaussian kernel conv ----------------
__global__ __launch_bounds__(128) void k_gauss(const float* __restrict__ pts, const float* __restrict__ sqp,
                                               const int* __restrict__ idxP, const float* __restrict__ cen,
                                               float* __restrict__ kout){
  __shared__ float nbx[KK], nby[KK], nbz[KK], nsq[KK];
  int p = blockIdx.x; int b = p>>12; int t = threadIdx.x;
  if(t < KK){
    int id = idxP[(size_t)p*KK + t] + (b<<12);
    nbx[t]=pts[id*3]; nby[t]=pts[id*3+1]; nbz[t]=pts[id*3+2];
    nsq[t]=sqp[id];
  }
  __syncthreads();
  float c0=cen[t*3], c1=cen[t*3+1], c2=cen[t*3+2];
  float sqc=(c0*c0+c1*c1)+c2*c2;
  float acc=0.f;
  #pragma unroll
  for(int k=0;k<KK;k++){
    float dot = nbx[k]*c0 + nby[k]*c1 + nbz[k]*c2;
    float d = (nsq[k] - 2.0f*dot) + sqc;
    acc += __expf(-0.5f*d);
  }
  kout[(size_t)((b<<7)+t)*4096 + (p&4095)] = acc;
}

// ---------------- finalize BN stats ----------------
__global__ void k_fin(const float* __restrict__ psum, const float* __restrict__ psq, int NW, int C, float Nn,
                      const float* __restrict__ g, const float* __restrict__ be,
                      float* __restrict__ sc, float* __restrict__ sh){
  int o = blockIdx.x, t = threadIdx.x;
  float s=0.f, q=0.f;
  for(int w=t; w<NW; w+=256){ s += psum[(size_t)w*C+o]; q += psq[(size_t)w*C+o]; }
  __shared__ float ls[256], lq[256];
  ls[t]=s; lq[t]=q; __syncthreads();
  for(int st=128; st; st>>=1){ if(t<st){ ls[t]+=ls[t+st]; lq[t]+=lq[t+st]; } __syncthreads(); }
  if(t==0){
    float mu = ls[0]/Nn;
    float var = lq[0]/Nn - mu*mu; if(var<0.f) var=0.f;
    float s1 = g[o]*rsqrtf(var + EPSB);
    sc[o]=s1; sh[o]=be[o]-mu*s1;
  }
}

// ---------------- edge-conv 1 BN1 stats via feature moments ----------------
__global__ __launch_bounds__(256) void k_ec1mom(const float* __restrict__ xe0, const int* __restrict__ idx1,
                                                float* __restrict__ pmom){
  int tid = blockIdx.x*256 + threadIdx.x;      // < 131072
  int l = threadIdx.x & 63;
  int wid = tid >> 6;                           // < 2048
  float a[27];
  #pragma unroll
  for(int v=0;v<27;v++) a[v]=0.f;
  #pragma unroll
  for(int u=0;u<2;u++){
    int s = tid*2 + u;
    int p = s>>5;
    int bb = (p>>12)<<12;
    int id = bb + idx1[s];
    const float* nb = xe0 + (size_t)id*3;
    const float* xc = xe0 + (size_t)p*3;
    float f[6];
    f[0]=nb[0]-xc[0]; f[1]=nb[1]-xc[1]; f[2]=nb[2]-xc[2];
    f[3]=xc[0]; f[4]=xc[1]; f[5]=xc[2];
    int v=0;
    #pragma unroll
    for(int i=0;i<6;i++){
      #pragma unroll
      for(int j=i;j<6;j++){ a[v] = fmaf(f[i], f[j], a[v]); v++; }
    }
    #pragma unroll
    for(int i=0;i<6;i++) a[21+i] += f[i];
  }
  #pragma unroll
  for(int v=0;v<27;v++){
    float t = a[v];
    #pragma unroll
    for(int off=32; off; off>>=1) t += __shfl_xor(t, off);
    if(l==0) pmom[v*2048 + wid] = t;
  }
}

__global__ void k_msum(const float* __restrict__ pmom, float* __restrict__ mom){
  int v = blockIdx.x; int t = threadIdx.x;
  float s=0.f;
  for(int i=t;i<2048;i+=256) s += pmom[v*2048+i];
  __shared__ float ls[256];
  ls[t]=s; __syncthreads();
  for(int st=128; st; st>>=1){ if(t<st) ls[t]+=ls[t+st]; __syncthreads(); }
  if(t==0) mom[v]=ls[0];
}

__global__ void k_ec1bn(const float* __restrict__ mom, const float* __restrict__ w1,
                        const float* __restrict__ g, const float* __restrict__ be,
                        float* __restrict__ sc, float* __restrict__ sh){
  __shared__ float M[27];
  int t = threadIdx.x;
  if(t<27) M[t]=mom[t];
  __syncthreads();
  if(t<64){
    float w[6];
    #pragma unroll
    for(int c=0;c<6;c++) w[c]=w1[t*6+c];
    float qf=0.f, m1=0.f;
    int v=0;
    #pragma unroll
    for(int i=0;i<6;i++){
      #pragma unroll
      for(int j=i;j<6;j++){ qf += (i==j?1.f:2.f)*w[i]*w[j]*M[v]; v++; }
    }
    #pragma unroll
    for(int i=0;i<6;i++) m1 += w[i]*M[21+i];
    float N = 262144.f;
    float mu = m1/N;
    float var = qf/N - mu*mu; if(var<0.f) var=0.f;
    float s1 = g[t]*rsqrtf(var + EPSB);
    sc[t]=s1; sh[t]=be[t]-mu*s1;
  }
}

// ---------------- edge-conv 1 fused ----------------
__global__ __launch_bounds__(256) void k_ec1g2(const float* __restrict__ xe0, const int* __restrict__ idx1,
                                               const float* __restrict__ w1, const float* __restrict__ w2T,
                                               const float* __restrict__ s1, const float* __restrict__ t1,
                                               float* __restrict__ h2m, float* __restrict__ psum,
                                               float* __restrict__ psq){
  __shared__ float As[64*64];
  __shared__ float Bs[64*132];
  __shared__ float feat[6][128];
  __shared__ float w1l[384];
  int t = threadIdx.x;
  int blk = blockIdx.x;
  int s0 = blk*128;
  int pbase = s0>>5;
  int bb = (s0>>17)<<12;
  #pragma unroll
  for(int i=0;i<16;i++) As[t + i*256] = w2T[t + i*256];
  for(int i=t; i<384; i+=256) w1l[i] = w1[i];
  if(t < 128){
    int s = s0 + t;
    int p = pbase + (t>>5);
    int id = bb + idx1[s];
    const float* nb = xe0 + (size_t)id*3;
    const float* xc = xe0 + (size_t)p*3;
    float x0 = xc[0], x1 = xc[1], x2 = xc[2];
    feat[0][t] = nb[0]-x0; feat[1][t] = nb[1]-x1; feat[2][t] = nb[2]-x2;
    feat[3][t] = x0; feat[4][t] = x1; feat[5][t] = x2;
  }
  __syncthreads();
  #pragma unroll
  for(int i=0;i<32;i++){
    int e = t + (i<<8);
    int k = e>>7, n = e&127;
    float h = w1l[k*6+0]*feat[0][n] + w1l[k*6+1]*feat[1][n] + w1l[k*6+2]*feat[2][n]
            + w1l[k*6+3]*feat[3][n] + w1l[k*6+4]*feat[4][n] + w1l[k*6+5]*feat[5][n];
    Bs[k*132 + n] = lrelu(fmaf(h, s1[k], t1[k]));
  }
  __syncthreads();
  int tx = t&15, ty = t>>4;
  float acc[4][8];
  #pragma unroll
  for(int i=0;i<4;i++){
    #pragma unroll
    for(int j=0;j<8;j++) acc[i][j]=0.f;
  }
  #pragma unroll 4
  for(int k=0;k<64;k++){
    float4 a  = *(const float4*)&As[k*64 + ty*4];
    float4 b0 = *(const float4*)&Bs[k*132 + tx*4];
    float4 b1 = *(const float4*)&Bs[k*132 + 64 + tx*4];
    float av[4] = {a.x,a.y,a.z,a.w};
    float bv[8] = {b0.x,b0.y,b0.z,b0.w,b1.x,b1.y,b1.z,b1.w};
    #pragma unroll
    for(int i=0;i<4;i++){
      #pragma unroll
      for(int j=0;j<8;j++) acc[i][j] = fmaf(av[i], bv[j], acc[i][j]);
    }
  }
  #pragma unroll
  for(int i=0;i<4;i++){
    int m = ty*4 + i;
    float sr = ((acc[i][0]+acc[i][1])+(acc[i][2]+acc[i][3])) + ((acc[i][4]+acc[i][5])+(acc[i][6]+acc[i][7]));
    float sq = ((acc[i][0]*acc[i][0]+acc[i][1]*acc[i][1])+(acc[i][2]*acc[i][2]+acc[i][3]*acc[i][3]))
             + ((acc[i][4]*acc[i][4]+acc[i][5]*acc[i][5])+(acc[i][6]*acc[i][6]+acc[i][7]*acc[i][7]));
    #pragma unroll
    for(int off=1; off<16; off<<=1){ sr += __shfl_xor(sr, off); sq += __shfl_xor(sq, off); }
    if(tx==0){ psum[(size_t)blk*64+m]=sr; psq[(size_t)blk*64+m]=sq; }
    float m0 = fmaxf(fmaxf(acc[i][0],acc[i][1]), fmaxf(acc[i][2],acc[i][3]));
    float m1 = fmaxf(fmaxf(acc[i][4],acc[i][5]), fmaxf(acc[i][6],acc[i][7]));
    #pragma unroll
    for(int off=1; off<8; off<<=1){ m0 = fmaxf(m0, __shfl_xor(m0, off)); m1 = fmaxf(m1, __shfl_xor(m1, off)); }
    if((tx&7)==0){
      int pl = pbase + (tx>>3);
      h2m[(size_t)pl*64 + m]     = m0;
      h2m[(size_t)(pl+2)*64 + m] = m1;
    }
  }
}

// ---------------- ec1 finalize ----------------
__global__ __launch_bounds__(256) void k_ec1fin(const float* __restrict__ h2m, const float* __restrict__ s2,
                                                const float* __restrict__ t2, float* __restrict__ xe1,
                                                float* __restrict__ xe1T, float* __restrict__ sqx){
  int gid = blockIdx.x*256 + threadIdx.x;  // < NP*64
  int p = gid>>6, l = gid&63;
  float v = lrelu(fmaf(h2m[(size_t)p*64+l], s2[l], t2[l]));
  xe1[(size_t)p*64+l] = v;
  int b=p>>12, pr=p&4095;
  xe1T[(size_t)(b*64+l)*4096 + pr] = v;
  float sq = v*v;
  #pragma unroll
  for(int off=32; off; off>>=1) sq += __shfl_xor(sq, off);
  if(l==0) sqx[p]=sq;
}

// ---------------- D (fp16) via bf16 MFMA: block (mb,nb,b); writes transposed (D symmetric) ----------------
__global__ __launch_bounds__(256) void k_dgemm_m(const short* __restrict__ X, const float* __restrict__ sqx,
                                                 __half* __restrict__ D){
  __shared__ short sA[8192], sB[8192];
  int t = threadIdx.x;
  int lane = t&63, w = t>>6;
  int wm4 = (w>>1)*4, wn4 = (w&1)*4;
  int mb = blockIdx.y, nb = blockIdx.x, b = blockIdx.z;
  const short* AG = X + (size_t)(b*32 + mb)*8192;
  const short* BG = X + (size_t)(b*32 + nb)*8192;
  #pragma unroll
  for(int i=0;i<4;i++){
    int slot = t + i*256;
    *(s8v*)&sA[slot*8] = *(const s8v*)&AG[slot*8];
    *(s8v*)&sB[slot*8] = *(const s8v*)&BG[slot*8];
  }
  __syncthreads();
  f4v acc[4][4];
  #pragma unroll
  for(int i=0;i<4;i++){
    #pragma unroll
    for(int j=0;j<4;j++) acc[i][j] = (f4v)(0.f);
  }
  #pragma unroll
  for(int kh=0;kh<2;kh++){
    s8v av[4], bv[4];
    #pragma unroll
    for(int f=0;f<4;f++) av[f] = *(const s8v*)&sA[(kh*8 + wm4 + f)*512 + lane*8];
    #pragma unroll
    for(int f=0;f<4;f++) bv[f] = *(const s8v*)&sB[(kh*8 + wn4 + f)*512 + lane*8];
    #pragma unroll
    for(int fm=0;fm<4;fm++){
      #pragma unroll
      for(int fn=0;fn<4;fn++)
        acc[fm][fn] = __builtin_amdgcn_mfma_f32_16x16x32_bf16(av[fm], bv[fn], acc[fm][fn], 0, 0, 0);
    }
  }
  const float* sb = sqx + (b<<12);
  __half* Db = D + ((size_t)b<<24);
  int l15 = lane&15, l4 = (lane>>4)*4;
  #pragma unroll
  for(int fm=0;fm<4;fm++){
    int m0 = mb*128 + wm4*16 + fm*16 + l4;
    float sm0 = sb[m0], sm1 = sb[m0+1], sm2 = sb[m0+2], sm3 = sb[m0+3];
    #pragma unroll
    for(int fn=0;fn<4;fn++){
      int n = nb*128 + wn4*16 + fn*16 + l15;
      float sqn = sb[n];
      __half2 h01 = __floats2half2_rn((sm0 + sqn) - 2.f*acc[fm][fn][0],
                                      (sm1 + sqn) - 2.f*acc[fm][fn][1]);
      __half2 h23 = __floats2half2_rn((sm2 + sqn) - 2.f*acc[fm][fn][2],
                                      (sm3 + sqn) - 2.f*acc[fm][fn][3]);
      __half2* p = (__half2*)&Db[(size_t)n*4096 + m0];
      p[0] = h01; p[1] = h23;
    }
  }
}

// ---------------- edge-conv 2 pass 1 (bf16 MFMA gather-GEMM; h1 stored bf16) ----------------
__global__ __launch_bounds__(256) void k_ec2m1(const float* __restrict__ xe1, const int* __restrict__ idx2,
                                               const short* __restrict__ wb, short* __restrict__ h1,
                                               float* __restrict__ psum, float* __restrict__ psq){
  __shared__ short sA[8192], sB[8192];
  __shared__ float cts[4][64];
  __shared__ int nid[128];
  __shared__ float srs[2][128], srq[2][128];
  int t = threadIdx.x;
  int blk = blockIdx.x;
  int s0 = blk*128;
  int pbase = s0>>5;
  int bb = (s0>>17)<<12;
  if(t<128) nid[t] = (idx2[s0+t] + bb)<<6;
  cts[t>>6][t&63] = xe1[(size_t)(pbase + (t>>6))*64 + (t&63)];
  int lane = t&63, w = t>>6;
  int wm4 = (w>>1)*4, wn4 = (w&1)*4;
  f4v acc[4][4];
  #pragma unroll
  for(int i=0;i<4;i++){
    #pragma unroll
    for(int j=0;j<4;j++) acc[i][j] = (f4v)(0.f);
  }
  for(int st=0; st<2; ++st){
    __syncthreads();
    #pragma unroll
    for(int i=0;i<4;i++){
      int slot = t + i*256;
      *(s8v*)&sA[slot*8] = *(const s8v*)&wb[st*8192 + slot*8];
      int chunk = slot>>6, li = slot&63;
      int n = (chunk&7)*16 + (li&15);
      int c = ((chunk>>3)<<5) + ((li>>4)<<3);
      float v[8];
      if(st==0){
        const float* src = xe1 + nid[n] + c;
        float4 a0 = *(const float4*)src;
        float4 a1 = *(const float4*)(src+4);
        const float* cc = &cts[n>>5][c];
        float4 c0 = *(const float4*)cc;
        float4 c1 = *(const float4*)(cc+4);
        v[0]=a0.x-c0.x; v[1]=a0.y-c0.y; v[2]=a0.z-c0.z; v[3]=a0.w-c0.w;
        v[4]=a1.x-c1.x; v[5]=a1.y-c1.y; v[6]=a1.z-c1.z; v[7]=a1.w-c1.w;
      } else {
        const float* cc = &cts[n>>5][c];
        float4 c0 = *(const float4*)cc;
        float4 c1 = *(const float4*)(cc+4);
        v[0]=c0.x; v[1]=c0.y; v[2]=c0.z; v[3]=c0.w;
        v[4]=c1.x; v[5]=c1.y; v[6]=c1.z; v[7]=c1.w;
      }
      s8v r;
      #pragma unroll
      for(int j=0;j<8;j++) r[j] = f2bf(v[j]);
      *(s8v*)&sB[slot*8] = r;
    }
    __syncthreads();
    #pragma unroll
    for(int kh=0;kh<2;kh++){
      s8v av[4], bv[4];
      #pragma unroll
      for(int f=0;f<4;f++) av[f] = *(const s8v*)&sA[(kh*8 + wm4 + f)*512 + lane*8];
      #pragma unroll
      for(int f=0;f<4;f++) bv[f] = *(const s8v*)&sB[(kh*8 + wn4 + f)*512 + lane*8];
      #pragma unroll
      for(int fm=0;fm<4;fm++){
        #pragma unroll
        for(int fn=0;fn<4;fn++)
          acc[fm][fn] = __builtin_amdgcn_mfma_f32_16x16x32_bf16(av[fm], bv[fn], acc[fm][fn], 0, 0, 0);
      }
    }
  }
  int l15 = lane&15, l4 = (lane>>4)<<2;
  #pragma unroll
  for(int fm=0;fm<4;fm++){
    int mb_ = wm4*16 + fm*16 + l4;
    #pragma unroll
    for(int fn=0;fn<4;fn++){
      int n = wn4*16 + fn*16 + l15;
      s4v hw;
      hw[0]=f2bf(acc[fm][fn][0]); hw[1]=f2bf(acc[fm][fn][1]);
      hw[2]=f2bf(acc[fm][fn][2]); hw[3]=f2bf(acc[fm][fn][3]);
      *(s4v*)&h1[(size_t)(s0+n)*128 + mb_] = hw;
    }
    #pragma unroll
    for(int r=0;r<4;r++){
      float sr = (acc[fm][0][r]+acc[fm][1][r]) + (acc[fm][2][r]+acc[fm][3][r]);
      float sq = (acc[fm][0][r]*acc[fm][0][r]+acc[fm][1][r]*acc[fm][1][r])
               + (acc[fm][2][r]*acc[fm][2][r]+acc[fm][3][r]*acc[fm][3][r]);
      #pragma unroll
      for(int off=1; off<16; off<<=1){ sr += __shfl_xor(sr, off); sq += __shfl_xor(sq, off); }
      if(l15==0){ srs[w&1][mb_+r] = sr; srq[w&1][mb_+r] = sq; }
    }
  }
  __syncthreads();
  if(t<128){
    psum[(size_t)blk*128+t] = srs[0][t]+srs[1][t];
    psq[(size_t)blk*128+t]  = srq[0][t]+srq[1][t];
  }
}

// ---------------- edge-conv 2 pass 2 (bf16 h1 in, bf16 MFMA, fused BN1+lrelu, stats + per-point max) ----------------
__global__ __launch_bounds__(256) void k_ec2m2(const short* __restrict__ h1, const short* __restrict__ wb,
                                               const float* __restrict__ s1, const float* __restrict__ t1,
                                               float* __restrict__ h2max, float* __restrict__ psum,
                                               float* __restrict__ psq){
  __shared__ short sA[8192], sB[8192];
  __shared__ float bnS[128], bnT[128];
  __shared__ float srs[2][128], srq[2][128];
  int t = threadIdx.x;
  int blk = blockIdx.x;
  int s0 = blk*128;
  int pbase = s0>>5;
  if(t<128){ bnS[t]=s1[t]; bnT[t]=t1[t]; }
  int lane = t&63, w = t>>6;
  int wm4 = (w>>1)*4, wn4 = (w&1)*4;
  f4v acc[4][4];
  #pragma unroll
  for(int i=0;i<4;i++){
    #pragma unroll
    for(int j=0;j<4;j++) acc[i][j] = (f4v)(0.f);
  }
  for(int st=0; st<2; ++st){
    __syncthreads();
    #pragma unroll
    for(int i=0;i<4;i++){
      int slot = t + i*256;
      *(s8v*)&sA[slot*8] = *(const s8v*)&wb[st*8192 + slot*8];
      int chunk = slot>>6, li = slot&63;
      int n = (chunk&7)*16 + (li&15);
      int c = st*64 + ((chunk>>3)<<5) + ((li>>4)<<3);
      s8v hv = *(const s8v*)&h1[(size_t)(s0+n)*128 + c];
      s8v r;
      #pragma unroll
      for(int j=0;j<8;j++){
        float v = bf2f(hv[j]);
        r[j] = f2bf(lrelu(fmaf(v, bnS[c+j], bnT[c+j])));
      }
      *(s8v*)&sB[slot*8] = r;
    }
    __syncthreads();
    #pragma unroll
    for(int kh=0;kh<2;kh++){
      s8v av[4], bv[4];
      #pragma unroll
      for(int f=0;f<4;f++) av[f] = *(const s8v*)&sA[(kh*8 + wm4 + f)*512 + lane*8];
      #pragma unroll
      for(int f=0;f<4;f++) bv[f] = *(const s8v*)&sB[(kh*8 + wn4 + f)*512 + lane*8];
      #pragma unroll
      for(int fm=0;fm<4;fm++){
        #pragma unroll
        for(int fn=0;fn<4;fn++)
          acc[fm][fn] = __builtin_amdgcn_mfma_f32_16x16x32_bf16(av[fm], bv[fn], acc[fm][fn], 0, 0, 0);
      }
    }
  }
  int l15 = lane&15, l4 = (lane>>4)<<2;
  int pp0 = wn4>>1;
  #pragma unroll
  for(int fm=0;fm<4;fm++){
    int mb_ = wm4*16 + fm*16 + l4;
    #pragma unroll
    for(int r=0;r<4;r++){
      float sr = (acc[fm][0][r]+acc[fm][1][r]) + (acc[fm][2][r]+acc[fm][3][r]);
      float sq = (acc[fm][0][r]*acc[fm][0][r]+acc[fm][1][r]*acc[fm][1][r])
               + (acc[fm][2][r]*acc[fm][2][r]+acc[fm][3][r]*acc[fm][3][r]);
      float m0 = fmaxf(acc[fm][0][r], acc[fm][1][r]);
      float m1 = fmaxf(acc[fm][2][r], acc[fm][3][r]);
      #pragma unroll
      for(int off=1; off<16; off<<=1){ sr += __shfl_xor(sr, off); sq += __shfl_xor(sq, off); }
      #pragma unroll
      for(int off=1; off<16; off<<=1){ m0 = fmaxf(m0, __shfl_xor(m0, off)); m1 = fmaxf(m1, __shfl_xor(m1, off)); }
      if(l15==0){
        srs[w&1][mb_+r] = sr; srq[w&1][mb_+r] = sq;
        h2max[(size_t)(pbase+pp0)*128   + mb_+r] = m0;
        h2max[(size_t)(pbase+pp0+1)*128 + mb_+r] = m1;
      }
    }
  }
  __syncthreads();
  if(t<128){
    psum[(size_t)blk*128+t] = srs[0][t]+srs[1][t];
    psq[(size_t)blk*128+t]  = srq[0][t]+srq[1][t];
  }
}

// ---------------- xe2 = lrelu(BN(h2max)) in-place ----------------
__global__ void k_xe2fin(float* __restrict__ xe2, const float* __restrict__ s2, const float* __restrict__ t2){
  int i = blockIdx.x*256 + threadIdx.x;   // < NP*128
  if(i >= NP*128) return;
  int o = i&127;
  xe2[i] = lrelu(fmaf(xe2[i], s2[o], t2[o]));
}

// ---------------- generic small transpose ----------------
__global__ void k_transpose(const float* __restrict__ w, float* __restrict__ wT, int O, int C){
  int i = blockIdx.x*256 + threadIdx.x;
  if(i >= O*C) return;
  int o = i / C, c = i % C;
  wT[(size_t)c*O + o] = w[i];
}

// ---------------- weight fp32 -> bf16 fragment-linear ----------------
__global__ void k_wprep(const float* __restrict__ w, short* __restrict__ wb, int M, int K){
  int tid = blockIdx.x*256 + threadIdx.x;
  int m = tid % M, kb8 = tid / M;
  int k0 = kb8*8;
  float4 v0 = *(const float4*)&w[(size_t)m*K + k0];
  float4 v1 = *(const float4*)&w[(size_t)m*K + k0 + 4];
  s8v r;
  r[0]=f2bf(v0.x); r[1]=f2bf(v0.y); r[2]=f2bf(v0.z); r[3]=f2bf(v0.w);
  r[4]=f2bf(v1.x); r[5]=f2bf(v1.y); r[6]=f2bf(v1.z); r[7]=f2bf(v1.w);
  int region = (m>>7)*(K>>6) + (k0>>6);
  int chunk = ((kb8>>2)&1)*8 + ((m>>4)&7);
  int lane = (kb8&3)*16 + (m&15);
  *(s8v*)&wb[(size_t)region*8192 + chunk*512 + lane*8] = r;
}

// ---------------- activations -> bf16 fragment-linear ----------------
__global__ void k_bprep(const float* __restrict__ in, const float* __restrict__ sc, const float* __restrict__ sh,
                        short* __restrict__ ob, int K){
  int tid = blockIdx.x*256 + threadIdx.x;
  int n = tid & 8191, kb8 = tid >> 13;
  int k0 = kb8*8;
  int b = n>>12, s = n&4095;
  const float* ib = in + ((size_t)b*K + k0)*4096 + s;
  float v[8];
  #pragma unroll
  for(int j=0;j<8;j++) v[j] = ib[(size_t)j*4096];
  if(sc){
    #pragma unroll
    for(int j=0;j<8;j++) v[j] = lrelu(fmaf(v[j], sc[k0+j], sh[k0+j]));
  }
  s8v r;
  #pragma unroll
  for(int j=0;j<8;j++) r[j] = f2bf(v[j]);
  int region = (n>>7)*(K>>6) + (k0>>6);
  int chunk = ((kb8>>2)&1)*8 + ((n>>4)&7);
  int lane = (kb8&3)*16 + (n&15);
  *(s8v*)&ob[(size_t)region*8192 + chunk*512 + lane*8] = r;
}

// ---------------- layer-1 activations: read [xe2-flat ; kr] directly ----------------
__global__ void k_bprep1(const float* __restrict__ xe2, const float* __restrict__ kr,
                         short* __restrict__ ob){
  int tid = blockIdx.x*256 + threadIdx.x;   // < 8192*256/8
  int n = tid & 8191, kb8 = tid >> 13;
  int k0 = kb8*8;
  int b = n>>12, s = n&4095;
  const float* ib;
  if(k0 < 128) ib = xe2 + (size_t)b*524288 + (size_t)k0*4096 + s;
  else         ib = kr + ((size_t)(b*128 + (k0-128)))*4096 + s;
  float v[8];
  #pragma unroll
  for(int j=0;j<8;j++) v[j] = ib[(size_t)j*4096];
  s8v r;
  #pragma unroll
  for(int j=0;j<8;j++) r[j] = f2bf(v[j]);
  int region = (n>>7)*4 + (k0>>6);
  int chunk = ((kb8>>2)&1)*8 + ((n>>4)&7);
  int lane = (kb8&3)*16 + (n&15);
  *(s8v*)&ob[(size_t)region*8192 + chunk*512 + lane*8] = r;
}

// ---------------- bf16 MFMA GEMM ----------------
__global__ __launch_bounds__(256) void k_gmm(const short* __restrict__ A, const short* __restrict__ B,
                                             float* __restrict__ out, int M, int K){
  __shared__ short sA[8192], sB[8192];
  int t = threadIdx.x;
  int lane = t&63;
  int w = t>>6;
  int wm4 = (w>>1)*4, wn4 = (w&1)*4;
  int mb = blockIdx.y, nb = blockIdx.x;
  int ksteps = K>>6;
  const short* AG = A + (size_t)mb*ksteps*8192;
  const short* BG = B + (size_t)nb*ksteps*8192;
  f4v acc[4][4];
  #pragma unroll
  for(int i=0;i<4;i++){
    #pragma unroll
    for(int j=0;j<4;j++) acc[i][j] = (f4v)(0.f);
  }
  for(int st=0; st<ksteps; ++st){
    __syncthreads();
    #pragma unroll
    for(int i=0;i<4;i++){
      int slot = t + i*256;
      *(s8v*)&sA[slot*8] = *(const s8v*)&AG[(size_t)st*8192 + slot*8];
      *(s8v*)&sB[slot*8] = *(const s8v*)&BG[(size_t)st*8192 + slot*8];
    }
    __syncthreads();
    #pragma unroll
    for(int kh=0;kh<2;kh++){
      s8v av[4], bv[4];
      #pragma unroll
      for(int f=0;f<4;f++) av[f] = *(const s8v*)&sA[(kh*8 + wm4 + f)*512 + lane*8];
      #pragma unroll
      for(int f=0;f<4;f++) bv[f] = *(const s8v*)&sB[(kh*8 + wn4 + f)*512 + lane*8];
      #pragma unroll
      for(int fm=0;fm<4;fm++){
        #pragma unroll
        for(int fn=0;fn<4;fn++)
          acc[fm][fn] = __builtin_amdgcn_mfma_f32_16x16x32_bf16(av[fm], bv[fn], acc[fm][fn], 0, 0, 0);
      }
    }
  }
  int l15 = lane&15, l4 = (lane>>4)*4;
  #pragma unroll
  for(int fm=0;fm<4;fm++){
    int mrow = mb*128 + wm4*16 + fm*16 + l4;
    #pragma unroll
    for(int fn=0;fn<4;fn++){
      int n = nb*128 + wn4*16 + fn*16 + l15;
      int b = n>>12, s = n&4095;
      float* ob = out + ((size_t)b*M + mrow)*4096 + s;
      #pragma unroll
      for(int r=0;r<4;r++) ob[(size_t)r*4096] = acc[fm][fn][r];
    }
  }
}

// ---------------- per-channel stats for cbr layers ----------------
__global__ void k_cstats(const float* __restrict__ buf, int C, const float* __restrict__ g,
                         const float* __restrict__ be, float* __restrict__ sc, float* __restrict__ sh){
  int o = blockIdx.x, t = threadIdx.x;
  float s=0.f, q=0.f;
  for(int i=t;i<8192;i+=256){
    int b=i>>12, ss_=i&4095;
    float v = buf[(size_t)(b*C+o)*4096 + ss_];
    s+=v; q+=v*v;
  }
  __shared__ float ls[256], lq[256];
  ls[t]=s; lq[t]=q; __syncthreads();
  for(int st=128; st; st>>=1){ if(t<st){ ls[t]+=ls[t+st]; lq[t]+=lq[t+st]; } __syncthreads(); }
  if(t==0){
    float mu = ls[0]/8192.f;
    float var = lq[0]/8192.f - mu*mu; if(var<0.f) var=0.f;
    float s1 = g[o]*rsqrtf(var + EPSB);
    sc[o]=s1; sh[o]=be[o]-mu*s1;
  }
}

// ---------------- final layer ----------------
__global__ __launch_bounds__(256) void k_final4(const float* __restrict__ c3, const float* __restrict__ w4T,
                                                const float* __restrict__ sc, const float* __restrict__ sh,
                                                float* __restrict__ pmax){
  int b = blockIdx.y, st = blockIdx.x;
  int t = threadIdx.x; int s = st*256 + t;
  float acc[9];
  #pragma unroll
  for(int j=0;j<9;j++) acc[j]=0.f;
  const float* ib = c3 + (size_t)b*256*4096;
  for(int c=0;c<256;c++){
    float x = lrelu(fmaf(ib[(size_t)c*4096+s], sc[c], sh[c]));
    #pragma unroll
    for(int j=0;j<9;j++) acc[j]=fmaf(x, w4T[c*9+j], acc[j]);
  }
  __shared__ float red[256];
  for(int j=0;j<9;j++){
    red[t]=acc[j]; __syncthreads();
    for(int stp=128; stp; stp>>=1){ if(t<stp) red[t]=fmaxf(red[t],red[t+stp]); __syncthreads(); }
    if(t==0) pmax[(b*16+st)*9 + j]=red[0];
    __syncthreads();
  }
}

__global__ void k_out(const float* __restrict__ pmax, float* __restrict__ out){
  int i = threadIdx.x;
  if(i<18){
    int b=i/9, o=i%9;
    float m=-3.4e38f;
    for(int k=0;k<16;k++) m=fmaxf(m, pmax[(b*16+k)*9+o]);
    out[i] = m + ((o==0||o==4||o==8)?1.f:0.f);
  }
}

// ---------------- launch ----------------
extern "C" void kernel_launch(void* const* d_in, const int* in_sizes, int n_in,
                              void* d_out, int out_size, void* d_ws, size_t ws_size,
                              hipStream_t stream){
  const float* x    = (const float*)d_in[0];
  const float* kc   = (const float*)d_in[1];
  const float* e1w1 = (const float*)d_in[2];
  const float* e1g1 = (const float*)d_in[3];
  const float* e1b1 = (const float*)d_in[4];
  const float* e1w2 = (const float*)d_in[5];
  const float* e1g2 = (const float*)d_in[6];
  const float* e1b2 = (const float*)d_in[7];
  const float* e2w1 = (const float*)d_in[8];
  const float* e2g1 = (const float*)d_in[9];
  const float* e2b1 = (const float*)d_in[10];
  const float* e2w2 = (const float*)d_in[11];
  const float* e2g2 = (const float*)d_in[12];
  const float* e2b2 = (const float*)d_in[13];
  const float* w1   = (const float*)d_in[14];
  const float* g1   = (const float*)d_in[15];
  const float* b1   = (const float*)d_in[16];
  const float* w2   = (const float*)d_in[17];
  const float* g2   = (const float*)d_in[18];
  const float* b2   = (const float*)d_in[19];
  const float* w3   = (const float*)d_in[20];
  const float* g3   = (const float*)d_in[21];
  const float* b3   = (const float*)d_in[22];
  const float* w4   = (const float*)d_in[23];

  if(ws_size < 156061696ull) return;
  char* ws = (char*)d_ws;
  float* pts   = (float*)(ws + 0);
  float* xe0   = (float*)(ws + 98304);
  float* sqp   = (float*)(ws + 196608);
  float* sqe   = (float*)(ws + 229376);
  float* sqx1  = (float*)(ws + 262144);
  float* xe1   = (float*)(ws + 294912);
  float* xe1T  = (float*)(ws + 2392064);
  float* xe2   = (float*)(ws + 4489216);
  float* kr    = (float*)(ws + 8683520);
  int*   idxP  = (int*)  (ws + 12877824);
  int*   idx1  = (int*)  (ws + 13926400);
  int*   idx2  = (int*)  (ws + 14974976);
  float* psum  = (float*)(ws + 16023552);
  float* psq   = (float*)(ws + 17072128);
  float* par   = (float*)(ws + 18120704);
  float* pmax  = (float*)(ws + 18153472);
  float* e1w2T = (float*)(ws + 18157568);
  float* wT4   = (float*)(ws + 21827584);
  float* hbuf  = (float*)(ws + 21843968);
  short* wbe1  = (short*)(ws + 0);
  short* wbe2  = (short*)(ws + 65536);
  float4* pts4 = (float4*)(ws + 4489216);
  float4* xe04 = (float4*)(ws + 4489216 + 131072);
  short* actB  = (short*)(ws + 88952832);
  short* xpack = (short*)(ws + 88952832);
  short* h1b   = (short*)(ws + 21843968);   // bf16 h1, 67 MB; reuses D region (dead after knn_sel)
  short* wb1   = (short*)(ws + 105730048);
  short* wb2   = (short*)(ws + 106254336);
  short* wb3   = (short*)(ws + 107302912);
  float* pmom  = psum;
  float* momv  = psq;

  float* e1s1 = par+0;    float* e1t1 = par+64;
  float* e1s2 = par+128;  float* e1t2 = par+192;
  float* e2s1 = par+256;  float* e2t1 = par+384;
  float* e2s2 = par+512;  float* e2t2 = par+640;
  float* c1s  = par+768;  float* c1t  = par+1792;
  float* c2s  = par+2816; float* c2t  = par+3328;
  float* c3s  = par+3840; float* c3t  = par+4096;

  float* c1out = hbuf + 2097152;
  float* c2out = hbuf + 10485760;
  float* c3out = hbuf + 14680064;

  hipLaunchKernelGGL(k_prep, dim3(32), dim3(256), 0, stream, x, pts, xe0, sqp, sqe, pts4, xe04);
  hipLaunchKernelGGL(k_knn3, dim3(2048), dim3(256), 0, stream, pts4, idxP);
  hipLaunchKernelGGL(k_knn3, dim3(2048), dim3(256), 0, stream, xe04, idx1);
  hipLaunchKernelGGL(k_gauss, dim3(8192), dim3(128), 0, stream, pts, sqp, idxP, kc, kr);

  // edge-conv 1 (moment-based BN1 stats; h1 never stored)
  hipLaunchKernelGGL(k_transpose, dim3(16), dim3(256), 0, stream, e1w2, e1w2T, 64, 64);
  hipLaunchKernelGGL(k_ec1mom, dim3(512), dim3(256), 0, stream, xe0, idx1, pmom);
  hipLaunchKernelGGL(k_msum, dim3(27), dim3(256), 0, stream, pmom, momv);
  hipLaunchKernelGGL(k_ec1bn, dim3(1), dim3(64), 0, stream, momv, e1w1, e1g1, e1b1, e1s1, e1t1);
  hipLaunchKernelGGL(k_ec1g2, dim3(2048), dim3(256), 0, stream, xe0, idx1, e1w1, e1w2T, e1s1, e1t1, hbuf, psum, psq);
  hipLaunchKernelGGL(k_fin, dim3(64), dim3(256), 0, stream, psum, psq, 2048, 64, 262144.f, e1g2, e1b2, e1s2, e1t2);
  hipLaunchKernelGGL(k_ec1fin, dim3(2048), dim3(256), 0, stream, hbuf, e1s2, e1t2, xe1, xe1T, sqx1);

  // knn on 64-d features: bf16 MFMA distance GEMM (fp16-packed D) + streaming selection
  hipLaunchKernelGGL(k_wprep, dim3(256), dim3(256), 0, stream, xe1, xpack, 8192, 64);
  hipLaunchKernelGGL(k_dgemm_m, dim3(32,32,2), dim3(256), 0, stream, xpack, sqx1, (__half*)hbuf);
  hipLaunchKernelGGL(k_knn_sel, dim3(2048), dim3(256), 0, stream, (const __half2*)hbuf, idx2);

  // edge-conv 2 (bf16 MFMA formulation, h1 kept bf16, fused stats+max)
  hipLaunchKernelGGL(k_wprep, dim3(8), dim3(256), 0, stream, e2w1, wbe1, 128, 128);
  hipLaunchKernelGGL(k_wprep, dim3(8), dim3(256), 0, stream, e2w2, wbe2, 128, 128);
  hipLaunchKernelGGL(k_ec2m1, dim3(2048), dim3(256), 0, stream, xe1, idx2, wbe1, h1b, psum, psq);
  hipLaunchKernelGGL(k_fin, dim3(128), dim3(256), 0, stream, psum, psq, 2048, 128, 262144.f, e2g1, e2b1, e2s1, e2t1);
  hipLaunchKernelGGL(k_ec2m2, dim3(2048), dim3(256), 0, stream, h1b, wbe2, e2s1, e2t1, xe2, psum, psq);
  hipLaunchKernelGGL(k_fin, dim3(128), dim3(256), 0, stream, psum, psq, 2048, 128, 262144.f, e2g2, e2b2, e2s2, e2t2);
  hipLaunchKernelGGL(k_xe2fin, dim3(4096), dim3(256), 0, stream, xe2, e2s2, e2t2);

  // bf16 MFMA cbr chain (hcat fused into k_bprep1)
  hipLaunchKernelGGL(k_wprep, dim3(128), dim3(256), 0, stream, w1, wb1, 1024, 256);
  hipLaunchKernelGGL(k_wprep, dim3(256), dim3(256), 0, stream, w2, wb2, 512, 1024);
  hipLaunchKernelGGL(k_wprep, dim3(64),  dim3(256), 0, stream, w3, wb3, 256, 512);
  hipLaunchKernelGGL(k_transpose, dim3((9*256+255)/256), dim3(256), 0, stream, w4, wT4, 9, 256);

  hipLaunchKernelGGL(k_bprep1, dim3(1024), dim3(256), 0, stream, xe2, kr, actB);
  hipLaunchKernelGGL(k_gmm, dim3(64,8), dim3(256), 0, stream, wb1, actB, c1out, 1024, 256);
  hipLaunchKernelGGL(k_cstats, dim3(1024), dim3(256), 0, stream, c1out, 1024, g1, b1, c1s, c1t);

  hipLaunchKernelGGL(k_bprep, dim3(4096), dim3(256), 0, stream, c1out, c1s, c1t, actB, 1024);
  hipLaunchKernelGGL(k_gmm, dim3(64,4), dim3(256), 0, stream, wb2, actB, c2out, 512, 1024);
  hipLaunchKernelGGL(k_cstats, dim3(512), dim3(256), 0, stream, c2out, 512, g2, b2, c2s, c2t);

  hipLaunchKernelGGL(k_bprep, dim3(2048), dim3(256), 0, stream, c2out, c2s, c2t, actB, 512);
  hipLaunchKernelGGL(k_gmm, dim3(64,2), dim3(256), 0, stream, wb3, actB, c3out, 256, 512);
  hipLaunchKernelGGL(k_cstats, dim3(256), dim3(256), 0, stream, c3out, 256, g3, b3, c3s, c3t);

  hipLaunchKernelGGL(k_final4, dim3(16,2), dim3(256), 0, stream, c3out, wT4, c3s, c3t, pmax);
  hipLaunchKernelGGL(k_out, dim3(1), dim3(32), 0, stream, pmax, (float*)d_out);
}

// Round 22
// 516.737 us; speedup vs baseline: 1.2840x; 1.0262x over previous
//
#include <hip/hip_runtime.h>
#include <hip/hip_fp16.h>
#include <math.h>

#define WN 4096
#define NP 8192
#define KK 32
#define EPSB 1e-5f

typedef __attribute__((ext_vector_type(8))) short s8v;
typedef __attribute__((ext_vector_type(4))) short s4v;
typedef __attribute__((ext_vector_type(4))) float f4v;

__device__ __forceinline__ float lrelu(float x){ return fmaxf(x, 0.01f*x); }
__device__ __forceinline__ float rlane(float v, int c){
  return __int_as_float(__builtin_amdgcn_readlane(__float_as_int(v), c));
}
__device__ __forceinline__ short f2bf(float f){
  unsigned u = __float_as_uint(f);
  u = (u + 0x7fffu + ((u>>16)&1u)) >> 16;
  return (short)u;
}
__device__ __forceinline__ float bf2f(short s){
  return __uint_as_float(((unsigned)(unsigned short)s) << 16);
}

// ---------------- prep ----------------
__global__ void k_prep(const float* __restrict__ x, float* __restrict__ pts, float* __restrict__ xe0,
                       float* __restrict__ sqp, float* __restrict__ sqe,
                       float4* __restrict__ pts4, float4* __restrict__ xe04){
  int i = blockIdx.x*256 + threadIdx.x;
  if(i >= NP) return;
  int b = i>>12, p = i&4095;
  const float* xb = x + b*12288;
  float a0 = xb[p], a1 = xb[4096+p], a2 = xb[8192+p];
  pts[i*3+0]=a0; pts[i*3+1]=a1; pts[i*3+2]=a2;
  float sp = (a0*a0 + a1*a1) + a2*a2;
  sqp[i] = sp;
  pts4[i] = make_float4(a0,a1,a2,sp);
  float e0 = xb[p*3+0], e1 = xb[p*3+1], e2 = xb[p*3+2];
  xe0[i*3+0]=e0; xe0[i*3+1]=e1; xe0[i*3+2]=e2;
  float se = (e0*e0 + e1*e1) + e2*e2;
  sqe[i] = se;
  xe04[i] = make_float4(e0,e1,e2,se);
}

// ---------------- bitonic sort of 64 (d, idx) pairs across lanes, ascending ----------------
__device__ __forceinline__ void bitonic64(float& d, int& m, int l){
  #pragma unroll
  for(int k=2;k<=64;k<<=1){
    #pragma unroll
    for(int j=k>>1;j>0;j>>=1){
      float pd = __shfl_xor(d, j);
      int pm = __shfl_xor(m, j);
      bool pLess = (pd < d);
      bool dirUp = ((l & k) == 0);
      bool lower = ((l & j) == 0);
      bool take = dirUp ? (lower ? pLess : !pLess) : (lower ? !pLess : pLess);
      if(take){ d = pd; m = pm; }
    }
  }
}

// ---------------- merge sorted list (lanes 0..31) with LDS reservoir (cnt entries) ----------------
__device__ __forceinline__ void kmerge(const float2* __restrict__ buf, int cnt, int l,
                                       float& lv, int& li){
  __builtin_amdgcn_wave_barrier();       // ensure buffered ds_writes are ordered before reads
  float md; int mi;
  if(l < 32){ md = lv; mi = li; }
  else{
    int i = l - 32;
    if(i < cnt){ float2 e = buf[i]; md = e.x; mi = __float_as_int(e.y); }
    else{ md = 3.4e38f; mi = 0x7fffffff; }
  }
  bitonic64(md, mi, l);
  if(l < 32){ lv = md; li = mi; }
}

// ---------------- buffered streaming top-32 insert (reservoir; exact) ----------------
// thr only tightens at merges; d >= thr is always a safe reject.
__device__ __forceinline__ void topk_buf(float d, int m, int l, float2* __restrict__ buf,
                                         int& cnt, float& thr, float& lv, int& li){
  bool alive = d < thr;
  unsigned long long mask = __ballot(alive);
  while(mask){
    int nsurv = __popcll(mask);
    int space = 32 - cnt;                      // cnt in [0,31] here -> space >= 1
    int prefix = __popcll(mask & ((1ull<<l)-1ull));
    bool store = alive && (prefix < space);
    if(store) buf[cnt + prefix] = make_float2(d, __int_as_float(m));
    cnt += (nsurv < space) ? nsurv : space;
    alive = alive && !store;
    if(cnt == 32){
      kmerge(buf, 32, l, lv, li);
      cnt = 0;
      thr = rlane(lv, 31);
      alive = alive && (d < thr);
    }
    mask = __ballot(alive);
  }
}

// ---------------- KNN on 3-D points (reservoir selection) ----------------
__global__ __launch_bounds__(256) void k_knn3(const float4* __restrict__ pnt4, int* __restrict__ idx){
  __shared__ float2 bufs[4][32];
  int l = threadIdx.x&63;
  int wid = threadIdx.x>>6;
  int q = blockIdx.x*4 + wid;
  int b = q>>12, qr = q&4095;
  const float4* pb = pnt4 + ((size_t)b<<12);
  float2* buf = bufs[wid];
  float4 qv = pb[qr];
  float q0=qv.x, q1=qv.y, q2=qv.z, sqq=qv.w;
  float4 nc = pb[l + 64];          // prefetch batch 1
  float dd; int mm = l;
  {
    float4 c = pb[l];
    float dot = q0*c.x + q1*c.y + q2*c.z;
    dd = (sqq - 2.0f*dot) + c.w;
  }
  bitonic64(dd, mm, l);
  float lv = (l<32) ? dd : 3.4e38f;
  int li = (l<32) ? mm : 0x7fffffff;
  float thr = rlane(lv, 31);
  int cnt = 0;
  #pragma unroll 4
  for(int j=1;j<64;j++){
    float4 c = nc;
    nc = pb[l + (((j+1)&63)<<6)];
    float dot = q0*c.x + q1*c.y + q2*c.z;
    float d = (sqq - 2.0f*dot) + c.w;
    topk_buf(d, l + (j<<6), l, buf, cnt, thr, lv, li);
  }
  if(cnt) kmerge(buf, cnt, l, lv, li);
  if(l < 32) idx[(size_t)q*KK + l] = li;
}

// ---------------- KNN selection from fp16-packed D (reservoir; 2 candidates per load) ----------------
__global__ __launch_bounds__(256) void k_knn_sel(const __half2* __restrict__ D, int* __restrict__ idx){
  __shared__ float2 bufs[4][32];
  int l = threadIdx.x&63;
  int wid = threadIdx.x>>6;
  int q = blockIdx.x*4 + wid;
  int b = q>>12, qr = q&4095;
  const __half2* row = D + ((size_t)b<<23) + ((size_t)qr<<11);
  float2* buf = bufs[wid];
  __half2 h0 = row[l];
  __half2 nh = row[l + 64];        // prefetch batch 1
  float2 f0 = __half22float2(h0);
  float dmin, dmax; int mmin, mmax;
  if(f0.x <= f0.y){ dmin=f0.x; mmin=2*l;   dmax=f0.y; mmax=2*l+1; }
  else            { dmin=f0.y; mmin=2*l+1; dmax=f0.x; mmax=2*l;   }
  bitonic64(dmin, mmin, l);
  float lv = (l<32) ? dmin : 3.4e38f;
  int li = (l<32) ? mmin : 0x7fffffff;
  float thr = rlane(lv, 31);
  int cnt = 0;
  topk_buf(dmax, mmax, l, buf, cnt, thr, lv, li);
  #pragma unroll 4
  for(int j=1;j<32;j++){
    __half2 h = nh;
    nh = row[l + (((j+1)&31)<<6)];
    float2 g = __half22float2(h);
    int base = 2*(l + (j<<6));
    topk_buf(g.x, base,   l, buf, cnt, thr, lv, li);
    topk_buf(g.y, base+1, l, buf, cnt, thr, lv, li);
  }
  if(cnt) kmerge(buf, cnt, l, lv, li);
  if(l < 32) idx[(size_t)q*KK + l] = li;
}

// ---------------- gaussian kernel conv ----------------
__global__ __launch_bounds__(128) void k_gauss(const float* __restrict__ pts, const float* __restrict__ sqp,
                                               const int* __restrict__ idxP, const float* __restrict__ cen,
                                               float* __restrict__ kout){
  __shared__ float nbx[KK], nby[KK], nbz[KK], nsq[KK];
  int p = blockIdx.x; int b = p>>12; int t = threadIdx.x;
  if(t < KK){
    int id = idxP[(size_t)p*KK + t] + (b<<12);
    nbx[t]=pts[id*3]; nby[t]=pts[id*3+1]; nbz[t]=pts[id*3+2];
    nsq[t]=sqp[id];
  }
  __syncthreads();
  float c0=cen[t*3], c1=cen[t*3+1], c2=cen[t*3+2];
  float sqc=(c0*c0+c1*c1)+c2*c2;
  float acc=0.f;
  #pragma unroll
  for(int k=0;k<KK;k++){
    float dot = nbx[k]*c0 + nby[k]*c1 + nbz[k]*c2;
    float d = (nsq[k] - 2.0f*dot) + sqc;
    acc += __expf(-0.5f*d);
  }
  kout[(size_t)((b<<7)+t)*4096 + (p&4095)] = acc;
}

// ---------------- finalize BN stats ----------------
__global__ void k_fin(const float* __restrict__ psum, const float* __restrict__ psq, int NW, int C, float Nn,
                      const float* __restrict__ g, const float* __restrict__ be,
                      float* __restrict__ sc, float* __restrict__ sh){
  int o = blockIdx.x, t = threadIdx.x;
  float s=0.f, q=0.f;
  for(int w=t; w<NW; w+=256){ s += psum[(size_t)w*C+o]; q += psq[(size_t)w*C+o]; }
  __shared__ float ls[256], lq[256];
  ls[t]=s; lq[t]=q; __syncthreads();
  for(int st=128; st; st>>=1){ if(t<st){ ls[t]+=ls[t+st]; lq[t]+=lq[t+st]; } __syncthreads(); }
  if(t==0){
    float mu = ls[0]/Nn;
    float var = lq[0]/Nn - mu*mu; if(var<0.f) var=0.f;
    float s1 = g[o]*rsqrtf(var + EPSB);
    sc[o]=s1; sh[o]=be[o]-mu*s1;
  }
}

// ---------------- edge-conv 1 BN1 stats via feature moments ----------------
__global__ __launch_bounds__(256) void k_ec1mom(const float* __restrict__ xe0, const int* __restrict__ idx1,
                                                float* __restrict__ pmom){
  int tid = blockIdx.x*256 + threadIdx.x;      // < 131072
  int l = threadIdx.x & 63;
  int wid = tid >> 6;                           // < 2048
  float a[27];
  #pragma unroll
  for(int v=0;v<27;v++) a[v]=0.f;
  #pragma unroll
  for(int u=0;u<2;u++){
    int s = tid*2 + u;
    int p = s>>5;
    int bb = (p>>12)<<12;
    int id = bb + idx1[s];
    const float* nb = xe0 + (size_t)id*3;
    const float* xc = xe0 + (size_t)p*3;
    float f[6];
    f[0]=nb[0]-xc[0]; f[1]=nb[1]-xc[1]; f[2]=nb[2]-xc[2];
    f[3]=xc[0]; f[4]=xc[1]; f[5]=xc[2];
    int v=0;
    #pragma unroll
    for(int i=0;i<6;i++){
      #pragma unroll
      for(int j=i;j<6;j++){ a[v] = fmaf(f[i], f[j], a[v]); v++; }
    }
    #pragma unroll
    for(int i=0;i<6;i++) a[21+i] += f[i];
  }
  #pragma unroll
  for(int v=0;v<27;v++){
    float t = a[v];
    #pragma unroll
    for(int off=32; off; off>>=1) t += __shfl_xor(t, off);
    if(l==0) pmom[v*2048 + wid] = t;
  }
}

__global__ void k_msum(const float* __restrict__ pmom, float* __restrict__ mom){
  int v = blockIdx.x; int t = threadIdx.x;
  float s=0.f;
  for(int i=t;i<2048;i+=256) s += pmom[v*2048+i];
  __shared__ float ls[256];
  ls[t]=s; __syncthreads();
  for(int st=128; st; st>>=1){ if(t<st) ls[t]+=ls[t+st]; __syncthreads(); }
  if(t==0) mom[v]=ls[0];
}

__global__ void k_ec1bn(const float* __restrict__ mom, const float* __restrict__ w1,
                        const float* __restrict__ g, const float* __restrict__ be,
                        float* __restrict__ sc, float* __restrict__ sh){
  __shared__ float M[27];
  int t = threadIdx.x;
  if(t<27) M[t]=mom[t];
  __syncthreads();
  if(t<64){
    float w[6];
    #pragma unroll
    for(int c=0;c<6;c++) w[c]=w1[t*6+c];
    float qf=0.f, m1=0.f;
    int v=0;
    #pragma unroll
    for(int i=0;i<6;i++){
      #pragma unroll
      for(int j=i;j<6;j++){ qf += (i==j?1.f:2.f)*w[i]*w[j]*M[v]; v++; }
    }
    #pragma unroll
    for(int i=0;i<6;i++) m1 += w[i]*M[21+i];
    float N = 262144.f;
    float mu = m1/N;
    float var = qf/N - mu*mu; if(var<0.f) var=0.f;
    float s1 = g[t]*rsqrtf(var + EPSB);
    sc[t]=s1; sh[t]=be[t]-mu*s1;
  }
}

// ---------------- edge-conv 1 fused (bf16 MFMA second layer) ----------------
// Per block: 128 neighbor-samples = 4 points. A = w2 (64x64, frag-packed), B = h (bf16, packed in-kernel).
// Each warp owns one point's 32 columns -> per-point max via 2-col fmax + l15 shfl-reduce.
__global__ __launch_bounds__(256) void k_ec1g2m(const float* __restrict__ xe0, const int* __restrict__ idx1,
                                                const short* __restrict__ w2b, const float* __restrict__ w1,
                                                const float* __restrict__ s1, const float* __restrict__ t1,
                                                float* __restrict__ h2m, float* __restrict__ psum,
                                                float* __restrict__ psq){
  __shared__ short sA[8192], sB[8192];
  __shared__ float feat[6][128];
  __shared__ float w1l[384];
  __shared__ float bnS[64], bnT[64];
  __shared__ float srs[4][64], srq[4][64];
  int t = threadIdx.x;
  int blk = blockIdx.x;
  int s0 = blk*128;
  int pbase = s0>>5;
  int bb = (s0>>17)<<12;
  #pragma unroll
  for(int i=0;i<4;i++){
    int slot = t + i*256;
    *(s8v*)&sA[slot*8] = *(const s8v*)&w2b[slot*8];
  }
  for(int i=t; i<384; i+=256) w1l[i] = w1[i];
  if(t<64){ bnS[t]=s1[t]; bnT[t]=t1[t]; }
  if(t < 128){
    int s = s0 + t;
    int p = pbase + (t>>5);
    int id = bb + idx1[s];
    const float* nb = xe0 + (size_t)id*3;
    const float* xc = xe0 + (size_t)p*3;
    float x0 = xc[0], x1 = xc[1], x2 = xc[2];
    feat[0][t] = nb[0]-x0; feat[1][t] = nb[1]-x1; feat[2][t] = nb[2]-x2;
    feat[3][t] = x0; feat[4][t] = x1; feat[5][t] = x2;
  }
  __syncthreads();
  // h = lrelu(BN1(w1·feat)) packed straight into bf16 B fragments
  #pragma unroll
  for(int i=0;i<4;i++){
    int e = t + (i<<8);           // 0..1023 : (n, kb8)
    int n = e & 127;
    int kb8 = e >> 7;             // 0..7
    int k0 = kb8*8;
    float f0=feat[0][n], f1=feat[1][n], f2=feat[2][n];
    float f3=feat[3][n], f4=feat[4][n], f5=feat[5][n];
    s8v r;
    #pragma unroll
    for(int j=0;j<8;j++){
      int k = k0 + j;
      float h = w1l[k*6+0]*f0 + w1l[k*6+1]*f1 + w1l[k*6+2]*f2
              + w1l[k*6+3]*f3 + w1l[k*6+4]*f4 + w1l[k*6+5]*f5;
      r[j] = f2bf(lrelu(fmaf(h, bnS[k], bnT[k])));
    }
    int chunk = (k0>>5)*8 + (n>>4);
    int lane_ = ((k0>>3)&3)*16 + (n&15);
    *(s8v*)&sB[chunk*512 + lane_*8] = r;
  }
  __syncthreads();
  int lane = t&63, w = t>>6;
  f4v acc[4][2];
  #pragma unroll
  for(int i=0;i<4;i++){
    #pragma unroll
    for(int j=0;j<2;j++) acc[i][j] = (f4v)(0.f);
  }
  #pragma unroll
  for(int kh=0;kh<2;kh++){
    s8v av[4], bv[2];
    #pragma unroll
    for(int f=0;f<4;f++) av[f] = *(const s8v*)&sA[(kh*8 + f)*512 + lane*8];
    #pragma unroll
    for(int g=0;g<2;g++) bv[g] = *(const s8v*)&sB[(kh*8 + w*2 + g)*512 + lane*8];
    #pragma unroll
    for(int fm=0;fm<4;fm++){
      #pragma unroll
      for(int fn=0;fn<2;fn++)
        acc[fm][fn] = __builtin_amdgcn_mfma_f32_16x16x32_bf16(av[fm], bv[fn], acc[fm][fn], 0, 0, 0);
    }
  }
  int l15 = lane&15, l4 = (lane>>4)*4;
  int point = pbase + w;
  #pragma unroll
  for(int fm=0;fm<4;fm++){
    #pragma unroll
    for(int r=0;r<4;r++){
      int m = fm*16 + l4 + r;
      float a0 = acc[fm][0][r], a1 = acc[fm][1][r];
      float sr = a0 + a1;
      float sq = a0*a0 + a1*a1;
      float mx = fmaxf(a0, a1);
      #pragma unroll
      for(int off=1; off<16; off<<=1){
        sr += __shfl_xor(sr, off);
        sq += __shfl_xor(sq, off);
        mx = fmaxf(mx, __shfl_xor(mx, off));
      }
      if(l15==0){
        srs[w][m] = sr; srq[w][m] = sq;
        h2m[(size_t)point*64 + m] = mx;
      }
    }
  }
  __syncthreads();
  if(t<64){
    psum[(size_t)blk*64+t] = (srs[0][t]+srs[1][t]) + (srs[2][t]+srs[3][t]);
    psq[(size_t)blk*64+t]  = (srq[0][t]+srq[1][t]) + (srq[2][t]+srq[3][t]);
  }
}

// ---------------- ec1 finalize ----------------
__global__ __launch_bounds__(256) void k_ec1fin(const float* __restrict__ h2m, const float* __restrict__ s2,
                                                const float* __restrict__ t2, float* __restrict__ xe1,
                                                float* __restrict__ xe1T, float* __restrict__ sqx){
  int gid = blockIdx.x*256 + threadIdx.x;  // < NP*64
  int p = gid>>6, l = gid&63;
  float v = lrelu(fmaf(h2m[(size_t)p*64+l], s2[l], t2[l]));
  xe1[(size_t)p*64+l] = v;
  int b=p>>12, pr=p&4095;
  xe1T[(size_t)(b*64+l)*4096 + pr] = v;
  float sq = v*v;
  #pragma unroll
  for(int off=32; off; off>>=1) sq += __shfl_xor(sq, off);
  if(l==0) sqx[p]=sq;
}

// ---------------- D (fp16) via bf16 MFMA: block (mb,nb,b); writes transposed (D symmetric) ----------------
__global__ __launch_bounds__(256) void k_dgemm_m(const short* __restrict__ X, const float* __restrict__ sqx,
                                                 __half* __restrict__ D){
  __shared__ short sA[8192], sB[8192];
  int t = threadIdx.x;
  int lane = t&63, w = t>>6;
  int wm4 = (w>>1)*4, wn4 = (w&1)*4;
  int mb = blockIdx.y, nb = blockIdx.x, b = blockIdx.z;
  const short* AG = X + (size_t)(b*32 + mb)*8192;
  const short* BG = X + (size_t)(b*32 + nb)*8192;
  #pragma unroll
  for(int i=0;i<4;i++){
    int slot = t + i*256;
    *(s8v*)&sA[slot*8] = *(const s8v*)&AG[slot*8];
    *(s8v*)&sB[slot*8] = *(const s8v*)&BG[slot*8];
  }
  __syncthreads();
  f4v acc[4][4];
  #pragma unroll
  for(int i=0;i<4;i++){
    #pragma unroll
    for(int j=0;j<4;j++) acc[i][j] = (f4v)(0.f);
  }
  #pragma unroll
  for(int kh=0;kh<2;kh++){
    s8v av[4], bv[4];
    #pragma unroll
    for(int f=0;f<4;f++) av[f] = *(const s8v*)&sA[(kh*8 + wm4 + f)*512 + lane*8];
    #pragma unroll
    for(int f=0;f<4;f++) bv[f] = *(const s8v*)&sB[(kh*8 + wn4 + f)*512 + lane*8];
    #pragma unroll
    for(int fm=0;fm<4;fm++){
      #pragma unroll
      for(int fn=0;fn<4;fn++)
        acc[fm][fn] = __builtin_amdgcn_mfma_f32_16x16x32_bf16(av[fm], bv[fn], acc[fm][fn], 0, 0, 0);
    }
  }
  const float* sb = sqx + (b<<12);
  __half* Db = D + ((size_t)b<<24);
  int l15 = lane&15, l4 = (lane>>4)*4;
  #pragma unroll
  for(int fm=0;fm<4;fm++){
    int m0 = mb*128 + wm4*16 + fm*16 + l4;
    float sm0 = sb[m0], sm1 = sb[m0+1], sm2 = sb[m0+2], sm3 = sb[m0+3];
    #pragma unroll
    for(int fn=0;fn<4;fn++){
      int n = nb*128 + wn4*16 + fn*16 + l15;
      float sqn = sb[n];
      __half2 h01 = __floats2half2_rn((sm0 + sqn) - 2.f*acc[fm][fn][0],
                                      (sm1 + sqn) - 2.f*acc[fm][fn][1]);
      __half2 h23 = __floats2half2_rn((sm2 + sqn) - 2.f*acc[fm][fn][2],
                                      (sm3 + sqn) - 2.f*acc[fm][fn][3]);
      __half2* p = (__half2*)&Db[(size_t)n*4096 + m0];
      p[0] = h01; p[1] = h23;
    }
  }
}

// ---------------- edge-conv 2 pass 1 (bf16 MFMA gather-GEMM; h1 stored bf16) ----------------
__global__ __launch_bounds__(256) void k_ec2m1(const float* __restrict__ xe1, const int* __restrict__ idx2,
                                               const short* __restrict__ wb, short* __restrict__ h1,
                                               float* __restrict__ psum, float* __restrict__ psq){
  __shared__ short sA[8192], sB[8192];
  __shared__ float cts[4][64];
  __shared__ int nid[128];
  __shared__ float srs[2][128], srq[2][128];
  int t = threadIdx.x;
  int blk = blockIdx.x;
  int s0 = blk*128;
  int pbase = s0>>5;
  int bb = (s0>>17)<<12;
  if(t<128) nid[t] = (idx2[s0+t] + bb)<<6;
  cts[t>>6][t&63] = xe1[(size_t)(pbase + (t>>6))*64 + (t&63)];
  int lane = t&63, w = t>>6;
  int wm4 = (w>>1)*4, wn4 = (w&1)*4;
  f4v acc[4][4];
  #pragma unroll
  for(int i=0;i<4;i++){
    #pragma unroll
    for(int j=0;j<4;j++) acc[i][j] = (f4v)(0.f);
  }
  for(int st=0; st<2; ++st){
    __syncthreads();
    #pragma unroll
    for(int i=0;i<4;i++){
      int slot = t + i*256;
      *(s8v*)&sA[slot*8] = *(const s8v*)&wb[st*8192 + slot*8];
      int chunk = slot>>6, li = slot&63;
      int n = (chunk&7)*16 + (li&15);
      int c = ((chunk>>3)<<5) + ((li>>4)<<3);
      float v[8];
      if(st==0){
        const float* src = xe1 + nid[n] + c;
        float4 a0 = *(const float4*)src;
        float4 a1 = *(const float4*)(src+4);
        const float* cc = &cts[n>>5][c];
        float4 c0 = *(const float4*)cc;
        float4 c1 = *(const float4*)(cc+4);
        v[0]=a0.x-c0.x; v[1]=a0.y-c0.y; v[2]=a0.z-c0.z; v[3]=a0.w-c0.w;
        v[4]=a1.x-c1.x; v[5]=a1.y-c1.y; v[6]=a1.z-c1.z; v[7]=a1.w-c1.w;
      } else {
        const float* cc = &cts[n>>5][c];
        float4 c0 = *(const float4*)cc;
        float4 c1 = *(const float4*)(cc+4);
        v[0]=c0.x; v[1]=c0.y; v[2]=c0.z; v[3]=c0.w;
        v[4]=c1.x; v[5]=c1.y; v[6]=c1.z; v[7]=c1.w;
      }
      s8v r;
      #pragma unroll
      for(int j=0;j<8;j++) r[j] = f2bf(v[j]);
      *(s8v*)&sB[slot*8] = r;
    }
    __syncthreads();
    #pragma unroll
    for(int kh=0;kh<2;kh++){
      s8v av[4], bv[4];
      #pragma unroll
      for(int f=0;f<4;f++) av[f] = *(const s8v*)&sA[(kh*8 + wm4 + f)*512 + lane*8];
      #pragma unroll
      for(int f=0;f<4;f++) bv[f] = *(const s8v*)&sB[(kh*8 + wn4 + f)*512 + lane*8];
      #pragma unroll
      for(int fm=0;fm<4;fm++){
        #pragma unroll
        for(int fn=0;fn<4;fn++)
          acc[fm][fn] = __builtin_amdgcn_mfma_f32_16x16x32_bf16(av[fm], bv[fn], acc[fm][fn], 0, 0, 0);
      }
    }
  }
  int l15 = lane&15, l4 = (lane>>4)<<2;
  #pragma unroll
  for(int fm=0;fm<4;fm++){
    int mb_ = wm4*16 + fm*16 + l4;
    #pragma unroll
    for(int fn=0;fn<4;fn++){
      int n = wn4*16 + fn*16 + l15;
      s4v hw;
      hw[0]=f2bf(acc[fm][fn][0]); hw[1]=f2bf(acc[fm][fn][1]);
      hw[2]=f2bf(acc[fm][fn][2]); hw[3]=f2bf(acc[fm][fn][3]);
      *(s4v*)&h1[(size_t)(s0+n)*128 + mb_] = hw;
    }
    #pragma unroll
    for(int r=0;r<4;r++){
      float sr = (acc[fm][0][r]+acc[fm][1][r]) + (acc[fm][2][r]+acc[fm][3][r]);
      float sq = (acc[fm][0][r]*acc[fm][0][r]+acc[fm][1][r]*acc[fm][1][r])
               + (acc[fm][2][r]*acc[fm][2][r]+acc[fm][3][r]*acc[fm][3][r]);
      #pragma unroll
      for(int off=1; off<16; off<<=1){ sr += __shfl_xor(sr, off); sq += __shfl_xor(sq, off); }
      if(l15==0){ srs[w&1][mb_+r] = sr; srq[w&1][mb_+r] = sq; }
    }
  }
  __syncthreads();
  if(t<128){
    psum[(size_t)blk*128+t] = srs[0][t]+srs[1][t];
    psq[(size_t)blk*128+t]  = srq[0][t]+srq[1][t];
  }
}

// ---------------- edge-conv 2 pass 2 (bf16 h1 in, bf16 MFMA, fused BN1+lrelu, stats + per-point max) ----------------
__global__ __launch_bounds__(256) void k_ec2m2(const short* __restrict__ h1, const short* __restrict__ wb,
                                               const float* __restrict__ s1, const float* __restrict__ t1,
                                               float* __restrict__ h2max, float* __restrict__ psum,
                                               float* __restrict__ psq){
  __shared__ short sA[8192], sB[8192];
  __shared__ float bnS[128], bnT[128];
  __shared__ float srs[2][128], srq[2][128];
  int t = threadIdx.x;
  int blk = blockIdx.x;
  int s0 = blk*128;
  int pbase = s0>>5;
  if(t<128){ bnS[t]=s1[t]; bnT[t]=t1[t]; }
  int lane = t&63, w = t>>6;
  int wm4 = (w>>1)*4, wn4 = (w&1)*4;
  f4v acc[4][4];
  #pragma unroll
  for(int i=0;i<4;i++){
    #pragma unroll
    for(int j=0;j<4;j++) acc[i][j] = (f4v)(0.f);
  }
  for(int st=0; st<2; ++st){
    __syncthreads();
    #pragma unroll
    for(int i=0;i<4;i++){
      int slot = t + i*256;
      *(s8v*)&sA[slot*8] = *(const s8v*)&wb[st*8192 + slot*8];
      int chunk = slot>>6, li = slot&63;
      int n = (chunk&7)*16 + (li&15);
      int c = st*64 + ((chunk>>3)<<5) + ((li>>4)<<3);
      s8v hv = *(const s8v*)&h1[(size_t)(s0+n)*128 + c];
      s8v r;
      #pragma unroll
      for(int j=0;j<8;j++){
        float v = bf2f(hv[j]);
        r[j] = f2bf(lrelu(fmaf(v, bnS[c+j], bnT[c+j])));
      }
      *(s8v*)&sB[slot*8] = r;
    }
    __syncthreads();
    #pragma unroll
    for(int kh=0;kh<2;kh++){
      s8v av[4], bv[4];
      #pragma unroll
      for(int f=0;f<4;f++) av[f] = *(const s8v*)&sA[(kh*8 + wm4 + f)*512 + lane*8];
      #pragma unroll
      for(int f=0;f<4;f++) bv[f] = *(const s8v*)&sB[(kh*8 + wn4 + f)*512 + lane*8];
      #pragma unroll
      for(int fm=0;fm<4;fm++){
        #pragma unroll
        for(int fn=0;fn<4;fn++)
          acc[fm][fn] = __builtin_amdgcn_mfma_f32_16x16x32_bf16(av[fm], bv[fn], acc[fm][fn], 0, 0, 0);
      }
    }
  }
  int l15 = lane&15, l4 = (lane>>4)<<2;
  int pp0 = wn4>>1;
  #pragma unroll
  for(int fm=0;fm<4;fm++){
    int mb_ = wm4*16 + fm*16 + l4;
    #pragma unroll
    for(int r=0;r<4;r++){
      float sr = (acc[fm][0][r]+acc[fm][1][r]) + (acc[fm][2][r]+acc[fm][3][r]);
      float sq = (acc[fm][0][r]*acc[fm][0][r]+acc[fm][1][r]*acc[fm][1][r])
               + (acc[fm][2][r]*acc[fm][2][r]+acc[fm][3][r]*acc[fm][3][r]);
      float m0 = fmaxf(acc[fm][0][r], acc[fm][1][r]);
      float m1 = fmaxf(acc[fm][2][r], acc[fm][3][r]);
      #pragma unroll
      for(int off=1; off<16; off<<=1){ sr += __shfl_xor(sr, off); sq += __shfl_xor(sq, off); }
      #pragma unroll
      for(int off=1; off<16; off<<=1){ m0 = fmaxf(m0, __shfl_xor(m0, off)); m1 = fmaxf(m1, __shfl_xor(m1, off)); }
      if(l15==0){
        srs[w&1][mb_+r] = sr; srq[w&1][mb_+r] = sq;
        h2max[(size_t)(pbase+pp0)*128   + mb_+r] = m0;
        h2max[(size_t)(pbase+pp0+1)*128 + mb_+r] = m1;
      }
    }
  }
  __syncthreads();
  if(t<128){
    psum[(size_t)blk*128+t] = srs[0][t]+srs[1][t];
    psq[(size_t)blk*128+t]  = srq[0][t]+srq[1][t];
  }
}

// ---------------- xe2 = lrelu(BN(h2max)) in-place ----------------
__global__ void k_xe2fin(float* __restrict__ xe2, const float* __restrict__ s2, const float* __restrict__ t2){
  int i = blockIdx.x*256 + threadIdx.x;   // < NP*128
  if(i >= NP*128) return;
  int o = i&127;
  xe2[i] = lrelu(fmaf(xe2[i], s2[o], t2[o]));
}

// ---------------- generic small transpose ----------------
__global__ void k_transpose(const float* __restrict__ w, float* __restrict__ wT, int O, int C){
  int i = blockIdx.x*256 + threadIdx.x;
  if(i >= O*C) return;
  int o = i / C, c = i % C;
  wT[(size_t)c*O + o] = w[i];
}

// ---------------- weight fp32 -> bf16 fragment-linear ----------------
__global__ void k_wprep(const float* __restrict__ w, short* __restrict__ wb, int M, int K){
  int tid = blockIdx.x*256 + threadIdx.x;
  int m = tid % M, kb8 = tid / M;
  int k0 = kb8*8;
  float4 v0 = *(const float4*)&w[(size_t)m*K + k0];
  float4 v1 = *(const float4*)&w[(size_t)m*K + k0 + 4];
  s8v r;
  r[0]=f2bf(v0.x); r[1]=f2bf(v0.y); r[2]=f2bf(v0.z); r[3]=f2bf(v0.w);
  r[4]=f2bf(v1.x); r[5]=f2bf(v1.y); r[6]=f2bf(v1.z); r[7]=f2bf(v1.w);
  int region = (m>>7)*(K>>6) + (k0>>6);
  int chunk = ((kb8>>2)&1)*8 + ((m>>4)&7);
  int lane = (kb8&3)*16 + (m&15);
  *(s8v*)&wb[(size_t)region*8192 + chunk*512 + lane*8] = r;
}

// ---------------- activations -> bf16 fragment-linear ----------------
__global__ void k_bprep(const float* __restrict__ in, const float* __restrict__ sc, const float* __restrict__ sh,
                        short* __restrict__ ob, int K){
  int tid = blockIdx.x*256 + threadIdx.x;
  int n = tid & 8191, kb8 = tid >> 13;
  int k0 = kb8*8;
  int b = n>>12, s = n&4095;
  const float* ib = in + ((size_t)b*K + k0)*4096 + s;
  float v[8];
  #pragma unroll
  for(int j=0;j<8;j++) v[j] = ib[(size_t)j*4096];
  if(sc){
    #pragma unroll
    for(int j=0;j<8;j++) v[j] = lrelu(fmaf(v[j], sc[k0+j], sh[k0+j]));
  }
  s8v r;
  #pragma unroll
  for(int j=0;j<8;j++) r[j] = f2bf(v[j]);
  int region = (n>>7)*(K>>6) + (k0>>6);
  int chunk = ((kb8>>2)&1)*8 + ((n>>4)&7);
  int lane = (kb8&3)*16 + (n&15);
  *(s8v*)&ob[(size_t)region*8192 + chunk*512 + lane*8] = r;
}

// ---------------- layer-1 activations: read [xe2-flat ; kr] directly ----------------
__global__ void k_bprep1(const float* __restrict__ xe2, const float* __restrict__ kr,
                         short* __restrict__ ob){
  int tid = blockIdx.x*256 + threadIdx.x;   // < 8192*256/8
  int n = tid & 8191, kb8 = tid >> 13;
  int k0 = kb8*8;
  int b = n>>12, s = n&4095;
  const float* ib;
  if(k0 < 128) ib = xe2 + (size_t)b*524288 + (size_t)k0*4096 + s;
  else         ib = kr + ((size_t)(b*128 + (k0-128)))*4096 + s;
  float v[8];
  #pragma unroll
  for(int j=0;j<8;j++) v[j] = ib[(size_t)j*4096];
  s8v r;
  #pragma unroll
  for(int j=0;j<8;j++) r[j] = f2bf(v[j]);
  int region = (n>>7)*4 + (k0>>6);
  int chunk = ((kb8>>2)&1)*8 + ((n>>4)&7);
  int lane = (kb8&3)*16 + (n&15);
  *(s8v*)&ob[(size_t)region*8192 + chunk*512 + lane*8] = r;
}

// ---------------- bf16 MFMA GEMM ----------------
__global__ __launch_bounds__(256) void k_gmm(const short* __restrict__ A, const short* __restrict__ B,
                                             float* __restrict__ out, int M, int K){
  __shared__ short sA[8192], sB[8192];
  int t = threadIdx.x;
  int lane = t&63;
  int w = t>>6;
  int wm4 = (w>>1)*4, wn4 = (w&1)*4;
  int mb = blockIdx.y, nb = blockIdx.x;
  int ksteps = K>>6;
  const short* AG = A + (size_t)mb*ksteps*8192;
  const short* BG = B + (size_t)nb*ksteps*8192;
  f4v acc[4][4];
  #pragma unroll
  for(int i=0;i<4;i++){
    #pragma unroll
    for(int j=0;j<4;j++) acc[i][j] = (f4v)(0.f);
  }
  for(int st=0; st<ksteps; ++st){
    __syncthreads();
    #pragma unroll
    for(int i=0;i<4;i++){
      int slot = t + i*256;
      *(s8v*)&sA[slot*8] = *(const s8v*)&AG[(size_t)st*8192 + slot*8];
      *(s8v*)&sB[slot*8] = *(const s8v*)&BG[(size_t)st*8192 + slot*8];
    }
    __syncthreads();
    #pragma unroll
    for(int kh=0;kh<2;kh++){
      s8v av[4], bv[4];
      #pragma unroll
      for(int f=0;f<4;f++) av[f] = *(const s8v*)&sA[(kh*8 + wm4 + f)*512 + lane*8];
      #pragma unroll
      for(int f=0;f<4;f++) bv[f] = *(const s8v*)&sB[(kh*8 + wn4 + f)*512 + lane*8];
      #pragma unroll
      for(int fm=0;fm<4;fm++){
        #pragma unroll
        for(int fn=0;fn<4;fn++)
          acc[fm][fn] = __builtin_amdgcn_mfma_f32_16x16x32_bf16(av[fm], bv[fn], acc[fm][fn], 0, 0, 0);
      }
    }
  }
  int l15 = lane&15, l4 = (lane>>4)*4;
  #pragma unroll
  for(int fm=0;fm<4;fm++){
    int mrow = mb*128 + wm4*16 + fm*16 + l4;
    #pragma unroll
    for(int fn=0;fn<4;fn++){
      int n = nb*128 + wn4*16 + fn*16 + l15;
      int b = n>>12, s = n&4095;
      float* ob = out + ((size_t)b*M + mrow)*4096 + s;
      #pragma unroll
      for(int r=0;r<4;r++) ob[(size_t)r*4096] = acc[fm][fn][r];
    }
  }
}

// ---------------- per-channel stats for cbr layers ----------------
__global__ void k_cstats(const float* __restrict__ buf, int C, const float* __restrict__ g,
                         const float* __restrict__ be, float* __restrict__ sc, float* __restrict__ sh){
  int o = blockIdx.x, t = threadIdx.x;
  float s=0.f, q=0.f;
  for(int i=t;i<8192;i+=256){
    int b=i>>12, ss_=i&4095;
    float v = buf[(size_t)(b*C+o)*4096 + ss_];
    s+=v; q+=v*v;
  }
  __shared__ float ls[256], lq[256];
  ls[t]=s; lq[t]=q; __syncthreads();
  for(int st=128; st; st>>=1){ if(t<st){ ls[t]+=ls[t+st]; lq[t]+=lq[t+st]; } __syncthreads(); }
  if(t==0){
    float mu = ls[0]/8192.f;
    float var = lq[0]/8192.f - mu*mu; if(var<0.f) var=0.f;
    float s1 = g[o]*rsqrtf(var + EPSB);
    sc[o]=s1; sh[o]=be[o]-mu*s1;
  }
}

// ---------------- final layer ----------------
__global__ __launch_bounds__(256) void k_final4(const float* __restrict__ c3, const float* __restrict__ w4T,
                                                const float* __restrict__ sc, const float* __restrict__ sh,
                                                float* __restrict__ pmax){
  int b = blockIdx.y, st = blockIdx.x;
  int t = threadIdx.x; int s = st*256 + t;
  float acc[9];
  #pragma unroll
  for(int j=0;j<9;j++) acc[j]=0.f;
  const float* ib = c3 + (size_t)b*256*4096;
  for(int c=0;c<256;c++){
    float x = lrelu(fmaf(ib[(size_t)c*4096+s], sc[c], sh[c]));
    #pragma unroll
    for(int j=0;j<9;j++) acc[j]=fmaf(x, w4T[c*9+j], acc[j]);
  }
  __shared__ float red[256];
  for(int j=0;j<9;j++){
    red[t]=acc[j]; __syncthreads();
    for(int stp=128; stp; stp>>=1){ if(t<stp) red[t]=fmaxf(red[t],red[t+stp]); __syncthreads(); }
    if(t==0) pmax[(b*16+st)*9 + j]=red[0];
    __syncthreads();
  }
}

__global__ void k_out(const float* __restrict__ pmax, float* __restrict__ out){
  int i = threadIdx.x;
  if(i<18){
    int b=i/9, o=i%9;
    float m=-3.4e38f;
    for(int k=0;k<16;k++) m=fmaxf(m, pmax[(b*16+k)*9+o]);
    out[i] = m + ((o==0||o==4||o==8)?1.f:0.f);
  }
}

// ---------------- launch ----------------
extern "C" void kernel_launch(void* const* d_in, const int* in_sizes, int n_in,
                              void* d_out, int out_size, void* d_ws, size_t ws_size,
                              hipStream_t stream){
  const float* x    = (const float*)d_in[0];
  const float* kc   = (const float*)d_in[1];
  const float* e1w1 = (const float*)d_in[2];
  const float* e1g1 = (const float*)d_in[3];
  const float* e1b1 = (const float*)d_in[4];
  const float* e1w2 = (const float*)d_in[5];
  const float* e1g2 = (const float*)d_in[6];
  const float* e1b2 = (const float*)d_in[7];
  const float* e2w1 = (const float*)d_in[8];
  const float* e2g1 = (const float*)d_in[9];
  const float* e2b1 = (const float*)d_in[10];
  const float* e2w2 = (const float*)d_in[11];
  const float* e2g2 = (const float*)d_in[12];
  const float* e2b2 = (const float*)d_in[13];
  const float* w1   = (const float*)d_in[14];
  const float* g1   = (const float*)d_in[15];
  const float* b1   = (const float*)d_in[16];
  const float* w2   = (const float*)d_in[17];
  const float* g2   = (const float*)d_in[18];
  const float* b2   = (const float*)d_in[19];
  const float* w3   = (const float*)d_in[20];
  const float* g3   = (const float*)d_in[21];
  const float* b3   = (const float*)d_in[22];
  const float* w4   = (const float*)d_in[23];

  if(ws_size < 156061696ull) return;
  char* ws = (char*)d_ws;
  float* pts   = (float*)(ws + 0);
  float* xe0   = (float*)(ws + 98304);
  float* sqp   = (float*)(ws + 196608);
  float* sqe   = (float*)(ws + 229376);
  float* sqx1  = (float*)(ws + 262144);
  float* xe1   = (float*)(ws + 294912);
  float* xe1T  = (float*)(ws + 2392064);
  float* xe2   = (float*)(ws + 4489216);
  float* kr    = (float*)(ws + 8683520);
  int*   idxP  = (int*)  (ws + 12877824);
  int*   idx1  = (int*)  (ws + 13926400);
  int*   idx2  = (int*)  (ws + 14974976);
  float* psum  = (float*)(ws + 16023552);
  float* psq   = (float*)(ws + 17072128);
  float* par   = (float*)(ws + 18120704);
  float* pmax  = (float*)(ws + 18153472);
  short* wb0   = (short*)(ws + 18157568);   // ec1 w2 bf16 fragments (16KB region)
  float* wT4   = (float*)(ws + 21827584);
  float* hbuf  = (float*)(ws + 21843968);
  short* wbe1  = (short*)(ws + 0);
  short* wbe2  = (short*)(ws + 65536);
  float4* pts4 = (float4*)(ws + 4489216);
  float4* xe04 = (float4*)(ws + 4489216 + 131072);
  short* actB  = (short*)(ws + 88952832);
  short* xpack = (short*)(ws + 88952832);
  short* h1b   = (short*)(ws + 21843968);   // bf16 h1, 67 MB; reuses D region (dead after knn_sel)
  short* wb1   = (short*)(ws + 105730048);
  short* wb2   = (short*)(ws + 106254336);
  short* wb3   = (short*)(ws + 107302912);
  float* pmom  = psum;
  float* momv  = psq;

  float* e1s1 = par+0;    float* e1t1 = par+64;
  float* e1s2 = par+128;  float* e1t2 = par+192;
  float* e2s1 = par+256;  float* e2t1 = par+384;
  float* e2s2 = par+512;  float* e2t2 = par+640;
  float* c1s  = par+768;  float* c1t  = par+1792;
  float* c2s  = par+2816; float* c2t  = par+3328;
  float* c3s  = par+3840; float* c3t  = par+4096;

  float* c1out = hbuf + 2097152;
  float* c2out = hbuf + 10485760;
  float* c3out = hbuf + 14680064;

  hipLaunchKernelGGL(k_prep, dim3(32), dim3(256), 0, stream, x, pts, xe0, sqp, sqe, pts4, xe04);
  hipLaunchKernelGGL(k_knn3, dim3(2048), dim3(256), 0, stream, pts4, idxP);
  hipLaunchKernelGGL(k_knn3, dim3(2048), dim3(256), 0, stream, xe04, idx1);
  hipLaunchKernelGGL(k_gauss, dim3(8192), dim3(128), 0, stream, pts, sqp, idxP, kc, kr);

  // edge-conv 1 (moment-based BN1 stats; bf16 MFMA second layer)
  hipLaunchKernelGGL(k_wprep, dim3(2), dim3(256), 0, stream, e1w2, wb0, 64, 64);
  hipLaunchKernelGGL(k_ec1mom, dim3(512), dim3(256), 0, stream, xe0, idx1, pmom);
  hipLaunchKernelGGL(k_msum, dim3(27), dim3(256), 0, stream, pmom, momv);
  hipLaunchKernelGGL(k_ec1bn, dim3(1), dim3(64), 0, stream, momv, e1w1, e1g1, e1b1, e1s1, e1t1);
  hipLaunchKernelGGL(k_ec1g2m, dim3(2048), dim3(256), 0, stream, xe0, idx1, wb0, e1w1, e1s1, e1t1, hbuf, psum, psq);
  hipLaunchKernelGGL(k_fin, dim3(64), dim3(256), 0, stream, psum, psq, 2048, 64, 262144.f, e1g2, e1b2, e1s2, e1t2);
  hipLaunchKernelGGL(k_ec1fin, dim3(2048), dim3(256), 0, stream, hbuf, e1s2, e1t2, xe1, xe1T, sqx1);

  // knn on 64-d features: bf16 MFMA distance GEMM (fp16-packed D) + streaming selection
  hipLaunchKernelGGL(k_wprep, dim3(256), dim3(256), 0, stream, xe1, xpack, 8192, 64);
  hipLaunchKernelGGL(k_dgemm_m, dim3(32,32,2), dim3(256), 0, stream, xpack, sqx1, (__half*)hbuf);
  hipLaunchKernelGGL(k_knn_sel, dim3(2048), dim3(256), 0, stream, (const __half2*)hbuf, idx2);

  // edge-conv 2 (bf16 MFMA formulation, h1 kept bf16, fused stats+max)
  hipLaunchKernelGGL(k_wprep, dim3(8), dim3(256), 0, stream, e2w1, wbe1, 128, 128);
  hipLaunchKernelGGL(k_wprep, dim3(8), dim3(256), 0, stream, e2w2, wbe2, 128, 128);
  hipLaunchKernelGGL(k_ec2m1, dim3(2048), dim3(256), 0, stream, xe1, idx2, wbe1, h1b, psum, psq);
  hipLaunchKernelGGL(k_fin, dim3(128), dim3(256), 0, stream, psum, psq, 2048, 128, 262144.f, e2g1, e2b1, e2s1, e2t1);
  hipLaunchKernelGGL(k_ec2m2, dim3(2048), dim3(256), 0, stream, h1b, wbe2, e2s1, e2t1, xe2, psum, psq);
  hipLaunchKernelGGL(k_fin, dim3(128), dim3(256), 0, stream, psum, psq, 2048, 128, 262144.f, e2g2, e2b2, e2s2, e2t2);
  hipLaunchKernelGGL(k_xe2fin, dim3(4096), dim3(256), 0, stream, xe2, e2s2, e2t2);

  // bf16 MFMA cbr chain (hcat fused into k_bprep1)
  hipLaunchKernelGGL(k_wprep, dim3(128), dim3(256), 0, stream, w1, wb1, 1024, 256);
  hipLaunchKernelGGL(k_wprep, dim3(256), dim3(256), 0, stream, w2, wb2, 512, 1024);
  hipLaunchKernelGGL(k_wprep, dim3(64),  dim3(256), 0, stream, w3, wb3, 256, 512);
  hipLaunchKernelGGL(k_transpose, dim3((9*256+255)/256), dim3(256), 0, stream, w4, wT4, 9, 256);

  hipLaunchKernelGGL(k_bprep1, dim3(1024), dim3(256), 0, stream, xe2, kr, actB);
  hipLaunchKernelGGL(k_gmm, dim3(64,8), dim3(256), 0, stream, wb1, actB, c1out, 1024, 256);
  hipLaunchKernelGGL(k_cstats, dim3(1024), dim3(256), 0, stream, c1out, 1024, g1, b1, c1s, c1t);

  hipLaunchKernelGGL(k_bprep, dim3(4096), dim3(256), 0, stream, c1out, c1s, c1t, actB, 1024);
  hipLaunchKernelGGL(k_gmm, dim3(64,4), dim3(256), 0, stream, wb2, actB, c2out, 512, 1024);
  hipLaunchKernelGGL(k_cstats, dim3(512), dim3(256), 0, stream, c2out, 512, g2, b2, c2s, c2t);

  hipLaunchKernelGGL(k_bprep, dim3(2048), dim3(256), 0, stream, c2out, c2s, c2t, actB, 512);
  hipLaunchKernelGGL(k_gmm, dim3(64,2), dim3(256), 0, stream, wb3, actB, c3out, 256, 512);
  hipLaunchKernelGGL(k_cstats, dim3(256), dim3(256), 0, stream, c3out, 256, g3, b3, c3s, c3t);

  hipLaunchKernelGGL(k_final4, dim3(16,2), dim3(256), 0, stream, c3out, wT4, c3s, c3t, pmax);
  hipLaunchKernelGGL(k_out, dim3(1), dim3(32), 0, stream, pmax, (float*)d_out);
}